// Round 5
// baseline (1191.411 us; speedup 1.0000x reference)
//
#include <hip/hip_runtime.h>
#include <stdint.h>
#include <math.h>

typedef __bf16 bf16_t;
typedef __bf16 bf16x8 __attribute__((ext_vector_type(8)));
typedef __bf16 bf16x4 __attribute__((ext_vector_type(4)));
typedef float f32x4 __attribute__((ext_vector_type(4)));

#define GLD_LDS16(g, l)                                             \
    __builtin_amdgcn_global_load_lds(                               \
        (const __attribute__((address_space(1))) void*)(g),         \
        (__attribute__((address_space(3))) void*)(l), 16, 0, 0)

__device__ __forceinline__ bf16_t split2h(float x) { return (bf16_t)x; }
__device__ __forceinline__ bf16_t split2l(float x)
{
    return (bf16_t)(x - (float)(bf16_t)x);
}

// ---------------------------------------------------------------------------
// transpose + split-convert: in [R][C] fp32 -> oh/ol [C][R] bf16 hi/lo
// ---------------------------------------------------------------------------
__global__ __launch_bounds__(256)
void transpose_split(const float* __restrict__ in, bf16_t* __restrict__ oh,
                     bf16_t* __restrict__ ol, int R, int C)
{
    __shared__ float t[64][65];
    const int r0 = blockIdx.y * 64, c0 = blockIdx.x * 64;
#pragma unroll
    for (int i = 0; i < 16; ++i) {
        int f = threadIdx.x + i * 256;
        int r = f >> 6, c = f & 63;
        t[r][c] = in[(size_t)(r0 + r) * C + c0 + c];
    }
    __syncthreads();
#pragma unroll
    for (int i = 0; i < 16; ++i) {
        int f = threadIdx.x + i * 256;
        int r = f >> 6, c = f & 63;
        float x = t[c][r];
        oh[(size_t)(c0 + r) * R + r0 + c] = split2h(x);
        ol[(size_t)(c0 + r) * R + r0 + c] = split2l(x);
    }
}

// ---------------------------------------------------------------------------
// RoPE cos/sin tables via fp64 (exact angle reduction)
// ---------------------------------------------------------------------------
__global__ __launch_bounds__(256)
void rope_tables(float* __restrict__ ct, float* __restrict__ st)
{
    int t = blockIdx.x * 256 + threadIdx.x;   // 4096*128
    int s = t >> 7, j = t & 127;
    double inv = exp2((double)j * (-13.28771237954945 / 128.0)); // log2(10000)
    double ang = fmod((double)s * inv, 6.283185307179586476925286766559);
    ct[t] = (float)cos(ang);
    st[t] = (float)sin(ang);
}

// ---------------------------------------------------------------------------
// GEMM1-QK: q/k = hs(fp32, split in-kernel) @ Wqk^T(pre-split hi/lo), 3-pass.
// ---------------------------------------------------------------------------
__global__ __launch_bounds__(256)
void gemm1qk(const float* __restrict__ A, const bf16_t* __restrict__ Bh,
             const bf16_t* __restrict__ Bl, bf16_t* __restrict__ qp,
             bf16_t* __restrict__ kp)
{
    __shared__ __attribute__((aligned(16))) bf16_t Ah[128 * 32];
    __shared__ __attribute__((aligned(16))) bf16_t Al[128 * 32];
    __shared__ __attribute__((aligned(16))) bf16_t Bsh[128 * 32];
    __shared__ __attribute__((aligned(16))) bf16_t Bsl[128 * 32];
    const int tid = threadIdx.x, lane = tid & 63, wid = tid >> 6;
    const int g = lane >> 4, c16 = lane & 15;
    const int m0 = blockIdx.y * 128, n0 = blockIdx.x * 128;
    const int wm = wid >> 1, wn = wid & 1;

    f32x4 acc[4][4];
#pragma unroll
    for (int i = 0; i < 4; ++i)
#pragma unroll
        for (int j = 0; j < 4; ++j) acc[i][j] = (f32x4)(0.f);

    const int f0 = tid, f1 = tid + 256;
    for (int k0 = 0; k0 < 2560; k0 += 32) {
        __syncthreads();
        GLD_LDS16(Bh + (size_t)(n0 + (f0 >> 2)) * 2560 + k0 + (f0 & 3) * 8,
                  (char*)Bsh + wid * 1024);
        GLD_LDS16(Bh + (size_t)(n0 + (f1 >> 2)) * 2560 + k0 + (f1 & 3) * 8,
                  (char*)Bsh + wid * 1024 + 4096);
        GLD_LDS16(Bl + (size_t)(n0 + (f0 >> 2)) * 2560 + k0 + (f0 & 3) * 8,
                  (char*)Bsl + wid * 1024);
        GLD_LDS16(Bl + (size_t)(n0 + (f1 >> 2)) * 2560 + k0 + (f1 & 3) * 8,
                  (char*)Bsl + wid * 1024 + 4096);
#pragma unroll
        for (int i = 0; i < 4; ++i) {
            int f = tid + i * 256;
            float4 v = *(const float4*)(A + (size_t)(m0 + (f >> 3)) * 2560
                                        + k0 + (f & 7) * 4);
            bf16x4 hv, lv;
            hv[0] = split2h(v.x); lv[0] = split2l(v.x);
            hv[1] = split2h(v.y); lv[1] = split2l(v.y);
            hv[2] = split2h(v.z); lv[2] = split2l(v.z);
            hv[3] = split2h(v.w); lv[3] = split2l(v.w);
            *(bf16x4*)((char*)Ah + (f >> 3) * 64 + (f & 7) * 8) = hv;
            *(bf16x4*)((char*)Al + (f >> 3) * 64 + (f & 7) * 8) = lv;
        }
        __syncthreads();
        bf16x8 ah[4], al[4], bh[4], bl[4];
#pragma unroll
        for (int m = 0; m < 4; ++m) {
            int off = (wm * 64 + m * 16 + c16) * 32 + g * 8;
            ah[m] = *(const bf16x8*)(Ah + off);
            al[m] = *(const bf16x8*)(Al + off);
        }
#pragma unroll
        for (int n = 0; n < 4; ++n) {
            int off = (wn * 64 + n * 16 + c16) * 32 + g * 8;
            bh[n] = *(const bf16x8*)(Bsh + off);
            bl[n] = *(const bf16x8*)(Bsl + off);
        }
#pragma unroll
        for (int m = 0; m < 4; ++m)
#pragma unroll
            for (int n = 0; n < 4; ++n) {
                acc[m][n] = __builtin_amdgcn_mfma_f32_16x16x32_bf16(ah[m], bh[n], acc[m][n], 0, 0, 0);
                acc[m][n] = __builtin_amdgcn_mfma_f32_16x16x32_bf16(al[m], bh[n], acc[m][n], 0, 0, 0);
                acc[m][n] = __builtin_amdgcn_mfma_f32_16x16x32_bf16(ah[m], bl[n], acc[m][n], 0, 0, 0);
            }
    }

    if (n0 < 2048) {          // q region
#pragma unroll
        for (int m = 0; m < 4; ++m)
#pragma unroll
            for (int n = 0; n < 4; ++n) {
                int col = n0 + wn * 64 + n * 16 + c16;
                int rowb = m0 + wm * 64 + m * 16 + g * 4;
#pragma unroll
                for (int r = 0; r < 4; ++r) {
                    float x = acc[m][n][r];
                    qp[(size_t)(rowb + r) * 4096 + col] = split2h(x);
                    qp[(size_t)(rowb + r) * 4096 + 2048 + col] = split2l(x);
                }
            }
    } else {                  // k region
#pragma unroll
        for (int m = 0; m < 4; ++m)
#pragma unroll
            for (int n = 0; n < 4; ++n) {
                int col = n0 + wn * 64 + n * 16 + c16 - 2048;
                int rowb = m0 + wm * 64 + m * 16 + g * 4;
#pragma unroll
                for (int r = 0; r < 4; ++r) {
                    float x = acc[m][n][r];
                    kp[(size_t)(rowb + r) * 2048 + col] = split2h(x);
                    kp[(size_t)(rowb + r) * 2048 + 1024 + col] = split2l(x);
                }
            }
    }
}

// ---------------------------------------------------------------------------
// GEMM1-V: v = hs @ Wv^T (3-pass), epilogue split+transpose -> vT hi/lo
// ---------------------------------------------------------------------------
__global__ __launch_bounds__(256)
void gemm1v(const float* __restrict__ A, const bf16_t* __restrict__ Bh,
            const bf16_t* __restrict__ Bl, bf16_t* __restrict__ vh,
            bf16_t* __restrict__ vl)
{
    __shared__ __attribute__((aligned(16))) bf16_t Ah[128 * 32];
    __shared__ __attribute__((aligned(16))) bf16_t Al[128 * 32];
    __shared__ __attribute__((aligned(16))) bf16_t Bsh[128 * 32];
    __shared__ __attribute__((aligned(16))) bf16_t Bsl[128 * 32];
    const int tid = threadIdx.x, lane = tid & 63, wid = tid >> 6;
    const int g = lane >> 4, c16 = lane & 15;
    const int m0 = blockIdx.y * 128, n0 = blockIdx.x * 128;
    const int wm = wid >> 1, wn = wid & 1;

    f32x4 acc[4][4];
#pragma unroll
    for (int i = 0; i < 4; ++i)
#pragma unroll
        for (int j = 0; j < 4; ++j) acc[i][j] = (f32x4)(0.f);

    const int f0 = tid, f1 = tid + 256;
    for (int k0 = 0; k0 < 2560; k0 += 32) {
        __syncthreads();
        GLD_LDS16(Bh + (size_t)(n0 + (f0 >> 2)) * 2560 + k0 + (f0 & 3) * 8,
                  (char*)Bsh + wid * 1024);
        GLD_LDS16(Bh + (size_t)(n0 + (f1 >> 2)) * 2560 + k0 + (f1 & 3) * 8,
                  (char*)Bsh + wid * 1024 + 4096);
        GLD_LDS16(Bl + (size_t)(n0 + (f0 >> 2)) * 2560 + k0 + (f0 & 3) * 8,
                  (char*)Bsl + wid * 1024);
        GLD_LDS16(Bl + (size_t)(n0 + (f1 >> 2)) * 2560 + k0 + (f1 & 3) * 8,
                  (char*)Bsl + wid * 1024 + 4096);
#pragma unroll
        for (int i = 0; i < 4; ++i) {
            int f = tid + i * 256;
            float4 v = *(const float4*)(A + (size_t)(m0 + (f >> 3)) * 2560
                                        + k0 + (f & 7) * 4);
            bf16x4 hv, lv;
            hv[0] = split2h(v.x); lv[0] = split2l(v.x);
            hv[1] = split2h(v.y); lv[1] = split2l(v.y);
            hv[2] = split2h(v.z); lv[2] = split2l(v.z);
            hv[3] = split2h(v.w); lv[3] = split2l(v.w);
            *(bf16x4*)((char*)Ah + (f >> 3) * 64 + (f & 7) * 8) = hv;
            *(bf16x4*)((char*)Al + (f >> 3) * 64 + (f & 7) * 8) = lv;
        }
        __syncthreads();
        bf16x8 ah[4], al[4], bh[4], bl[4];
#pragma unroll
        for (int m = 0; m < 4; ++m) {
            int off = (wm * 64 + m * 16 + c16) * 32 + g * 8;
            ah[m] = *(const bf16x8*)(Ah + off);
            al[m] = *(const bf16x8*)(Al + off);
        }
#pragma unroll
        for (int n = 0; n < 4; ++n) {
            int off = (wn * 64 + n * 16 + c16) * 32 + g * 8;
            bh[n] = *(const bf16x8*)(Bsh + off);
            bl[n] = *(const bf16x8*)(Bsl + off);
        }
#pragma unroll
        for (int m = 0; m < 4; ++m)
#pragma unroll
            for (int n = 0; n < 4; ++n) {
                acc[m][n] = __builtin_amdgcn_mfma_f32_16x16x32_bf16(ah[m], bh[n], acc[m][n], 0, 0, 0);
                acc[m][n] = __builtin_amdgcn_mfma_f32_16x16x32_bf16(al[m], bh[n], acc[m][n], 0, 0, 0);
                acc[m][n] = __builtin_amdgcn_mfma_f32_16x16x32_bf16(ah[m], bl[n], acc[m][n], 0, 0, 0);
            }
    }

#pragma unroll
    for (int m = 0; m < 4; ++m)
#pragma unroll
        for (int n = 0; n < 4; ++n) {
            int d = n0 + wn * 64 + n * 16 + c16;
            int rowb = m0 + wm * 64 + m * 16 + g * 4;
            bf16x4 hv, lv;
#pragma unroll
            for (int r = 0; r < 4; ++r) {
                float x = acc[m][n][r];
                hv[r] = split2h(x);
                lv[r] = split2l(x);
            }
            *(bf16x4*)(vh + (size_t)d * 4096 + rowb) = hv;
            *(bf16x4*)(vl + (size_t)d * 4096 + rowb) = lv;
        }
}

// ---------------------------------------------------------------------------
// RMSNorm + RoPE on q pair (in-place).
// ---------------------------------------------------------------------------
__global__ __launch_bounds__(256)
void norm_q(bf16_t* __restrict__ qp, const float* __restrict__ w,
            const float* __restrict__ ct, const float* __restrict__ st)
{
    const int s = blockIdx.x, t = threadIdx.x;
    const int h = t >> 5, l = t & 31;
    bf16_t* base = qp + (size_t)s * 4096 + h * 256 + l * 8;
    bf16x8 hv = *(const bf16x8*)base;
    bf16x8 lv = *(const bf16x8*)(base + 2048);
    float x[8], ss = 0.f;
#pragma unroll
    for (int j = 0; j < 8; ++j) { x[j] = (float)hv[j] + (float)lv[j]; ss += x[j] * x[j]; }
#pragma unroll
    for (int mk = 1; mk < 32; mk <<= 1) ss += __shfl_xor(ss, mk);
    const float rs = rsqrtf(ss * (1.f / 256.f) + 1e-6f);
    float4 w0 = *(const float4*)(w + l * 8);
    float4 w1 = *(const float4*)(w + l * 8 + 4);
    float wa[8] = { w0.x, w0.y, w0.z, w0.w, w1.x, w1.y, w1.z, w1.w };
    float xn[8];
#pragma unroll
    for (int j = 0; j < 8; ++j) xn[j] = x[j] * rs * (1.f + wa[j]);
    const int d0 = (l * 8) & 127;
    float4 c0 = *(const float4*)(ct + s * 128 + d0);
    float4 c1 = *(const float4*)(ct + s * 128 + d0 + 4);
    float4 s0 = *(const float4*)(st + s * 128 + d0);
    float4 s1 = *(const float4*)(st + s * 128 + d0 + 4);
    float cc[8] = { c0.x, c0.y, c0.z, c0.w, c1.x, c1.y, c1.z, c1.w };
    float sn[8] = { s0.x, s0.y, s0.z, s0.w, s1.x, s1.y, s1.z, s1.w };
    const bool upper = (l >= 16);
    bf16x8 oh, ol;
#pragma unroll
    for (int j = 0; j < 8; ++j) {
        float pn = __shfl_xor(xn[j], 16);
        float rot = upper ? pn : -pn;
        float out = xn[j] * cc[j] + rot * sn[j];
        oh[j] = split2h(out);
        ol[j] = split2l(out);
    }
    *(bf16x8*)base = oh;
    *(bf16x8*)(base + 2048) = ol;
}

// ---------------------------------------------------------------------------
// RMSNorm + RoPE on k pair (in-place).
// ---------------------------------------------------------------------------
__global__ __launch_bounds__(256)
void norm_k(bf16_t* __restrict__ kp, const float* __restrict__ w,
            const float* __restrict__ ct, const float* __restrict__ st)
{
    const int s = blockIdx.x, t = threadIdx.x;
    const int h = t >> 6, l = t & 63;
    bf16_t* base = kp + (size_t)s * 2048 + h * 256 + l * 4;
    bf16x4 hv = *(const bf16x4*)base;
    bf16x4 lv = *(const bf16x4*)(base + 1024);
    float x[4], ss = 0.f;
#pragma unroll
    for (int j = 0; j < 4; ++j) { x[j] = (float)hv[j] + (float)lv[j]; ss += x[j] * x[j]; }
#pragma unroll
    for (int mk = 1; mk < 64; mk <<= 1) ss += __shfl_xor(ss, mk);
    const float rs = rsqrtf(ss * (1.f / 256.f) + 1e-6f);
    float4 w0 = *(const float4*)(w + l * 4);
    float wa[4] = { w0.x, w0.y, w0.z, w0.w };
    float xn[4];
#pragma unroll
    for (int j = 0; j < 4; ++j) xn[j] = x[j] * rs * (1.f + wa[j]);
    const int d0 = (l * 4) & 127;
    float4 c0 = *(const float4*)(ct + s * 128 + d0);
    float4 s0 = *(const float4*)(st + s * 128 + d0);
    float cc[4] = { c0.x, c0.y, c0.z, c0.w };
    float sn[4] = { s0.x, s0.y, s0.z, s0.w };
    const bool upper = (l >= 32);
    bf16x4 oh, ol;
#pragma unroll
    for (int j = 0; j < 4; ++j) {
        float pn = __shfl_xor(xn[j], 32);
        float rot = upper ? pn : -pn;
        float out = xn[j] * cc[j] + rot * sn[j];
        oh[j] = split2h(out);
        ol[j] = split2l(out);
    }
    *(bf16x4*)base = oh;
    *(bf16x4*)(base + 1024) = ol;
}

// ---------------------------------------------------------------------------
// Sliding-window GQA flash attention, hi/lo split operands.
// grid (64 qtiles, 8 heads); block 256 (4 waves x 16 q-rows).
// Window spans 17 k-tiles: kt in [qt-16, qt].
// ---------------------------------------------------------------------------
__global__ __launch_bounds__(256)
void attn_fwd2(const bf16_t* __restrict__ qp, const bf16_t* __restrict__ kp,
               const bf16_t* __restrict__ vh, const bf16_t* __restrict__ vl,
               bf16_t* __restrict__ attn)
{
    __shared__ __attribute__((aligned(16))) bf16_t Ph[4][16][72];
    __shared__ __attribute__((aligned(16))) bf16_t Pl[4][16][72];
    const int tid = threadIdx.x, lane = tid & 63, wid = tid >> 6;
    const int g = lane >> 4, c16 = lane & 15;
    const int qt = blockIdx.x, h = blockIdx.y, kvh = h >> 1;
    const int qrow0 = qt * 64 + wid * 16;

    bf16x8 qh[8], ql[8];
#pragma unroll
    for (int c = 0; c < 8; ++c) {
        const bf16_t* qb = qp + (size_t)(qrow0 + c16) * 4096 + h * 256 + c * 32 + g * 8;
        qh[c] = *(const bf16x8*)qb;
        ql[c] = *(const bf16x8*)(qb + 2048);
    }

    float mrow[4] = { -1e30f, -1e30f, -1e30f, -1e30f };
    float lrow[4] = { 0.f, 0.f, 0.f, 0.f };
    f32x4 acc[16];
#pragma unroll
    for (int nd = 0; nd < 16; ++nd) acc[nd] = (f32x4)(0.f);

    const int kt_lo = (qt >= 16) ? qt - 16 : 0;
    for (int kt = kt_lo; kt <= qt; ++kt) {
        f32x4 sc[4];
#pragma unroll
        for (int n = 0; n < 4; ++n) sc[n] = (f32x4)(0.f);
#pragma unroll
        for (int n = 0; n < 4; ++n) {
            const bf16_t* kb = kp + (size_t)(kt * 64 + n * 16 + c16) * 2048
                               + kvh * 256 + g * 8;
#pragma unroll
            for (int c = 0; c < 8; ++c) {
                bf16x8 kh = *(const bf16x8*)(kb + c * 32);
                bf16x8 kl = *(const bf16x8*)(kb + 1024 + c * 32);
                sc[n] = __builtin_amdgcn_mfma_f32_16x16x32_bf16(qh[c], kh, sc[n], 0, 0, 0);
                sc[n] = __builtin_amdgcn_mfma_f32_16x16x32_bf16(ql[c], kh, sc[n], 0, 0, 0);
                sc[n] = __builtin_amdgcn_mfma_f32_16x16x32_bf16(qh[c], kl, sc[n], 0, 0, 0);
            }
        }
        float rm[4] = { -1e30f, -1e30f, -1e30f, -1e30f };
#pragma unroll
        for (int n = 0; n < 4; ++n) {
            const int key = kt * 64 + n * 16 + c16;
#pragma unroll
            for (int r = 0; r < 4; ++r) {
                const int q = qrow0 + g * 4 + r;
                float s = sc[n][r] * 0.0625f;
                bool valid = (key <= q) && (q - key < 1024);
                s = valid ? s : -1e30f;
                sc[n][r] = s;
                rm[r] = fmaxf(rm[r], s);
            }
        }
#pragma unroll
        for (int mk = 1; mk < 16; mk <<= 1)
#pragma unroll
            for (int r = 0; r < 4; ++r) rm[r] = fmaxf(rm[r], __shfl_xor(rm[r], mk));
        float alpha[4], psum[4] = { 0.f, 0.f, 0.f, 0.f };
#pragma unroll
        for (int r = 0; r < 4; ++r) {
            float nm = fmaxf(mrow[r], rm[r]);
            alpha[r] = __expf(mrow[r] - nm);
            mrow[r] = nm;
        }
#pragma unroll
        for (int n = 0; n < 4; ++n)
#pragma unroll
            for (int r = 0; r < 4; ++r) {
                // guard: fully-masked entries (s == -1e30 AND mrow == -1e30)
                // would give exp(0)=1; force exact 0 instead.
                float sv = sc[n][r];
                float pv = (sv > -1e29f) ? __expf(sv - mrow[r]) : 0.f;
                sc[n][r] = pv;
                psum[r] += pv;
            }
#pragma unroll
        for (int mk = 1; mk < 16; mk <<= 1)
#pragma unroll
            for (int r = 0; r < 4; ++r) psum[r] += __shfl_xor(psum[r], mk);
#pragma unroll
        for (int r = 0; r < 4; ++r) lrow[r] = lrow[r] * alpha[r] + psum[r];
#pragma unroll
        for (int nd = 0; nd < 16; ++nd)
#pragma unroll
            for (int r = 0; r < 4; ++r) acc[nd][r] *= alpha[r];

        __syncthreads();
#pragma unroll
        for (int n = 0; n < 4; ++n)
#pragma unroll
            for (int r = 0; r < 4; ++r) {
                float pv = sc[n][r];
                Ph[wid][g * 4 + r][n * 16 + c16] = split2h(pv);
                Pl[wid][g * 4 + r][n * 16 + c16] = split2l(pv);
            }
        __syncthreads();
        bf16x8 pah[2], pal[2];
#pragma unroll
        for (int c = 0; c < 2; ++c) {
            pah[c] = *(const bf16x8*)(&Ph[wid][c16][c * 32 + g * 8]);
            pal[c] = *(const bf16x8*)(&Pl[wid][c16][c * 32 + g * 8]);
        }
#pragma unroll
        for (int nd = 0; nd < 16; ++nd) {
            const size_t vb = (size_t)(kvh * 256 + nd * 16 + c16) * 4096 + kt * 64 + g * 8;
#pragma unroll
            for (int c = 0; c < 2; ++c) {
                bf16x8 vhv = *(const bf16x8*)(vh + vb + c * 32);
                bf16x8 vlv = *(const bf16x8*)(vl + vb + c * 32);
                acc[nd] = __builtin_amdgcn_mfma_f32_16x16x32_bf16(pah[c], vhv, acc[nd], 0, 0, 0);
                acc[nd] = __builtin_amdgcn_mfma_f32_16x16x32_bf16(pal[c], vhv, acc[nd], 0, 0, 0);
                acc[nd] = __builtin_amdgcn_mfma_f32_16x16x32_bf16(pah[c], vlv, acc[nd], 0, 0, 0);
            }
        }
    }
    float inv[4];
#pragma unroll
    for (int r = 0; r < 4; ++r) inv[r] = 1.f / lrow[r];
#pragma unroll
    for (int nd = 0; nd < 16; ++nd)
#pragma unroll
        for (int r = 0; r < 4; ++r) {
            int row = qrow0 + g * 4 + r;
            attn[(size_t)row * 2048 + h * 256 + nd * 16 + c16] =
                (bf16_t)(acc[nd][r] * inv[r]);
        }
}

// ---------------------------------------------------------------------------
// GEMM2: out(fp32) = attn(bf16) @ woT(pre-split hi/lo), 2-pass MFMA.
// ---------------------------------------------------------------------------
__global__ __launch_bounds__(256)
void gemm2(const bf16_t* __restrict__ A, const bf16_t* __restrict__ Bh,
           const bf16_t* __restrict__ Bl, float* __restrict__ C)
{
    __shared__ __attribute__((aligned(16))) bf16_t As[128 * 32];
    __shared__ __attribute__((aligned(16))) bf16_t Bsh[128 * 32];
    __shared__ __attribute__((aligned(16))) bf16_t Bsl[128 * 32];
    const int tid = threadIdx.x, lane = tid & 63, wid = tid >> 6;
    const int g = lane >> 4, c16 = lane & 15;
    const int m0 = blockIdx.y * 128, n0 = blockIdx.x * 128;
    const int wm = wid >> 1, wn = wid & 1;

    f32x4 acc[4][4];
#pragma unroll
    for (int i = 0; i < 4; ++i)
#pragma unroll
        for (int j = 0; j < 4; ++j) acc[i][j] = (f32x4)(0.f);

    const int f0 = tid, f1 = tid + 256;
    for (int k0 = 0; k0 < 2048; k0 += 32) {
        __syncthreads();
        GLD_LDS16(A + (size_t)(m0 + (f0 >> 2)) * 2048 + k0 + (f0 & 3) * 8,
                  (char*)As + wid * 1024);
        GLD_LDS16(A + (size_t)(m0 + (f1 >> 2)) * 2048 + k0 + (f1 & 3) * 8,
                  (char*)As + wid * 1024 + 4096);
        GLD_LDS16(Bh + (size_t)(n0 + (f0 >> 2)) * 2048 + k0 + (f0 & 3) * 8,
                  (char*)Bsh + wid * 1024);
        GLD_LDS16(Bh + (size_t)(n0 + (f1 >> 2)) * 2048 + k0 + (f1 & 3) * 8,
                  (char*)Bsh + wid * 1024 + 4096);
        GLD_LDS16(Bl + (size_t)(n0 + (f0 >> 2)) * 2048 + k0 + (f0 & 3) * 8,
                  (char*)Bsl + wid * 1024);
        GLD_LDS16(Bl + (size_t)(n0 + (f1 >> 2)) * 2048 + k0 + (f1 & 3) * 8,
                  (char*)Bsl + wid * 1024 + 4096);
        __syncthreads();
        bf16x8 af[4], bh[4], bl[4];
#pragma unroll
        for (int m = 0; m < 4; ++m)
            af[m] = *(const bf16x8*)(As + (wm * 64 + m * 16 + c16) * 32 + g * 8);
#pragma unroll
        for (int n = 0; n < 4; ++n) {
            int off = (wn * 64 + n * 16 + c16) * 32 + g * 8;
            bh[n] = *(const bf16x8*)(Bsh + off);
            bl[n] = *(const bf16x8*)(Bsl + off);
        }
#pragma unroll
        for (int m = 0; m < 4; ++m)
#pragma unroll
            for (int n = 0; n < 4; ++n) {
                acc[m][n] = __builtin_amdgcn_mfma_f32_16x16x32_bf16(af[m], bh[n], acc[m][n], 0, 0, 0);
                acc[m][n] = __builtin_amdgcn_mfma_f32_16x16x32_bf16(af[m], bl[n], acc[m][n], 0, 0, 0);
            }
    }

#pragma unroll
    for (int m = 0; m < 4; ++m)
#pragma unroll
        for (int n = 0; n < 4; ++n)
#pragma unroll
            for (int r = 0; r < 4; ++r) {
                int row = m0 + wm * 64 + m * 16 + g * 4 + r;
                int col = n0 + wn * 64 + n * 16 + c16;
                C[(size_t)row * 2560 + col] = acc[m][n][r];
            }
}

// ---------------------------------------------------------------------------
// Workspace layout (peak 80 MB; phase-aliased; all offsets 16B-aligned):
//   qp    [0,          33,554,432)   4096 x (2048 hi | 2048 lo) bf16
//   kp    [33,554,432, 50,331,648)   4096 x (1024 hi | 1024 lo)
//   vh    [50,331,648, 58,720,256)   vT hi [1024][4096]   (written gemm1v)
//   vl    [58,720,256, 67,108,864)   vT lo
//   Bqkh  [50,331,648, 66,060,288)   [3072][2560]  (dead after gemm1qk)
//   Bqkl  [66,060,288, 81,788,928)                 (dead after gemm1qk)
//   Bvh   [67,108,864, 72,351,744)   [1024][2560]  (dead after gemm1v)
//   Bvl   [72,351,744, 77,594,624)
//   ct    [77,594,624, 79,691,776)   cos table     (dead after norms)
//   st    [79,691,776, 81,788,928)   sin table
//   attnb [67,108,864, 83,886,080)   [4096][2048] bf16 (written by attn)
//   woh   [0,          10,485,760)   [2560][2048]  (over dead qp)
//   wol   [10,485,760, 20,971,520)
// ---------------------------------------------------------------------------
extern "C" void kernel_launch(void* const* d_in, const int* in_sizes, int n_in,
                              void* d_out, int out_size, void* d_ws, size_t ws_size,
                              hipStream_t stream)
{
    (void)in_sizes; (void)n_in; (void)out_size; (void)ws_size;
    const float* hs  = (const float*)d_in[0];
    const float* wq  = (const float*)d_in[3];
    const float* wk  = (const float*)d_in[4];
    const float* wv  = (const float*)d_in[5];
    const float* wo  = (const float*)d_in[6];
    const float* qnw = (const float*)d_in[7];
    const float* knw = (const float*)d_in[8];

    char* ws = (char*)d_ws;
    bf16_t* qp    = (bf16_t*)(ws);
    bf16_t* kp    = (bf16_t*)(ws + 33554432);
    bf16_t* vh    = (bf16_t*)(ws + 50331648);
    bf16_t* vl    = (bf16_t*)(ws + 58720256);
    bf16_t* Bqkh  = (bf16_t*)(ws + 50331648);
    bf16_t* Bqkl  = (bf16_t*)(ws + 66060288);
    bf16_t* Bvh   = (bf16_t*)(ws + 67108864);
    bf16_t* Bvl   = (bf16_t*)(ws + 72351744);
    float*  ct    = (float*)(ws + 77594624);
    float*  st    = (float*)(ws + 79691776);
    bf16_t* attnb = (bf16_t*)(ws + 67108864);
    bf16_t* woh   = (bf16_t*)(ws);
    bf16_t* wol   = (bf16_t*)(ws + 10485760);

    // 1. wq,wk -> Bqk panels [3072][2560] hi/lo
    transpose_split<<<dim3(32, 40), 256, 0, stream>>>(wq, Bqkh, Bqkl, 2560, 2048);
    transpose_split<<<dim3(16, 40), 256, 0, stream>>>(wk, Bqkh + (size_t)2048 * 2560,
                                                      Bqkl + (size_t)2048 * 2560, 2560, 1024);
    // 2. q/k projection (writes qp, kp)
    gemm1qk<<<dim3(24, 32), 256, 0, stream>>>(hs, Bqkh, Bqkl, qp, kp);

    // 3. wv -> Bv panels (over dead Bqkl tail region)
    transpose_split<<<dim3(16, 40), 256, 0, stream>>>(wv, Bvh, Bvl, 2560, 1024);
    // 4. v projection -> vT hi/lo (over dead Bqkh)
    gemm1v<<<dim3(8, 32), 256, 0, stream>>>(hs, Bvh, Bvl, vh, vl);

    // 5. RoPE tables + norms
    rope_tables<<<2048, 256, 0, stream>>>(ct, st);
    norm_q<<<4096, 256, 0, stream>>>(qp, qnw, ct, st);
    norm_k<<<4096, 256, 0, stream>>>(kp, knw, ct, st);

    // 6. attention (writes attnb over dead Bv/ct/st)
    attn_fwd2<<<dim3(64, 8), 256, 0, stream>>>(qp, kp, vh, vl, attnb);

    // 7. wo -> woT panels (over dead qp), then output projection
    transpose_split<<<dim3(40, 32), 256, 0, stream>>>(wo, woh, wol, 2048, 2560);
    gemm2<<<dim3(20, 32), 256, 0, stream>>>(attnb, woh, wol, (float*)d_out);
}

// Round 6
// 917.833 us; speedup vs baseline: 1.2981x; 1.2981x over previous
//
#include <hip/hip_runtime.h>
#include <stdint.h>
#include <math.h>

typedef __bf16 bf16_t;
typedef __bf16 bf16x8 __attribute__((ext_vector_type(8)));
typedef __bf16 bf16x4 __attribute__((ext_vector_type(4)));
typedef float f32x4 __attribute__((ext_vector_type(4)));

#define GLD_LDS16(g, l)                                             \
    __builtin_amdgcn_global_load_lds(                               \
        (const __attribute__((address_space(1))) void*)(g),         \
        (__attribute__((address_space(3))) void*)(l), 16, 0, 0)

__device__ __forceinline__ bf16_t split2h(float x) { return (bf16_t)x; }
__device__ __forceinline__ bf16_t split2l(float x)
{
    return (bf16_t)(x - (float)(bf16_t)x);
}

// ---------------------------------------------------------------------------
// transpose + split-convert: in [R][C] fp32 -> oh/ol [C][R] bf16 hi/lo
// ---------------------------------------------------------------------------
__global__ __launch_bounds__(256)
void transpose_split(const float* __restrict__ in, bf16_t* __restrict__ oh,
                     bf16_t* __restrict__ ol, int R, int C)
{
    __shared__ float t[64][65];
    const int r0 = blockIdx.y * 64, c0 = blockIdx.x * 64;
#pragma unroll
    for (int i = 0; i < 16; ++i) {
        int f = threadIdx.x + i * 256;
        int r = f >> 6, c = f & 63;
        t[r][c] = in[(size_t)(r0 + r) * C + c0 + c];
    }
    __syncthreads();
#pragma unroll
    for (int i = 0; i < 16; ++i) {
        int f = threadIdx.x + i * 256;
        int r = f >> 6, c = f & 63;
        float x = t[c][r];
        oh[(size_t)(c0 + r) * R + r0 + c] = split2h(x);
        ol[(size_t)(c0 + r) * R + r0 + c] = split2l(x);
    }
}

// ---------------------------------------------------------------------------
// RoPE cos/sin tables via fp64 (exact angle reduction)
// ---------------------------------------------------------------------------
__global__ __launch_bounds__(256)
void rope_tables(float* __restrict__ ct, float* __restrict__ st)
{
    int t = blockIdx.x * 256 + threadIdx.x;   // 4096*128
    int s = t >> 7, j = t & 127;
    double inv = exp2((double)j * (-13.28771237954945 / 128.0)); // log2(10000)
    double ang = fmod((double)s * inv, 6.283185307179586476925286766559);
    ct[t] = (float)cos(ang);
    st[t] = (float)sin(ang);
}

// ---------------------------------------------------------------------------
// GEMM1-QK: q/k = hs(fp32, split in-kernel) @ Wqk^T(pre-split hi/lo), 3-pass.
// Outputs plain bf16: qb[4096][2048], kb[4096][1024].
// ---------------------------------------------------------------------------
__global__ __launch_bounds__(256)
void gemm1qk(const float* __restrict__ A, const bf16_t* __restrict__ Bh,
             const bf16_t* __restrict__ Bl, bf16_t* __restrict__ qb,
             bf16_t* __restrict__ kb)
{
    __shared__ __attribute__((aligned(16))) bf16_t Ah[128 * 32];
    __shared__ __attribute__((aligned(16))) bf16_t Al[128 * 32];
    __shared__ __attribute__((aligned(16))) bf16_t Bsh[128 * 32];
    __shared__ __attribute__((aligned(16))) bf16_t Bsl[128 * 32];
    const int tid = threadIdx.x, lane = tid & 63, wid = tid >> 6;
    const int g = lane >> 4, c16 = lane & 15;
    const int m0 = blockIdx.y * 128, n0 = blockIdx.x * 128;
    const int wm = wid >> 1, wn = wid & 1;

    f32x4 acc[4][4];
#pragma unroll
    for (int i = 0; i < 4; ++i)
#pragma unroll
        for (int j = 0; j < 4; ++j) acc[i][j] = (f32x4)(0.f);

    const int f0 = tid, f1 = tid + 256;
    for (int k0 = 0; k0 < 2560; k0 += 32) {
        __syncthreads();
        GLD_LDS16(Bh + (size_t)(n0 + (f0 >> 2)) * 2560 + k0 + (f0 & 3) * 8,
                  (char*)Bsh + wid * 1024);
        GLD_LDS16(Bh + (size_t)(n0 + (f1 >> 2)) * 2560 + k0 + (f1 & 3) * 8,
                  (char*)Bsh + wid * 1024 + 4096);
        GLD_LDS16(Bl + (size_t)(n0 + (f0 >> 2)) * 2560 + k0 + (f0 & 3) * 8,
                  (char*)Bsl + wid * 1024);
        GLD_LDS16(Bl + (size_t)(n0 + (f1 >> 2)) * 2560 + k0 + (f1 & 3) * 8,
                  (char*)Bsl + wid * 1024 + 4096);
#pragma unroll
        for (int i = 0; i < 4; ++i) {
            int f = tid + i * 256;
            float4 v = *(const float4*)(A + (size_t)(m0 + (f >> 3)) * 2560
                                        + k0 + (f & 7) * 4);
            bf16x4 hv, lv;
            hv[0] = split2h(v.x); lv[0] = split2l(v.x);
            hv[1] = split2h(v.y); lv[1] = split2l(v.y);
            hv[2] = split2h(v.z); lv[2] = split2l(v.z);
            hv[3] = split2h(v.w); lv[3] = split2l(v.w);
            *(bf16x4*)((char*)Ah + (f >> 3) * 64 + (f & 7) * 8) = hv;
            *(bf16x4*)((char*)Al + (f >> 3) * 64 + (f & 7) * 8) = lv;
        }
        __syncthreads();
        bf16x8 ah[4], al[4], bh[4], bl[4];
#pragma unroll
        for (int m = 0; m < 4; ++m) {
            int off = (wm * 64 + m * 16 + c16) * 32 + g * 8;
            ah[m] = *(const bf16x8*)(Ah + off);
            al[m] = *(const bf16x8*)(Al + off);
        }
#pragma unroll
        for (int n = 0; n < 4; ++n) {
            int off = (wn * 64 + n * 16 + c16) * 32 + g * 8;
            bh[n] = *(const bf16x8*)(Bsh + off);
            bl[n] = *(const bf16x8*)(Bsl + off);
        }
#pragma unroll
        for (int m = 0; m < 4; ++m)
#pragma unroll
            for (int n = 0; n < 4; ++n) {
                acc[m][n] = __builtin_amdgcn_mfma_f32_16x16x32_bf16(ah[m], bh[n], acc[m][n], 0, 0, 0);
                acc[m][n] = __builtin_amdgcn_mfma_f32_16x16x32_bf16(al[m], bh[n], acc[m][n], 0, 0, 0);
                acc[m][n] = __builtin_amdgcn_mfma_f32_16x16x32_bf16(ah[m], bl[n], acc[m][n], 0, 0, 0);
            }
    }

    if (n0 < 2048) {          // q region
#pragma unroll
        for (int m = 0; m < 4; ++m)
#pragma unroll
            for (int n = 0; n < 4; ++n) {
                int col = n0 + wn * 64 + n * 16 + c16;
                int rowb = m0 + wm * 64 + m * 16 + g * 4;
#pragma unroll
                for (int r = 0; r < 4; ++r)
                    qb[(size_t)(rowb + r) * 2048 + col] = (bf16_t)acc[m][n][r];
            }
    } else {                  // k region
#pragma unroll
        for (int m = 0; m < 4; ++m)
#pragma unroll
            for (int n = 0; n < 4; ++n) {
                int col = n0 + wn * 64 + n * 16 + c16 - 2048;
                int rowb = m0 + wm * 64 + m * 16 + g * 4;
#pragma unroll
                for (int r = 0; r < 4; ++r)
                    kb[(size_t)(rowb + r) * 1024 + col] = (bf16_t)acc[m][n][r];
            }
    }
}

// ---------------------------------------------------------------------------
// GEMM1-V: v = hs @ Wv^T (3-pass), epilogue transpose -> vT[1024][4096] bf16.
// ---------------------------------------------------------------------------
__global__ __launch_bounds__(256)
void gemm1v(const float* __restrict__ A, const bf16_t* __restrict__ Bh,
            const bf16_t* __restrict__ Bl, bf16_t* __restrict__ vt)
{
    __shared__ __attribute__((aligned(16))) bf16_t Ah[128 * 32];
    __shared__ __attribute__((aligned(16))) bf16_t Al[128 * 32];
    __shared__ __attribute__((aligned(16))) bf16_t Bsh[128 * 32];
    __shared__ __attribute__((aligned(16))) bf16_t Bsl[128 * 32];
    const int tid = threadIdx.x, lane = tid & 63, wid = tid >> 6;
    const int g = lane >> 4, c16 = lane & 15;
    const int m0 = blockIdx.y * 128, n0 = blockIdx.x * 128;
    const int wm = wid >> 1, wn = wid & 1;

    f32x4 acc[4][4];
#pragma unroll
    for (int i = 0; i < 4; ++i)
#pragma unroll
        for (int j = 0; j < 4; ++j) acc[i][j] = (f32x4)(0.f);

    const int f0 = tid, f1 = tid + 256;
    for (int k0 = 0; k0 < 2560; k0 += 32) {
        __syncthreads();
        GLD_LDS16(Bh + (size_t)(n0 + (f0 >> 2)) * 2560 + k0 + (f0 & 3) * 8,
                  (char*)Bsh + wid * 1024);
        GLD_LDS16(Bh + (size_t)(n0 + (f1 >> 2)) * 2560 + k0 + (f1 & 3) * 8,
                  (char*)Bsh + wid * 1024 + 4096);
        GLD_LDS16(Bl + (size_t)(n0 + (f0 >> 2)) * 2560 + k0 + (f0 & 3) * 8,
                  (char*)Bsl + wid * 1024);
        GLD_LDS16(Bl + (size_t)(n0 + (f1 >> 2)) * 2560 + k0 + (f1 & 3) * 8,
                  (char*)Bsl + wid * 1024 + 4096);
#pragma unroll
        for (int i = 0; i < 4; ++i) {
            int f = tid + i * 256;
            float4 v = *(const float4*)(A + (size_t)(m0 + (f >> 3)) * 2560
                                        + k0 + (f & 7) * 4);
            bf16x4 hv, lv;
            hv[0] = split2h(v.x); lv[0] = split2l(v.x);
            hv[1] = split2h(v.y); lv[1] = split2l(v.y);
            hv[2] = split2h(v.z); lv[2] = split2l(v.z);
            hv[3] = split2h(v.w); lv[3] = split2l(v.w);
            *(bf16x4*)((char*)Ah + (f >> 3) * 64 + (f & 7) * 8) = hv;
            *(bf16x4*)((char*)Al + (f >> 3) * 64 + (f & 7) * 8) = lv;
        }
        __syncthreads();
        bf16x8 ah[4], al[4], bh[4], bl[4];
#pragma unroll
        for (int m = 0; m < 4; ++m) {
            int off = (wm * 64 + m * 16 + c16) * 32 + g * 8;
            ah[m] = *(const bf16x8*)(Ah + off);
            al[m] = *(const bf16x8*)(Al + off);
        }
#pragma unroll
        for (int n = 0; n < 4; ++n) {
            int off = (wn * 64 + n * 16 + c16) * 32 + g * 8;
            bh[n] = *(const bf16x8*)(Bsh + off);
            bl[n] = *(const bf16x8*)(Bsl + off);
        }
#pragma unroll
        for (int m = 0; m < 4; ++m)
#pragma unroll
            for (int n = 0; n < 4; ++n) {
                acc[m][n] = __builtin_amdgcn_mfma_f32_16x16x32_bf16(ah[m], bh[n], acc[m][n], 0, 0, 0);
                acc[m][n] = __builtin_amdgcn_mfma_f32_16x16x32_bf16(al[m], bh[n], acc[m][n], 0, 0, 0);
                acc[m][n] = __builtin_amdgcn_mfma_f32_16x16x32_bf16(ah[m], bl[n], acc[m][n], 0, 0, 0);
            }
    }

#pragma unroll
    for (int m = 0; m < 4; ++m)
#pragma unroll
        for (int n = 0; n < 4; ++n) {
            int d = n0 + wn * 64 + n * 16 + c16;
            int rowb = m0 + wm * 64 + m * 16 + g * 4;
            bf16x4 hv;
#pragma unroll
            for (int r = 0; r < 4; ++r) hv[r] = (bf16_t)acc[m][n][r];
            *(bf16x4*)(vt + (size_t)d * 4096 + rowb) = hv;
        }
}

// ---------------------------------------------------------------------------
// RMSNorm + RoPE on q (in-place, plain bf16 [4096][2048]).
// ---------------------------------------------------------------------------
__global__ __launch_bounds__(256)
void norm_q(bf16_t* __restrict__ qb, const float* __restrict__ w,
            const float* __restrict__ ct, const float* __restrict__ st)
{
    const int s = blockIdx.x, t = threadIdx.x;
    const int h = t >> 5, l = t & 31;
    bf16_t* base = qb + (size_t)s * 2048 + h * 256 + l * 8;
    bf16x8 hv = *(const bf16x8*)base;
    float x[8], ss = 0.f;
#pragma unroll
    for (int j = 0; j < 8; ++j) { x[j] = (float)hv[j]; ss += x[j] * x[j]; }
#pragma unroll
    for (int mk = 1; mk < 32; mk <<= 1) ss += __shfl_xor(ss, mk);
    const float rs = rsqrtf(ss * (1.f / 256.f) + 1e-6f);
    float4 w0 = *(const float4*)(w + l * 8);
    float4 w1 = *(const float4*)(w + l * 8 + 4);
    float wa[8] = { w0.x, w0.y, w0.z, w0.w, w1.x, w1.y, w1.z, w1.w };
    float xn[8];
#pragma unroll
    for (int j = 0; j < 8; ++j) xn[j] = x[j] * rs * (1.f + wa[j]);
    const int d0 = (l * 8) & 127;
    float4 c0 = *(const float4*)(ct + s * 128 + d0);
    float4 c1 = *(const float4*)(ct + s * 128 + d0 + 4);
    float4 s0 = *(const float4*)(st + s * 128 + d0);
    float4 s1 = *(const float4*)(st + s * 128 + d0 + 4);
    float cc[8] = { c0.x, c0.y, c0.z, c0.w, c1.x, c1.y, c1.z, c1.w };
    float sn[8] = { s0.x, s0.y, s0.z, s0.w, s1.x, s1.y, s1.z, s1.w };
    const bool upper = (l >= 16);
    bf16x8 oh;
#pragma unroll
    for (int j = 0; j < 8; ++j) {
        float pn = __shfl_xor(xn[j], 16);
        float rot = upper ? pn : -pn;
        oh[j] = (bf16_t)(xn[j] * cc[j] + rot * sn[j]);
    }
    *(bf16x8*)base = oh;
}

// ---------------------------------------------------------------------------
// RMSNorm + RoPE on k (in-place, plain bf16 [4096][1024]).
// ---------------------------------------------------------------------------
__global__ __launch_bounds__(256)
void norm_k(bf16_t* __restrict__ kb, const float* __restrict__ w,
            const float* __restrict__ ct, const float* __restrict__ st)
{
    const int s = blockIdx.x, t = threadIdx.x;
    const int h = t >> 6, l = t & 63;
    bf16_t* base = kb + (size_t)s * 1024 + h * 256 + l * 4;
    bf16x4 hv = *(const bf16x4*)base;
    float x[4], ss = 0.f;
#pragma unroll
    for (int j = 0; j < 4; ++j) { x[j] = (float)hv[j]; ss += x[j] * x[j]; }
#pragma unroll
    for (int mk = 1; mk < 64; mk <<= 1) ss += __shfl_xor(ss, mk);
    const float rs = rsqrtf(ss * (1.f / 256.f) + 1e-6f);
    float4 w0 = *(const float4*)(w + l * 4);
    float wa[4] = { w0.x, w0.y, w0.z, w0.w };
    float xn[4];
#pragma unroll
    for (int j = 0; j < 4; ++j) xn[j] = x[j] * rs * (1.f + wa[j]);
    const int d0 = (l * 4) & 127;
    float4 c0 = *(const float4*)(ct + s * 128 + d0);
    float4 s0 = *(const float4*)(st + s * 128 + d0);
    float cc[4] = { c0.x, c0.y, c0.z, c0.w };
    float sn[4] = { s0.x, s0.y, s0.z, s0.w };
    const bool upper = (l >= 32);
    bf16x4 oh;
#pragma unroll
    for (int j = 0; j < 4; ++j) {
        float pn = __shfl_xor(xn[j], 32);
        float rot = upper ? pn : -pn;
        oh[j] = (bf16_t)(xn[j] * cc[j] + rot * sn[j]);
    }
    *(bf16x4*)base = oh;
}

// ---------------------------------------------------------------------------
// Sliding-window GQA flash attention, plain bf16 operands (1-pass QK, 1-pass PV).
// grid (64, 8); block 256 (4 waves x 16 q-rows).  Window = 17 k-tiles.
// qt swizzled for load balance.  No __syncthreads: P buffer is per-wave.
// ---------------------------------------------------------------------------
__global__ __launch_bounds__(256)
void attn_fwd3(const bf16_t* __restrict__ qb, const bf16_t* __restrict__ kb,
               const bf16_t* __restrict__ vt, bf16_t* __restrict__ attn)
{
    __shared__ __attribute__((aligned(16))) bf16_t Ph[4][16][72];
    const int tid = threadIdx.x, lane = tid & 63, wid = tid >> 6;
    const int g = lane >> 4, c16 = lane & 15;
    const int bx = blockIdx.x;
    const int qt = (bx & 1) ? (63 - (bx >> 1)) : (bx >> 1);   // load-balance pair
    const int h = blockIdx.y, kvh = h >> 1;
    const int qrow0 = qt * 64 + wid * 16;

    bf16x8 qf[8];
#pragma unroll
    for (int c = 0; c < 8; ++c)
        qf[c] = *(const bf16x8*)(qb + (size_t)(qrow0 + c16) * 2048 + h * 256 + c * 32 + g * 8);

    float mrow[4] = { -1e30f, -1e30f, -1e30f, -1e30f };
    float lrow[4] = { 0.f, 0.f, 0.f, 0.f };
    f32x4 acc[16];
#pragma unroll
    for (int nd = 0; nd < 16; ++nd) acc[nd] = (f32x4)(0.f);

    const int kt_lo = (qt >= 16) ? qt - 16 : 0;
    for (int kt = kt_lo; kt <= qt; ++kt) {
        f32x4 sc[4];
#pragma unroll
        for (int n = 0; n < 4; ++n) sc[n] = (f32x4)(0.f);
#pragma unroll
        for (int n = 0; n < 4; ++n) {
            const bf16_t* kbp = kb + (size_t)(kt * 64 + n * 16 + c16) * 1024
                                + kvh * 256 + g * 8;
#pragma unroll
            for (int c = 0; c < 8; ++c) {
                bf16x8 kf = *(const bf16x8*)(kbp + c * 32);
                sc[n] = __builtin_amdgcn_mfma_f32_16x16x32_bf16(qf[c], kf, sc[n], 0, 0, 0);
            }
        }
        float rm[4] = { -1e30f, -1e30f, -1e30f, -1e30f };
#pragma unroll
        for (int n = 0; n < 4; ++n) {
            const int key = kt * 64 + n * 16 + c16;
#pragma unroll
            for (int r = 0; r < 4; ++r) {
                const int q = qrow0 + g * 4 + r;
                float s = sc[n][r] * 0.0625f;
                bool valid = (key <= q) && (q - key < 1024);
                s = valid ? s : -1e30f;
                sc[n][r] = s;
                rm[r] = fmaxf(rm[r], s);
            }
        }
#pragma unroll
        for (int mk = 1; mk < 16; mk <<= 1)
#pragma unroll
            for (int r = 0; r < 4; ++r) rm[r] = fmaxf(rm[r], __shfl_xor(rm[r], mk));
        float alpha[4], psum[4] = { 0.f, 0.f, 0.f, 0.f };
#pragma unroll
        for (int r = 0; r < 4; ++r) {
            float nm = fmaxf(mrow[r], rm[r]);
            alpha[r] = __expf(mrow[r] - nm);
            mrow[r] = nm;
        }
#pragma unroll
        for (int n = 0; n < 4; ++n)
#pragma unroll
            for (int r = 0; r < 4; ++r) {
                float sv = sc[n][r];
                float pv = (sv > -1e29f) ? __expf(sv - mrow[r]) : 0.f;
                sc[n][r] = pv;
                psum[r] += pv;
            }
#pragma unroll
        for (int mk = 1; mk < 16; mk <<= 1)
#pragma unroll
            for (int r = 0; r < 4; ++r) psum[r] += __shfl_xor(psum[r], mk);
#pragma unroll
        for (int r = 0; r < 4; ++r) lrow[r] = lrow[r] * alpha[r] + psum[r];
#pragma unroll
        for (int nd = 0; nd < 16; ++nd)
#pragma unroll
            for (int r = 0; r < 4; ++r) acc[nd][r] *= alpha[r];

        // P (C-layout) -> per-wave LDS -> A-layout.  Intra-wave only: no barrier.
#pragma unroll
        for (int n = 0; n < 4; ++n)
#pragma unroll
            for (int r = 0; r < 4; ++r)
                Ph[wid][g * 4 + r][n * 16 + c16] = (bf16_t)sc[n][r];
        bf16x8 pa[2];
#pragma unroll
        for (int c = 0; c < 2; ++c)
            pa[c] = *(const bf16x8*)(&Ph[wid][c16][c * 32 + g * 8]);
#pragma unroll
        for (int nd = 0; nd < 16; ++nd) {
            const bf16_t* vb = vt + (size_t)(kvh * 256 + nd * 16 + c16) * 4096
                               + kt * 64 + g * 8;
#pragma unroll
            for (int c = 0; c < 2; ++c) {
                bf16x8 vf = *(const bf16x8*)(vb + c * 32);
                acc[nd] = __builtin_amdgcn_mfma_f32_16x16x32_bf16(pa[c], vf, acc[nd], 0, 0, 0);
            }
        }
    }
    float inv[4];
#pragma unroll
    for (int r = 0; r < 4; ++r) inv[r] = 1.f / lrow[r];
#pragma unroll
    for (int nd = 0; nd < 16; ++nd)
#pragma unroll
        for (int r = 0; r < 4; ++r) {
            int row = qrow0 + g * 4 + r;
            attn[(size_t)row * 2048 + h * 256 + nd * 16 + c16] =
                (bf16_t)(acc[nd][r] * inv[r]);
        }
}

// ---------------------------------------------------------------------------
// GEMM2: out(fp32) = attn(bf16) @ woT(pre-split hi/lo), 2-pass MFMA.
// ---------------------------------------------------------------------------
__global__ __launch_bounds__(256)
void gemm2(const bf16_t* __restrict__ A, const bf16_t* __restrict__ Bh,
           const bf16_t* __restrict__ Bl, float* __restrict__ C)
{
    __shared__ __attribute__((aligned(16))) bf16_t As[128 * 32];
    __shared__ __attribute__((aligned(16))) bf16_t Bsh[128 * 32];
    __shared__ __attribute__((aligned(16))) bf16_t Bsl[128 * 32];
    const int tid = threadIdx.x, lane = tid & 63, wid = tid >> 6;
    const int g = lane >> 4, c16 = lane & 15;
    const int m0 = blockIdx.y * 128, n0 = blockIdx.x * 128;
    const int wm = wid >> 1, wn = wid & 1;

    f32x4 acc[4][4];
#pragma unroll
    for (int i = 0; i < 4; ++i)
#pragma unroll
        for (int j = 0; j < 4; ++j) acc[i][j] = (f32x4)(0.f);

    const int f0 = tid, f1 = tid + 256;
    for (int k0 = 0; k0 < 2048; k0 += 32) {
        __syncthreads();
        GLD_LDS16(A + (size_t)(m0 + (f0 >> 2)) * 2048 + k0 + (f0 & 3) * 8,
                  (char*)As + wid * 1024);
        GLD_LDS16(A + (size_t)(m0 + (f1 >> 2)) * 2048 + k0 + (f1 & 3) * 8,
                  (char*)As + wid * 1024 + 4096);
        GLD_LDS16(Bh + (size_t)(n0 + (f0 >> 2)) * 2048 + k0 + (f0 & 3) * 8,
                  (char*)Bsh + wid * 1024);
        GLD_LDS16(Bh + (size_t)(n0 + (f1 >> 2)) * 2048 + k0 + (f1 & 3) * 8,
                  (char*)Bsh + wid * 1024 + 4096);
        GLD_LDS16(Bl + (size_t)(n0 + (f0 >> 2)) * 2048 + k0 + (f0 & 3) * 8,
                  (char*)Bsl + wid * 1024);
        GLD_LDS16(Bl + (size_t)(n0 + (f1 >> 2)) * 2048 + k0 + (f1 & 3) * 8,
                  (char*)Bsl + wid * 1024 + 4096);
        __syncthreads();
        bf16x8 af[4], bh[4], bl[4];
#pragma unroll
        for (int m = 0; m < 4; ++m)
            af[m] = *(const bf16x8*)(As + (wm * 64 + m * 16 + c16) * 32 + g * 8);
#pragma unroll
        for (int n = 0; n < 4; ++n) {
            int off = (wn * 64 + n * 16 + c16) * 32 + g * 8;
            bh[n] = *(const bf16x8*)(Bsh + off);
            bl[n] = *(const bf16x8*)(Bsl + off);
        }
#pragma unroll
        for (int m = 0; m < 4; ++m)
#pragma unroll
            for (int n = 0; n < 4; ++n) {
                acc[m][n] = __builtin_amdgcn_mfma_f32_16x16x32_bf16(af[m], bh[n], acc[m][n], 0, 0, 0);
                acc[m][n] = __builtin_amdgcn_mfma_f32_16x16x32_bf16(af[m], bl[n], acc[m][n], 0, 0, 0);
            }
    }

#pragma unroll
    for (int m = 0; m < 4; ++m)
#pragma unroll
        for (int n = 0; n < 4; ++n)
#pragma unroll
            for (int r = 0; r < 4; ++r) {
                int row = m0 + wm * 64 + m * 16 + g * 4 + r;
                int col = n0 + wn * 64 + n * 16 + c16;
                C[(size_t)row * 2560 + col] = acc[m][n][r];
            }
}

// ---------------------------------------------------------------------------
// Workspace layout (peak ~79.7 MB; phase-aliased):
//   qb    [0,          16,777,216)   [4096][2048] bf16
//   kb    [16,777,216, 25,165,824)   [4096][1024]
//   vT    [25,165,824, 33,554,432)   [1024][4096]
//   Bqkh  [33,554,432, 49,283,072)   [3072][2560]  (dead after gemm1qk)
//   Bqkl  [49,283,072, 65,011,712)
//   Bvh   [65,011,712, 70,254,592)   [1024][2560]  (dead after gemm1v)
//   Bvl   [70,254,592, 75,497,472)
//   ct    [75,497,472, 77,594,624)   (dead after norms)
//   st    [77,594,624, 79,691,776)
//   attnb [33,554,432, 50,331,648)   [4096][2048]  (over dead Bqkh)
//   woh   [50,331,648, 60,817,408)   [2560][2048]  (over dead Bqkl)
//   wol   [60,817,408, 71,303,168)   (over dead Bqkl/Bvh)
// ---------------------------------------------------------------------------
extern "C" void kernel_launch(void* const* d_in, const int* in_sizes, int n_in,
                              void* d_out, int out_size, void* d_ws, size_t ws_size,
                              hipStream_t stream)
{
    (void)in_sizes; (void)n_in; (void)out_size; (void)ws_size;
    const float* hs  = (const float*)d_in[0];
    const float* wq  = (const float*)d_in[3];
    const float* wk  = (const float*)d_in[4];
    const float* wv  = (const float*)d_in[5];
    const float* wo  = (const float*)d_in[6];
    const float* qnw = (const float*)d_in[7];
    const float* knw = (const float*)d_in[8];

    char* ws = (char*)d_ws;
    bf16_t* qb    = (bf16_t*)(ws);
    bf16_t* kb    = (bf16_t*)(ws + 16777216);
    bf16_t* vt    = (bf16_t*)(ws + 25165824);
    bf16_t* Bqkh  = (bf16_t*)(ws + 33554432);
    bf16_t* Bqkl  = (bf16_t*)(ws + 49283072);
    bf16_t* Bvh   = (bf16_t*)(ws + 65011712);
    bf16_t* Bvl   = (bf16_t*)(ws + 70254592);
    float*  ct    = (float*)(ws + 75497472);
    float*  st    = (float*)(ws + 77594624);
    bf16_t* attnb = (bf16_t*)(ws + 33554432);
    bf16_t* woh   = (bf16_t*)(ws + 50331648);
    bf16_t* wol   = (bf16_t*)(ws + 60817408);

    // 1. wq,wk -> Bqk panels [3072][2560] hi/lo
    transpose_split<<<dim3(32, 40), 256, 0, stream>>>(wq, Bqkh, Bqkl, 2560, 2048);
    transpose_split<<<dim3(16, 40), 256, 0, stream>>>(wk, Bqkh + (size_t)2048 * 2560,
                                                      Bqkl + (size_t)2048 * 2560, 2560, 1024);
    // 2. q/k projection (writes qb, kb)
    gemm1qk<<<dim3(24, 32), 256, 0, stream>>>(hs, Bqkh, Bqkl, qb, kb);

    // 3. wv -> Bv panels
    transpose_split<<<dim3(16, 40), 256, 0, stream>>>(wv, Bvh, Bvl, 2560, 1024);
    // 4. v projection -> vT
    gemm1v<<<dim3(8, 32), 256, 0, stream>>>(hs, Bvh, Bvl, vt);

    // 5. RoPE tables + norms
    rope_tables<<<2048, 256, 0, stream>>>(ct, st);
    norm_q<<<4096, 256, 0, stream>>>(qb, qnw, ct, st);
    norm_k<<<4096, 256, 0, stream>>>(kb, knw, ct, st);

    // 6. attention (writes attnb over dead Bqkh)
    attn_fwd3<<<dim3(64, 8), 256, 0, stream>>>(qb, kb, vt, attnb);

    // 7. wo -> woT panels (over dead Bqkl), then output projection
    transpose_split<<<dim3(40, 32), 256, 0, stream>>>(wo, woh, wol, 2048, 2560);
    gemm2<<<dim3(20, 32), 256, 0, stream>>>(attnb, woh, wol, (float*)d_out);
}

// Round 7
// 674.149 us; speedup vs baseline: 1.7673x; 1.3615x over previous
//
#include <hip/hip_runtime.h>
#include <stdint.h>
#include <math.h>

typedef __bf16 bf16_t;
typedef __bf16 bf16x8 __attribute__((ext_vector_type(8)));
typedef __bf16 bf16x4 __attribute__((ext_vector_type(4)));
typedef float f32x4 __attribute__((ext_vector_type(4)));

#define GLD_LDS16(g, l)                                             \
    __builtin_amdgcn_global_load_lds(                               \
        (const __attribute__((address_space(1))) void*)(g),         \
        (__attribute__((address_space(3))) void*)(l), 16, 0, 0)

__device__ __forceinline__ bf16_t split2h(float x) { return (bf16_t)x; }
__device__ __forceinline__ bf16_t split2l(float x)
{
    return (bf16_t)(x - (float)(bf16_t)x);
}

// ---------------------------------------------------------------------------
// transpose + split-convert: in [R][C] fp32 -> oh/ol [C][R] bf16 hi/lo
// ---------------------------------------------------------------------------
__global__ __launch_bounds__(256)
void transpose_split(const float* __restrict__ in, bf16_t* __restrict__ oh,
                     bf16_t* __restrict__ ol, int R, int C)
{
    __shared__ float t[64][65];
    const int r0 = blockIdx.y * 64, c0 = blockIdx.x * 64;
#pragma unroll
    for (int i = 0; i < 16; ++i) {
        int f = threadIdx.x + i * 256;
        int r = f >> 6, c = f & 63;
        t[r][c] = in[(size_t)(r0 + r) * C + c0 + c];
    }
    __syncthreads();
#pragma unroll
    for (int i = 0; i < 16; ++i) {
        int f = threadIdx.x + i * 256;
        int r = f >> 6, c = f & 63;
        float x = t[c][r];
        oh[(size_t)(c0 + r) * R + r0 + c] = split2h(x);
        ol[(size_t)(c0 + r) * R + r0 + c] = split2l(x);
    }
}

// ---------------------------------------------------------------------------
// RoPE cos/sin tables via fp64 (exact angle reduction)
// ---------------------------------------------------------------------------
__global__ __launch_bounds__(256)
void rope_tables(float* __restrict__ ct, float* __restrict__ st)
{
    int t = blockIdx.x * 256 + threadIdx.x;   // 4096*128
    int s = t >> 7, j = t & 127;
    double inv = exp2((double)j * (-13.28771237954945 / 128.0)); // log2(10000)
    double ang = fmod((double)s * inv, 6.283185307179586476925286766559);
    ct[t] = (float)cos(ang);
    st[t] = (float)sin(ang);
}

// ---------------------------------------------------------------------------
// GEMM1-QK: q/k = hs(fp32, split in-kernel) @ Wqk^T(pre-split hi/lo), 3-pass.
// Outputs plain bf16: qb[4096][2048], kb[4096][1024].
// ---------------------------------------------------------------------------
__global__ __launch_bounds__(256)
void gemm1qk(const float* __restrict__ A, const bf16_t* __restrict__ Bh,
             const bf16_t* __restrict__ Bl, bf16_t* __restrict__ qb,
             bf16_t* __restrict__ kb)
{
    __shared__ __attribute__((aligned(16))) bf16_t Ah[128 * 32];
    __shared__ __attribute__((aligned(16))) bf16_t Al[128 * 32];
    __shared__ __attribute__((aligned(16))) bf16_t Bsh[128 * 32];
    __shared__ __attribute__((aligned(16))) bf16_t Bsl[128 * 32];
    const int tid = threadIdx.x, lane = tid & 63, wid = tid >> 6;
    const int g = lane >> 4, c16 = lane & 15;
    const int m0 = blockIdx.y * 128, n0 = blockIdx.x * 128;
    const int wm = wid >> 1, wn = wid & 1;

    f32x4 acc[4][4];
#pragma unroll
    for (int i = 0; i < 4; ++i)
#pragma unroll
        for (int j = 0; j < 4; ++j) acc[i][j] = (f32x4)(0.f);

    const int f0 = tid, f1 = tid + 256;
    for (int k0 = 0; k0 < 2560; k0 += 32) {
        __syncthreads();
        GLD_LDS16(Bh + (size_t)(n0 + (f0 >> 2)) * 2560 + k0 + (f0 & 3) * 8,
                  (char*)Bsh + wid * 1024);
        GLD_LDS16(Bh + (size_t)(n0 + (f1 >> 2)) * 2560 + k0 + (f1 & 3) * 8,
                  (char*)Bsh + wid * 1024 + 4096);
        GLD_LDS16(Bl + (size_t)(n0 + (f0 >> 2)) * 2560 + k0 + (f0 & 3) * 8,
                  (char*)Bsl + wid * 1024);
        GLD_LDS16(Bl + (size_t)(n0 + (f1 >> 2)) * 2560 + k0 + (f1 & 3) * 8,
                  (char*)Bsl + wid * 1024 + 4096);
#pragma unroll
        for (int i = 0; i < 4; ++i) {
            int f = tid + i * 256;
            float4 v = *(const float4*)(A + (size_t)(m0 + (f >> 3)) * 2560
                                        + k0 + (f & 7) * 4);
            bf16x4 hv, lv;
            hv[0] = split2h(v.x); lv[0] = split2l(v.x);
            hv[1] = split2h(v.y); lv[1] = split2l(v.y);
            hv[2] = split2h(v.z); lv[2] = split2l(v.z);
            hv[3] = split2h(v.w); lv[3] = split2l(v.w);
            *(bf16x4*)((char*)Ah + (f >> 3) * 64 + (f & 7) * 8) = hv;
            *(bf16x4*)((char*)Al + (f >> 3) * 64 + (f & 7) * 8) = lv;
        }
        __syncthreads();
        bf16x8 ah[4], al[4], bh[4], bl[4];
#pragma unroll
        for (int m = 0; m < 4; ++m) {
            int off = (wm * 64 + m * 16 + c16) * 32 + g * 8;
            ah[m] = *(const bf16x8*)(Ah + off);
            al[m] = *(const bf16x8*)(Al + off);
        }
#pragma unroll
        for (int n = 0; n < 4; ++n) {
            int off = (wn * 64 + n * 16 + c16) * 32 + g * 8;
            bh[n] = *(const bf16x8*)(Bsh + off);
            bl[n] = *(const bf16x8*)(Bsl + off);
        }
#pragma unroll
        for (int m = 0; m < 4; ++m)
#pragma unroll
            for (int n = 0; n < 4; ++n) {
                acc[m][n] = __builtin_amdgcn_mfma_f32_16x16x32_bf16(ah[m], bh[n], acc[m][n], 0, 0, 0);
                acc[m][n] = __builtin_amdgcn_mfma_f32_16x16x32_bf16(al[m], bh[n], acc[m][n], 0, 0, 0);
                acc[m][n] = __builtin_amdgcn_mfma_f32_16x16x32_bf16(ah[m], bl[n], acc[m][n], 0, 0, 0);
            }
    }

    if (n0 < 2048) {          // q region
#pragma unroll
        for (int m = 0; m < 4; ++m)
#pragma unroll
            for (int n = 0; n < 4; ++n) {
                int col = n0 + wn * 64 + n * 16 + c16;
                int rowb = m0 + wm * 64 + m * 16 + g * 4;
#pragma unroll
                for (int r = 0; r < 4; ++r)
                    qb[(size_t)(rowb + r) * 2048 + col] = (bf16_t)acc[m][n][r];
            }
    } else {                  // k region
#pragma unroll
        for (int m = 0; m < 4; ++m)
#pragma unroll
            for (int n = 0; n < 4; ++n) {
                int col = n0 + wn * 64 + n * 16 + c16 - 2048;
                int rowb = m0 + wm * 64 + m * 16 + g * 4;
#pragma unroll
                for (int r = 0; r < 4; ++r)
                    kb[(size_t)(rowb + r) * 1024 + col] = (bf16_t)acc[m][n][r];
            }
    }
}

// ---------------------------------------------------------------------------
// GEMM1-V: v = hs @ Wv^T (3-pass), epilogue transpose -> vT[1024][4096] bf16.
// ---------------------------------------------------------------------------
__global__ __launch_bounds__(256)
void gemm1v(const float* __restrict__ A, const bf16_t* __restrict__ Bh,
            const bf16_t* __restrict__ Bl, bf16_t* __restrict__ vt)
{
    __shared__ __attribute__((aligned(16))) bf16_t Ah[128 * 32];
    __shared__ __attribute__((aligned(16))) bf16_t Al[128 * 32];
    __shared__ __attribute__((aligned(16))) bf16_t Bsh[128 * 32];
    __shared__ __attribute__((aligned(16))) bf16_t Bsl[128 * 32];
    const int tid = threadIdx.x, lane = tid & 63, wid = tid >> 6;
    const int g = lane >> 4, c16 = lane & 15;
    const int m0 = blockIdx.y * 128, n0 = blockIdx.x * 128;
    const int wm = wid >> 1, wn = wid & 1;

    f32x4 acc[4][4];
#pragma unroll
    for (int i = 0; i < 4; ++i)
#pragma unroll
        for (int j = 0; j < 4; ++j) acc[i][j] = (f32x4)(0.f);

    const int f0 = tid, f1 = tid + 256;
    for (int k0 = 0; k0 < 2560; k0 += 32) {
        __syncthreads();
        GLD_LDS16(Bh + (size_t)(n0 + (f0 >> 2)) * 2560 + k0 + (f0 & 3) * 8,
                  (char*)Bsh + wid * 1024);
        GLD_LDS16(Bh + (size_t)(n0 + (f1 >> 2)) * 2560 + k0 + (f1 & 3) * 8,
                  (char*)Bsh + wid * 1024 + 4096);
        GLD_LDS16(Bl + (size_t)(n0 + (f0 >> 2)) * 2560 + k0 + (f0 & 3) * 8,
                  (char*)Bsl + wid * 1024);
        GLD_LDS16(Bl + (size_t)(n0 + (f1 >> 2)) * 2560 + k0 + (f1 & 3) * 8,
                  (char*)Bsl + wid * 1024 + 4096);
#pragma unroll
        for (int i = 0; i < 4; ++i) {
            int f = tid + i * 256;
            float4 v = *(const float4*)(A + (size_t)(m0 + (f >> 3)) * 2560
                                        + k0 + (f & 7) * 4);
            bf16x4 hv, lv;
            hv[0] = split2h(v.x); lv[0] = split2l(v.x);
            hv[1] = split2h(v.y); lv[1] = split2l(v.y);
            hv[2] = split2h(v.z); lv[2] = split2l(v.z);
            hv[3] = split2h(v.w); lv[3] = split2l(v.w);
            *(bf16x4*)((char*)Ah + (f >> 3) * 64 + (f & 7) * 8) = hv;
            *(bf16x4*)((char*)Al + (f >> 3) * 64 + (f & 7) * 8) = lv;
        }
        __syncthreads();
        bf16x8 ah[4], al[4], bh[4], bl[4];
#pragma unroll
        for (int m = 0; m < 4; ++m) {
            int off = (wm * 64 + m * 16 + c16) * 32 + g * 8;
            ah[m] = *(const bf16x8*)(Ah + off);
            al[m] = *(const bf16x8*)(Al + off);
        }
#pragma unroll
        for (int n = 0; n < 4; ++n) {
            int off = (wn * 64 + n * 16 + c16) * 32 + g * 8;
            bh[n] = *(const bf16x8*)(Bsh + off);
            bl[n] = *(const bf16x8*)(Bsl + off);
        }
#pragma unroll
        for (int m = 0; m < 4; ++m)
#pragma unroll
            for (int n = 0; n < 4; ++n) {
                acc[m][n] = __builtin_amdgcn_mfma_f32_16x16x32_bf16(ah[m], bh[n], acc[m][n], 0, 0, 0);
                acc[m][n] = __builtin_amdgcn_mfma_f32_16x16x32_bf16(al[m], bh[n], acc[m][n], 0, 0, 0);
                acc[m][n] = __builtin_amdgcn_mfma_f32_16x16x32_bf16(ah[m], bl[n], acc[m][n], 0, 0, 0);
            }
    }

#pragma unroll
    for (int m = 0; m < 4; ++m)
#pragma unroll
        for (int n = 0; n < 4; ++n) {
            int d = n0 + wn * 64 + n * 16 + c16;
            int rowb = m0 + wm * 64 + m * 16 + g * 4;
            bf16x4 hv;
#pragma unroll
            for (int r = 0; r < 4; ++r) hv[r] = (bf16_t)acc[m][n][r];
            *(bf16x4*)(vt + (size_t)d * 4096 + rowb) = hv;
        }
}

// ---------------------------------------------------------------------------
// RMSNorm + RoPE on q (in-place, plain bf16 [4096][2048]).
// ---------------------------------------------------------------------------
__global__ __launch_bounds__(256)
void norm_q(bf16_t* __restrict__ qb, const float* __restrict__ w,
            const float* __restrict__ ct, const float* __restrict__ st)
{
    const int s = blockIdx.x, t = threadIdx.x;
    const int h = t >> 5, l = t & 31;
    bf16_t* base = qb + (size_t)s * 2048 + h * 256 + l * 8;
    bf16x8 hv = *(const bf16x8*)base;
    float x[8], ss = 0.f;
#pragma unroll
    for (int j = 0; j < 8; ++j) { x[j] = (float)hv[j]; ss += x[j] * x[j]; }
#pragma unroll
    for (int mk = 1; mk < 32; mk <<= 1) ss += __shfl_xor(ss, mk);
    const float rs = rsqrtf(ss * (1.f / 256.f) + 1e-6f);
    float4 w0 = *(const float4*)(w + l * 8);
    float4 w1 = *(const float4*)(w + l * 8 + 4);
    float wa[8] = { w0.x, w0.y, w0.z, w0.w, w1.x, w1.y, w1.z, w1.w };
    float xn[8];
#pragma unroll
    for (int j = 0; j < 8; ++j) xn[j] = x[j] * rs * (1.f + wa[j]);
    const int d0 = (l * 8) & 127;
    float4 c0 = *(const float4*)(ct + s * 128 + d0);
    float4 c1 = *(const float4*)(ct + s * 128 + d0 + 4);
    float4 s0 = *(const float4*)(st + s * 128 + d0);
    float4 s1 = *(const float4*)(st + s * 128 + d0 + 4);
    float cc[8] = { c0.x, c0.y, c0.z, c0.w, c1.x, c1.y, c1.z, c1.w };
    float sn[8] = { s0.x, s0.y, s0.z, s0.w, s1.x, s1.y, s1.z, s1.w };
    const bool upper = (l >= 16);
    bf16x8 oh;
#pragma unroll
    for (int j = 0; j < 8; ++j) {
        float pn = __shfl_xor(xn[j], 16);
        float rot = upper ? pn : -pn;
        oh[j] = (bf16_t)(xn[j] * cc[j] + rot * sn[j]);
    }
    *(bf16x8*)base = oh;
}

// ---------------------------------------------------------------------------
// RMSNorm + RoPE on k (in-place, plain bf16 [4096][1024]).
// ---------------------------------------------------------------------------
__global__ __launch_bounds__(256)
void norm_k(bf16_t* __restrict__ kb, const float* __restrict__ w,
            const float* __restrict__ ct, const float* __restrict__ st)
{
    const int s = blockIdx.x, t = threadIdx.x;
    const int h = t >> 6, l = t & 63;
    bf16_t* base = kb + (size_t)s * 1024 + h * 256 + l * 4;
    bf16x4 hv = *(const bf16x4*)base;
    float x[4], ss = 0.f;
#pragma unroll
    for (int j = 0; j < 4; ++j) { x[j] = (float)hv[j]; ss += x[j] * x[j]; }
#pragma unroll
    for (int mk = 1; mk < 64; mk <<= 1) ss += __shfl_xor(ss, mk);
    const float rs = rsqrtf(ss * (1.f / 256.f) + 1e-6f);
    float4 w0 = *(const float4*)(w + l * 4);
    float wa[4] = { w0.x, w0.y, w0.z, w0.w };
    float xn[4];
#pragma unroll
    for (int j = 0; j < 4; ++j) xn[j] = x[j] * rs * (1.f + wa[j]);
    const int d0 = (l * 4) & 127;
    float4 c0 = *(const float4*)(ct + s * 128 + d0);
    float4 s0 = *(const float4*)(st + s * 128 + d0);
    float cc[4] = { c0.x, c0.y, c0.z, c0.w };
    float sn[4] = { s0.x, s0.y, s0.z, s0.w };
    const bool upper = (l >= 32);
    bf16x4 oh;
#pragma unroll
    for (int j = 0; j < 4; ++j) {
        float pn = __shfl_xor(xn[j], 32);
        float rot = upper ? pn : -pn;
        oh[j] = (bf16_t)(xn[j] * cc[j] + rot * sn[j]);
    }
    *(bf16x4*)base = oh;
}

// ---------------------------------------------------------------------------
// Sliding-window GQA flash attention with async double-buffered LDS staging.
// grid (64, 8); block 256 (4 waves x 16 q-rows).  KVBLK = 32 keys/tile.
// K tile: 32 keys x 512 B (XOR-swizzled blk^(row&7), pre-swizzled global src)
// V tile: 256 d   x  64 B (XOR-swizzled blk^(row&3))
// LDS: 2 x (16K + 16K) dbuf + P = ~69 KB -> 2 blocks/CU.
// ---------------------------------------------------------------------------
__global__ __launch_bounds__(256)
void attn_fwd4(const bf16_t* __restrict__ qb, const bf16_t* __restrict__ kb,
               const bf16_t* __restrict__ vt, bf16_t* __restrict__ attn)
{
    __shared__ __attribute__((aligned(16))) char smem[2 * 32768];
    __shared__ __attribute__((aligned(16))) bf16_t P[4][16][40];
    const int tid = threadIdx.x, lane = tid & 63, wid = tid >> 6;
    const int g = lane >> 4, c16 = lane & 15;
    const int bx = blockIdx.x;
    const int qt = (bx & 1) ? (63 - (bx >> 1)) : (bx >> 1);   // load-balance pair
    const int h = blockIdx.y, kvh = h >> 1;
    const int qrow0 = qt * 64 + wid * 16;

    bf16x8 qf[8];
#pragma unroll
    for (int c = 0; c < 8; ++c)
        qf[c] = *(const bf16x8*)(qb + (size_t)(qrow0 + c16) * 2048 + h * 256 + c * 32 + g * 8);

    float mrow[4] = { -1e30f, -1e30f, -1e30f, -1e30f };
    float lrow[4] = { 0.f, 0.f, 0.f, 0.f };
    f32x4 acc[16];
#pragma unroll
    for (int nd = 0; nd < 16; ++nd) acc[nd] = (f32x4)(0.f);

    // async stage of K+V tile kt into buffer buf (src pre-swizzled, dest linear)
    auto STAGE = [&](int buf, int kt) {
        char* Kd = smem + buf * 32768;
        char* Vd = smem + buf * 32768 + 16384;
        const char* ksrc = (const char*)kb + (size_t)kt * 32 * 2048 + (size_t)kvh * 512;
        const char* vsrc = (const char*)vt + (size_t)kvh * 256 * 8192 + (size_t)kt * 64;
#pragma unroll
        for (int j = 0; j < 4; ++j) {
            int c_ = j * 256 + tid;
            int row = c_ >> 5, b = c_ & 31;
            GLD_LDS16(ksrc + (size_t)row * 2048 + ((b ^ (row & 7)) << 4),
                      Kd + (j * 256 + wid * 64) * 16);
        }
#pragma unroll
        for (int j = 0; j < 4; ++j) {
            int c_ = j * 256 + tid;
            int row = c_ >> 2, b = c_ & 3;
            GLD_LDS16(vsrc + (size_t)row * 8192 + ((b ^ (row & 3)) << 4),
                      Vd + (j * 256 + wid * 64) * 16);
        }
    };

    const int ktb_lo = (qt >= 16) ? 2 * qt - 32 : 0;
    const int ktb_hi = 2 * qt + 1;
    int cur = 0;
    STAGE(0, ktb_lo);
    __syncthreads();

    const int swk = (c16 & 7) << 4;
    const int swv = (g ^ (c16 & 3)) << 4;

    for (int kt = ktb_lo; kt <= ktb_hi; ++kt) {
        if (kt < ktb_hi) STAGE(cur ^ 1, kt + 1);

        // wave-uniform relevance: any key in [kt*32, kt*32+31] hits
        // any row window [qrow0-1023, qrow0+15]?
        if (kt * 32 <= qrow0 + 15 && kt * 32 + 31 >= qrow0 - 1023) {
            const char* Kc = smem + cur * 32768;
            const char* Vc = smem + cur * 32768 + 16384;

            f32x4 sc[2];
#pragma unroll
            for (int n = 0; n < 2; ++n) sc[n] = (f32x4)(0.f);
#pragma unroll
            for (int n = 0; n < 2; ++n) {
                const char* kr = Kc + (n * 16 + c16) * 512;
#pragma unroll
                for (int c = 0; c < 8; ++c) {
                    bf16x8 kf = *(const bf16x8*)(kr + ((((c * 4 + g) << 4) ^ swk)));
                    sc[n] = __builtin_amdgcn_mfma_f32_16x16x32_bf16(qf[c], kf, sc[n], 0, 0, 0);
                }
            }
            float rm[4] = { -1e30f, -1e30f, -1e30f, -1e30f };
#pragma unroll
            for (int n = 0; n < 2; ++n) {
                const int key = kt * 32 + n * 16 + c16;
#pragma unroll
                for (int r = 0; r < 4; ++r) {
                    const int q = qrow0 + g * 4 + r;
                    float s = sc[n][r] * 0.0625f;
                    bool valid = (key <= q) && (q - key < 1024);
                    s = valid ? s : -1e30f;
                    sc[n][r] = s;
                    rm[r] = fmaxf(rm[r], s);
                }
            }
#pragma unroll
            for (int mk = 1; mk < 16; mk <<= 1)
#pragma unroll
                for (int r = 0; r < 4; ++r) rm[r] = fmaxf(rm[r], __shfl_xor(rm[r], mk));
            float alpha[4], psum[4] = { 0.f, 0.f, 0.f, 0.f };
#pragma unroll
            for (int r = 0; r < 4; ++r) {
                float nm = fmaxf(mrow[r], rm[r]);
                alpha[r] = __expf(mrow[r] - nm);
                mrow[r] = nm;
            }
#pragma unroll
            for (int n = 0; n < 2; ++n)
#pragma unroll
                for (int r = 0; r < 4; ++r) {
                    float sv = sc[n][r];
                    float pv = (sv > -1e29f) ? __expf(sv - mrow[r]) : 0.f;
                    sc[n][r] = pv;
                    psum[r] += pv;
                }
#pragma unroll
            for (int mk = 1; mk < 16; mk <<= 1)
#pragma unroll
                for (int r = 0; r < 4; ++r) psum[r] += __shfl_xor(psum[r], mk);
#pragma unroll
            for (int r = 0; r < 4; ++r) lrow[r] = lrow[r] * alpha[r] + psum[r];
#pragma unroll
            for (int nd = 0; nd < 16; ++nd)
#pragma unroll
                for (int r = 0; r < 4; ++r) acc[nd][r] *= alpha[r];

            // P (C-layout) -> per-wave LDS -> A-layout (intra-wave, no barrier)
#pragma unroll
            for (int n = 0; n < 2; ++n)
#pragma unroll
                for (int r = 0; r < 4; ++r)
                    P[wid][g * 4 + r][n * 16 + c16] = (bf16_t)sc[n][r];
            bf16x8 pa = *(const bf16x8*)(&P[wid][c16][g * 8]);
#pragma unroll
            for (int nd = 0; nd < 16; ++nd) {
                bf16x8 vf = *(const bf16x8*)(Vc + (nd * 16 + c16) * 64 + swv);
                acc[nd] = __builtin_amdgcn_mfma_f32_16x16x32_bf16(pa, vf, acc[nd], 0, 0, 0);
            }
        }
        __syncthreads();   // drains stage vmcnt + all waves done with buffer cur
        cur ^= 1;
    }

    float inv[4];
#pragma unroll
    for (int r = 0; r < 4; ++r) inv[r] = 1.f / lrow[r];
#pragma unroll
    for (int nd = 0; nd < 16; ++nd)
#pragma unroll
        for (int r = 0; r < 4; ++r) {
            int row = qrow0 + g * 4 + r;
            attn[(size_t)row * 2048 + h * 256 + nd * 16 + c16] =
                (bf16_t)(acc[nd][r] * inv[r]);
        }
}

// ---------------------------------------------------------------------------
// GEMM2: out(fp32) = attn(bf16) @ woT(pre-split hi/lo), 2-pass MFMA.
// ---------------------------------------------------------------------------
__global__ __launch_bounds__(256)
void gemm2(const bf16_t* __restrict__ A, const bf16_t* __restrict__ Bh,
           const bf16_t* __restrict__ Bl, float* __restrict__ C)
{
    __shared__ __attribute__((aligned(16))) bf16_t As[128 * 32];
    __shared__ __attribute__((aligned(16))) bf16_t Bsh[128 * 32];
    __shared__ __attribute__((aligned(16))) bf16_t Bsl[128 * 32];
    const int tid = threadIdx.x, lane = tid & 63, wid = tid >> 6;
    const int g = lane >> 4, c16 = lane & 15;
    const int m0 = blockIdx.y * 128, n0 = blockIdx.x * 128;
    const int wm = wid >> 1, wn = wid & 1;

    f32x4 acc[4][4];
#pragma unroll
    for (int i = 0; i < 4; ++i)
#pragma unroll
        for (int j = 0; j < 4; ++j) acc[i][j] = (f32x4)(0.f);

    const int f0 = tid, f1 = tid + 256;
    for (int k0 = 0; k0 < 2048; k0 += 32) {
        __syncthreads();
        GLD_LDS16(A + (size_t)(m0 + (f0 >> 2)) * 2048 + k0 + (f0 & 3) * 8,
                  (char*)As + wid * 1024);
        GLD_LDS16(A + (size_t)(m0 + (f1 >> 2)) * 2048 + k0 + (f1 & 3) * 8,
                  (char*)As + wid * 1024 + 4096);
        GLD_LDS16(Bh + (size_t)(n0 + (f0 >> 2)) * 2048 + k0 + (f0 & 3) * 8,
                  (char*)Bsh + wid * 1024);
        GLD_LDS16(Bh + (size_t)(n0 + (f1 >> 2)) * 2048 + k0 + (f1 & 3) * 8,
                  (char*)Bsh + wid * 1024 + 4096);
        GLD_LDS16(Bl + (size_t)(n0 + (f0 >> 2)) * 2048 + k0 + (f0 & 3) * 8,
                  (char*)Bsl + wid * 1024);
        GLD_LDS16(Bl + (size_t)(n0 + (f1 >> 2)) * 2048 + k0 + (f1 & 3) * 8,
                  (char*)Bsl + wid * 1024 + 4096);
        __syncthreads();
        bf16x8 af[4], bh[4], bl[4];
#pragma unroll
        for (int m = 0; m < 4; ++m)
            af[m] = *(const bf16x8*)(As + (wm * 64 + m * 16 + c16) * 32 + g * 8);
#pragma unroll
        for (int n = 0; n < 4; ++n) {
            int off = (wn * 64 + n * 16 + c16) * 32 + g * 8;
            bh[n] = *(const bf16x8*)(Bsh + off);
            bl[n] = *(const bf16x8*)(Bsl + off);
        }
#pragma unroll
        for (int m = 0; m < 4; ++m)
#pragma unroll
            for (int n = 0; n < 4; ++n) {
                acc[m][n] = __builtin_amdgcn_mfma_f32_16x16x32_bf16(af[m], bh[n], acc[m][n], 0, 0, 0);
                acc[m][n] = __builtin_amdgcn_mfma_f32_16x16x32_bf16(af[m], bl[n], acc[m][n], 0, 0, 0);
            }
    }

#pragma unroll
    for (int m = 0; m < 4; ++m)
#pragma unroll
        for (int n = 0; n < 4; ++n)
#pragma unroll
            for (int r = 0; r < 4; ++r) {
                int row = m0 + wm * 64 + m * 16 + g * 4 + r;
                int col = n0 + wn * 64 + n * 16 + c16;
                C[(size_t)row * 2560 + col] = acc[m][n][r];
            }
}

// ---------------------------------------------------------------------------
// Workspace layout (peak ~79.7 MB; phase-aliased):
//   qb    [0,          16,777,216)   [4096][2048] bf16
//   kb    [16,777,216, 25,165,824)   [4096][1024]
//   vT    [25,165,824, 33,554,432)   [1024][4096]
//   Bqkh  [33,554,432, 49,283,072)   [3072][2560]  (dead after gemm1qk)
//   Bqkl  [49,283,072, 65,011,712)
//   Bvh   [65,011,712, 70,254,592)   [1024][2560]  (dead after gemm1v)
//   Bvl   [70,254,592, 75,497,472)
//   ct    [75,497,472, 77,594,624)   (dead after norms)
//   st    [77,594,624, 79,691,776)
//   attnb [33,554,432, 50,331,648)   [4096][2048]  (over dead Bqkh)
//   woh   [50,331,648, 60,817,408)   [2560][2048]  (over dead Bqkl)
//   wol   [60,817,408, 71,303,168)   (over dead Bqkl/Bvh)
// ---------------------------------------------------------------------------
extern "C" void kernel_launch(void* const* d_in, const int* in_sizes, int n_in,
                              void* d_out, int out_size, void* d_ws, size_t ws_size,
                              hipStream_t stream)
{
    (void)in_sizes; (void)n_in; (void)out_size; (void)ws_size;
    const float* hs  = (const float*)d_in[0];
    const float* wq  = (const float*)d_in[3];
    const float* wk  = (const float*)d_in[4];
    const float* wv  = (const float*)d_in[5];
    const float* wo  = (const float*)d_in[6];
    const float* qnw = (const float*)d_in[7];
    const float* knw = (const float*)d_in[8];

    char* ws = (char*)d_ws;
    bf16_t* qb    = (bf16_t*)(ws);
    bf16_t* kb    = (bf16_t*)(ws + 16777216);
    bf16_t* vt    = (bf16_t*)(ws + 25165824);
    bf16_t* Bqkh  = (bf16_t*)(ws + 33554432);
    bf16_t* Bqkl  = (bf16_t*)(ws + 49283072);
    bf16_t* Bvh   = (bf16_t*)(ws + 65011712);
    bf16_t* Bvl   = (bf16_t*)(ws + 70254592);
    float*  ct    = (float*)(ws + 75497472);
    float*  st    = (float*)(ws + 77594624);
    bf16_t* attnb = (bf16_t*)(ws + 33554432);
    bf16_t* woh   = (bf16_t*)(ws + 50331648);
    bf16_t* wol   = (bf16_t*)(ws + 60817408);

    // 1. wq,wk -> Bqk panels [3072][2560] hi/lo
    transpose_split<<<dim3(32, 40), 256, 0, stream>>>(wq, Bqkh, Bqkl, 2560, 2048);
    transpose_split<<<dim3(16, 40), 256, 0, stream>>>(wk, Bqkh + (size_t)2048 * 2560,
                                                      Bqkl + (size_t)2048 * 2560, 2560, 1024);
    // 2. q/k projection (writes qb, kb)
    gemm1qk<<<dim3(24, 32), 256, 0, stream>>>(hs, Bqkh, Bqkl, qb, kb);

    // 3. wv -> Bv panels
    transpose_split<<<dim3(16, 40), 256, 0, stream>>>(wv, Bvh, Bvl, 2560, 1024);
    // 4. v projection -> vT
    gemm1v<<<dim3(8, 32), 256, 0, stream>>>(hs, Bvh, Bvl, vt);

    // 5. RoPE tables + norms
    rope_tables<<<2048, 256, 0, stream>>>(ct, st);
    norm_q<<<4096, 256, 0, stream>>>(qb, qnw, ct, st);
    norm_k<<<4096, 256, 0, stream>>>(kb, knw, ct, st);

    // 6. attention (writes attnb over dead Bqkh)
    attn_fwd4<<<dim3(64, 8), 256, 0, stream>>>(qb, kb, vt, attnb);

    // 7. wo -> woT panels (over dead Bqkl), then output projection
    transpose_split<<<dim3(40, 32), 256, 0, stream>>>(wo, woh, wol, 2048, 2560);
    gemm2<<<dim3(20, 32), 256, 0, stream>>>(attnb, woh, wol, (float*)d_out);
}

// Round 8
// 514.013 us; speedup vs baseline: 2.3179x; 1.3115x over previous
//
#include <hip/hip_runtime.h>
#include <stdint.h>
#include <math.h>

typedef __bf16 bf16_t;
typedef __bf16 bf16x8 __attribute__((ext_vector_type(8)));
typedef __bf16 bf16x4 __attribute__((ext_vector_type(4)));
typedef float f32x4 __attribute__((ext_vector_type(4)));

#define GLD_LDS16(g, l)                                             \
    __builtin_amdgcn_global_load_lds(                               \
        (const __attribute__((address_space(1))) void*)(g),         \
        (__attribute__((address_space(3))) void*)(l), 16, 0, 0)

__device__ __forceinline__ bf16_t split2h(float x) { return (bf16_t)x; }
__device__ __forceinline__ bf16_t split2l(float x)
{
    return (bf16_t)(x - (float)(bf16_t)x);
}

// ---------------------------------------------------------------------------
// transpose + convert (hi only): in [R][C] fp32 -> out [C][R] bf16
// ---------------------------------------------------------------------------
__global__ __launch_bounds__(256)
void transpose_h(const float* __restrict__ in, bf16_t* __restrict__ out,
                 int R, int C)
{
    __shared__ float t[64][65];
    const int r0 = blockIdx.y * 64, c0 = blockIdx.x * 64;
#pragma unroll
    for (int i = 0; i < 16; ++i) {
        int f = threadIdx.x + i * 256;
        int r = f >> 6, c = f & 63;
        t[r][c] = in[(size_t)(r0 + r) * C + c0 + c];
    }
    __syncthreads();
#pragma unroll
    for (int i = 0; i < 16; ++i) {
        int f = threadIdx.x + i * 256;
        int r = f >> 6, c = f & 63;
        out[(size_t)(c0 + r) * R + r0 + c] = (bf16_t)t[c][r];
    }
}

// ---------------------------------------------------------------------------
// transpose + split-convert: in [R][C] fp32 -> oh/ol [C][R] bf16 hi/lo
// ---------------------------------------------------------------------------
__global__ __launch_bounds__(256)
void transpose_split(const float* __restrict__ in, bf16_t* __restrict__ oh,
                     bf16_t* __restrict__ ol, int R, int C)
{
    __shared__ float t[64][65];
    const int r0 = blockIdx.y * 64, c0 = blockIdx.x * 64;
#pragma unroll
    for (int i = 0; i < 16; ++i) {
        int f = threadIdx.x + i * 256;
        int r = f >> 6, c = f & 63;
        t[r][c] = in[(size_t)(r0 + r) * C + c0 + c];
    }
    __syncthreads();
#pragma unroll
    for (int i = 0; i < 16; ++i) {
        int f = threadIdx.x + i * 256;
        int r = f >> 6, c = f & 63;
        float x = t[c][r];
        oh[(size_t)(c0 + r) * R + r0 + c] = split2h(x);
        ol[(size_t)(c0 + r) * R + r0 + c] = split2l(x);
    }
}

// ---------------------------------------------------------------------------
// RoPE cos/sin tables via fp64 (exact angle reduction)
// ---------------------------------------------------------------------------
__global__ __launch_bounds__(256)
void rope_tables(float* __restrict__ ct, float* __restrict__ st)
{
    int t = blockIdx.x * 256 + threadIdx.x;   // 4096*128
    int s = t >> 7, j = t & 127;
    double inv = exp2((double)j * (-13.28771237954945 / 128.0)); // log2(10000)
    double ang = fmod((double)s * inv, 6.283185307179586476925286766559);
    ct[t] = (float)cos(ang);
    st[t] = (float)sin(ang);
}

// ---------------------------------------------------------------------------
// GEMM1 (fused qkv): [4096][2560] fp32 A  x  Bh^T [4096][2560] bf16, 2-pass
// (ah*bh + al*bh; A split in-kernel).  Epilogue routes by n0:
//   n0 <  2048 : qb[4096][2048]
//   n0 <  3072 : kb[4096][1024]
//   else       : vT[1024][4096] (transposed store)
// ---------------------------------------------------------------------------
__global__ __launch_bounds__(256)
void gemm1(const float* __restrict__ A, const bf16_t* __restrict__ Bh,
           bf16_t* __restrict__ qb, bf16_t* __restrict__ kb,
           bf16_t* __restrict__ vt)
{
    __shared__ __attribute__((aligned(16))) bf16_t Ah[128 * 32];
    __shared__ __attribute__((aligned(16))) bf16_t Al[128 * 32];
    __shared__ __attribute__((aligned(16))) bf16_t Bsh[128 * 32];
    const int tid = threadIdx.x, lane = tid & 63, wid = tid >> 6;
    const int g = lane >> 4, c16 = lane & 15;
    const int m0 = blockIdx.y * 128, n0 = blockIdx.x * 128;
    const int wm = wid >> 1, wn = wid & 1;

    f32x4 acc[4][4];
#pragma unroll
    for (int i = 0; i < 4; ++i)
#pragma unroll
        for (int j = 0; j < 4; ++j) acc[i][j] = (f32x4)(0.f);

    const int f0 = tid, f1 = tid + 256;
    for (int k0 = 0; k0 < 2560; k0 += 32) {
        __syncthreads();
        GLD_LDS16(Bh + (size_t)(n0 + (f0 >> 2)) * 2560 + k0 + (f0 & 3) * 8,
                  (char*)Bsh + wid * 1024);
        GLD_LDS16(Bh + (size_t)(n0 + (f1 >> 2)) * 2560 + k0 + (f1 & 3) * 8,
                  (char*)Bsh + wid * 1024 + 4096);
#pragma unroll
        for (int i = 0; i < 4; ++i) {
            int f = tid + i * 256;
            float4 v = *(const float4*)(A + (size_t)(m0 + (f >> 3)) * 2560
                                        + k0 + (f & 7) * 4);
            bf16x4 hv, lv;
            hv[0] = split2h(v.x); lv[0] = split2l(v.x);
            hv[1] = split2h(v.y); lv[1] = split2l(v.y);
            hv[2] = split2h(v.z); lv[2] = split2l(v.z);
            hv[3] = split2h(v.w); lv[3] = split2l(v.w);
            *(bf16x4*)((char*)Ah + (f >> 3) * 64 + (f & 7) * 8) = hv;
            *(bf16x4*)((char*)Al + (f >> 3) * 64 + (f & 7) * 8) = lv;
        }
        __syncthreads();
        bf16x8 ah[4], al[4], bh[4];
#pragma unroll
        for (int m = 0; m < 4; ++m) {
            int off = (wm * 64 + m * 16 + c16) * 32 + g * 8;
            ah[m] = *(const bf16x8*)(Ah + off);
            al[m] = *(const bf16x8*)(Al + off);
        }
#pragma unroll
        for (int n = 0; n < 4; ++n) {
            int off = (wn * 64 + n * 16 + c16) * 32 + g * 8;
            bh[n] = *(const bf16x8*)(Bsh + off);
        }
#pragma unroll
        for (int m = 0; m < 4; ++m)
#pragma unroll
            for (int n = 0; n < 4; ++n) {
                acc[m][n] = __builtin_amdgcn_mfma_f32_16x16x32_bf16(ah[m], bh[n], acc[m][n], 0, 0, 0);
                acc[m][n] = __builtin_amdgcn_mfma_f32_16x16x32_bf16(al[m], bh[n], acc[m][n], 0, 0, 0);
            }
    }

    if (n0 < 2048) {          // q region
#pragma unroll
        for (int m = 0; m < 4; ++m)
#pragma unroll
            for (int n = 0; n < 4; ++n) {
                int col = n0 + wn * 64 + n * 16 + c16;
                int rowb = m0 + wm * 64 + m * 16 + g * 4;
#pragma unroll
                for (int r = 0; r < 4; ++r)
                    qb[(size_t)(rowb + r) * 2048 + col] = (bf16_t)acc[m][n][r];
            }
    } else if (n0 < 3072) {   // k region
#pragma unroll
        for (int m = 0; m < 4; ++m)
#pragma unroll
            for (int n = 0; n < 4; ++n) {
                int col = n0 + wn * 64 + n * 16 + c16 - 2048;
                int rowb = m0 + wm * 64 + m * 16 + g * 4;
#pragma unroll
                for (int r = 0; r < 4; ++r)
                    kb[(size_t)(rowb + r) * 1024 + col] = (bf16_t)acc[m][n][r];
            }
    } else {                  // v region: transposed store
#pragma unroll
        for (int m = 0; m < 4; ++m)
#pragma unroll
            for (int n = 0; n < 4; ++n) {
                int d = n0 + wn * 64 + n * 16 + c16 - 3072;
                int rowb = m0 + wm * 64 + m * 16 + g * 4;
                bf16x4 hv;
#pragma unroll
                for (int r = 0; r < 4; ++r) hv[r] = (bf16_t)acc[m][n][r];
                *(bf16x4*)(vt + (size_t)d * 4096 + rowb) = hv;
            }
    }
}

// ---------------------------------------------------------------------------
// RMSNorm + RoPE on q (in-place, plain bf16 [4096][2048]).
// ---------------------------------------------------------------------------
__global__ __launch_bounds__(256)
void norm_q(bf16_t* __restrict__ qb, const float* __restrict__ w,
            const float* __restrict__ ct, const float* __restrict__ st)
{
    const int s = blockIdx.x, t = threadIdx.x;
    const int h = t >> 5, l = t & 31;
    bf16_t* base = qb + (size_t)s * 2048 + h * 256 + l * 8;
    bf16x8 hv = *(const bf16x8*)base;
    float x[8], ss = 0.f;
#pragma unroll
    for (int j = 0; j < 8; ++j) { x[j] = (float)hv[j]; ss += x[j] * x[j]; }
#pragma unroll
    for (int mk = 1; mk < 32; mk <<= 1) ss += __shfl_xor(ss, mk);
    const float rs = rsqrtf(ss * (1.f / 256.f) + 1e-6f);
    float4 w0 = *(const float4*)(w + l * 8);
    float4 w1 = *(const float4*)(w + l * 8 + 4);
    float wa[8] = { w0.x, w0.y, w0.z, w0.w, w1.x, w1.y, w1.z, w1.w };
    float xn[8];
#pragma unroll
    for (int j = 0; j < 8; ++j) xn[j] = x[j] * rs * (1.f + wa[j]);
    const int d0 = (l * 8) & 127;
    float4 c0 = *(const float4*)(ct + s * 128 + d0);
    float4 c1 = *(const float4*)(ct + s * 128 + d0 + 4);
    float4 s0 = *(const float4*)(st + s * 128 + d0);
    float4 s1 = *(const float4*)(st + s * 128 + d0 + 4);
    float cc[8] = { c0.x, c0.y, c0.z, c0.w, c1.x, c1.y, c1.z, c1.w };
    float sn[8] = { s0.x, s0.y, s0.z, s0.w, s1.x, s1.y, s1.z, s1.w };
    const bool upper = (l >= 16);
    bf16x8 oh;
#pragma unroll
    for (int j = 0; j < 8; ++j) {
        float pn = __shfl_xor(xn[j], 16);
        float rot = upper ? pn : -pn;
        oh[j] = (bf16_t)(xn[j] * cc[j] + rot * sn[j]);
    }
    *(bf16x8*)base = oh;
}

// ---------------------------------------------------------------------------
// RMSNorm + RoPE on k (in-place, plain bf16 [4096][1024]).
// ---------------------------------------------------------------------------
__global__ __launch_bounds__(256)
void norm_k(bf16_t* __restrict__ kb, const float* __restrict__ w,
            const float* __restrict__ ct, const float* __restrict__ st)
{
    const int s = blockIdx.x, t = threadIdx.x;
    const int h = t >> 6, l = t & 63;
    bf16_t* base = kb + (size_t)s * 1024 + h * 256 + l * 4;
    bf16x4 hv = *(const bf16x4*)base;
    float x[4], ss = 0.f;
#pragma unroll
    for (int j = 0; j < 4; ++j) { x[j] = (float)hv[j]; ss += x[j] * x[j]; }
#pragma unroll
    for (int mk = 1; mk < 64; mk <<= 1) ss += __shfl_xor(ss, mk);
    const float rs = rsqrtf(ss * (1.f / 256.f) + 1e-6f);
    float4 w0 = *(const float4*)(w + l * 4);
    float wa[4] = { w0.x, w0.y, w0.z, w0.w };
    float xn[4];
#pragma unroll
    for (int j = 0; j < 4; ++j) xn[j] = x[j] * rs * (1.f + wa[j]);
    const int d0 = (l * 4) & 127;
    float4 c0 = *(const float4*)(ct + s * 128 + d0);
    float4 s0 = *(const float4*)(st + s * 128 + d0);
    float cc[4] = { c0.x, c0.y, c0.z, c0.w };
    float sn[4] = { s0.x, s0.y, s0.z, s0.w };
    const bool upper = (l >= 32);
    bf16x4 oh;
#pragma unroll
    for (int j = 0; j < 4; ++j) {
        float pn = __shfl_xor(xn[j], 32);
        float rot = upper ? pn : -pn;
        oh[j] = (bf16_t)(xn[j] * cc[j] + rot * sn[j]);
    }
    *(bf16x4*)base = oh;
}

// ---------------------------------------------------------------------------
// Sliding-window GQA flash attention with async double-buffered LDS staging.
// grid (64, 8); block 256 (4 waves x 16 q-rows).  KVBLK = 32 keys/tile.
// ---------------------------------------------------------------------------
__global__ __launch_bounds__(256)
void attn_fwd4(const bf16_t* __restrict__ qb, const bf16_t* __restrict__ kb,
               const bf16_t* __restrict__ vt, bf16_t* __restrict__ attn)
{
    __shared__ __attribute__((aligned(16))) char smem[2 * 32768];
    __shared__ __attribute__((aligned(16))) bf16_t P[4][16][40];
    const int tid = threadIdx.x, lane = tid & 63, wid = tid >> 6;
    const int g = lane >> 4, c16 = lane & 15;
    const int bx = blockIdx.x;
    const int qt = (bx & 1) ? (63 - (bx >> 1)) : (bx >> 1);   // load-balance pair
    const int h = blockIdx.y, kvh = h >> 1;
    const int qrow0 = qt * 64 + wid * 16;

    bf16x8 qf[8];
#pragma unroll
    for (int c = 0; c < 8; ++c)
        qf[c] = *(const bf16x8*)(qb + (size_t)(qrow0 + c16) * 2048 + h * 256 + c * 32 + g * 8);

    float mrow[4] = { -1e30f, -1e30f, -1e30f, -1e30f };
    float lrow[4] = { 0.f, 0.f, 0.f, 0.f };
    f32x4 acc[16];
#pragma unroll
    for (int nd = 0; nd < 16; ++nd) acc[nd] = (f32x4)(0.f);

    auto STAGE = [&](int buf, int kt) {
        char* Kd = smem + buf * 32768;
        char* Vd = smem + buf * 32768 + 16384;
        const char* ksrc = (const char*)kb + (size_t)kt * 32 * 2048 + (size_t)kvh * 512;
        const char* vsrc = (const char*)vt + (size_t)kvh * 256 * 8192 + (size_t)kt * 64;
#pragma unroll
        for (int j = 0; j < 4; ++j) {
            int c_ = j * 256 + tid;
            int row = c_ >> 5, b = c_ & 31;
            GLD_LDS16(ksrc + (size_t)row * 2048 + ((b ^ (row & 7)) << 4),
                      Kd + (j * 256 + wid * 64) * 16);
        }
#pragma unroll
        for (int j = 0; j < 4; ++j) {
            int c_ = j * 256 + tid;
            int row = c_ >> 2, b = c_ & 3;
            GLD_LDS16(vsrc + (size_t)row * 8192 + ((b ^ (row & 3)) << 4),
                      Vd + (j * 256 + wid * 64) * 16);
        }
    };

    const int ktb_lo = (qt >= 16) ? 2 * qt - 32 : 0;
    const int ktb_hi = 2 * qt + 1;
    int cur = 0;
    STAGE(0, ktb_lo);
    __syncthreads();

    const int swk = (c16 & 7) << 4;
    const int swv = (g ^ (c16 & 3)) << 4;

    for (int kt = ktb_lo; kt <= ktb_hi; ++kt) {
        if (kt < ktb_hi) STAGE(cur ^ 1, kt + 1);

        if (kt * 32 <= qrow0 + 15 && kt * 32 + 31 >= qrow0 - 1023) {
            const char* Kc = smem + cur * 32768;
            const char* Vc = smem + cur * 32768 + 16384;

            f32x4 sc[2];
#pragma unroll
            for (int n = 0; n < 2; ++n) sc[n] = (f32x4)(0.f);
#pragma unroll
            for (int n = 0; n < 2; ++n) {
                const char* kr = Kc + (n * 16 + c16) * 512;
#pragma unroll
                for (int c = 0; c < 8; ++c) {
                    bf16x8 kf = *(const bf16x8*)(kr + ((((c * 4 + g) << 4) ^ swk)));
                    sc[n] = __builtin_amdgcn_mfma_f32_16x16x32_bf16(qf[c], kf, sc[n], 0, 0, 0);
                }
            }
            float rm[4] = { -1e30f, -1e30f, -1e30f, -1e30f };
#pragma unroll
            for (int n = 0; n < 2; ++n) {
                const int key = kt * 32 + n * 16 + c16;
#pragma unroll
                for (int r = 0; r < 4; ++r) {
                    const int q = qrow0 + g * 4 + r;
                    float s = sc[n][r] * 0.0625f;
                    bool valid = (key <= q) && (q - key < 1024);
                    s = valid ? s : -1e30f;
                    sc[n][r] = s;
                    rm[r] = fmaxf(rm[r], s);
                }
            }
#pragma unroll
            for (int mk = 1; mk < 16; mk <<= 1)
#pragma unroll
                for (int r = 0; r < 4; ++r) rm[r] = fmaxf(rm[r], __shfl_xor(rm[r], mk));
            float alpha[4], psum[4] = { 0.f, 0.f, 0.f, 0.f };
#pragma unroll
            for (int r = 0; r < 4; ++r) {
                float nm = fmaxf(mrow[r], rm[r]);
                alpha[r] = __expf(mrow[r] - nm);
                mrow[r] = nm;
            }
#pragma unroll
            for (int n = 0; n < 2; ++n)
#pragma unroll
                for (int r = 0; r < 4; ++r) {
                    float sv = sc[n][r];
                    float pv = (sv > -1e29f) ? __expf(sv - mrow[r]) : 0.f;
                    sc[n][r] = pv;
                    psum[r] += pv;
                }
#pragma unroll
            for (int mk = 1; mk < 16; mk <<= 1)
#pragma unroll
                for (int r = 0; r < 4; ++r) psum[r] += __shfl_xor(psum[r], mk);
#pragma unroll
            for (int r = 0; r < 4; ++r) lrow[r] = lrow[r] * alpha[r] + psum[r];
#pragma unroll
            for (int nd = 0; nd < 16; ++nd)
#pragma unroll
                for (int r = 0; r < 4; ++r) acc[nd][r] *= alpha[r];

#pragma unroll
            for (int n = 0; n < 2; ++n)
#pragma unroll
                for (int r = 0; r < 4; ++r)
                    P[wid][g * 4 + r][n * 16 + c16] = (bf16_t)sc[n][r];
            bf16x8 pa = *(const bf16x8*)(&P[wid][c16][g * 8]);
#pragma unroll
            for (int nd = 0; nd < 16; ++nd) {
                bf16x8 vf = *(const bf16x8*)(Vc + (nd * 16 + c16) * 64 + swv);
                acc[nd] = __builtin_amdgcn_mfma_f32_16x16x32_bf16(pa, vf, acc[nd], 0, 0, 0);
            }
        }
        __syncthreads();
        cur ^= 1;
    }

    float inv[4];
#pragma unroll
    for (int r = 0; r < 4; ++r) inv[r] = 1.f / lrow[r];
#pragma unroll
    for (int nd = 0; nd < 16; ++nd)
#pragma unroll
        for (int r = 0; r < 4; ++r) {
            int row = qrow0 + g * 4 + r;
            attn[(size_t)row * 2048 + h * 256 + nd * 16 + c16] =
                (bf16_t)(acc[nd][r] * inv[r]);
        }
}

// ---------------------------------------------------------------------------
// GEMM2: out(fp32) = attn(bf16) @ woT(pre-split hi/lo), 2-pass MFMA.
// ---------------------------------------------------------------------------
__global__ __launch_bounds__(256)
void gemm2(const bf16_t* __restrict__ A, const bf16_t* __restrict__ Bh,
           const bf16_t* __restrict__ Bl, float* __restrict__ C)
{
    __shared__ __attribute__((aligned(16))) bf16_t As[128 * 32];
    __shared__ __attribute__((aligned(16))) bf16_t Bsh[128 * 32];
    __shared__ __attribute__((aligned(16))) bf16_t Bsl[128 * 32];
    const int tid = threadIdx.x, lane = tid & 63, wid = tid >> 6;
    const int g = lane >> 4, c16 = lane & 15;
    const int m0 = blockIdx.y * 128, n0 = blockIdx.x * 128;
    const int wm = wid >> 1, wn = wid & 1;

    f32x4 acc[4][4];
#pragma unroll
    for (int i = 0; i < 4; ++i)
#pragma unroll
        for (int j = 0; j < 4; ++j) acc[i][j] = (f32x4)(0.f);

    const int f0 = tid, f1 = tid + 256;
    for (int k0 = 0; k0 < 2048; k0 += 32) {
        __syncthreads();
        GLD_LDS16(A + (size_t)(m0 + (f0 >> 2)) * 2048 + k0 + (f0 & 3) * 8,
                  (char*)As + wid * 1024);
        GLD_LDS16(A + (size_t)(m0 + (f1 >> 2)) * 2048 + k0 + (f1 & 3) * 8,
                  (char*)As + wid * 1024 + 4096);
        GLD_LDS16(Bh + (size_t)(n0 + (f0 >> 2)) * 2048 + k0 + (f0 & 3) * 8,
                  (char*)Bsh + wid * 1024);
        GLD_LDS16(Bh + (size_t)(n0 + (f1 >> 2)) * 2048 + k0 + (f1 & 3) * 8,
                  (char*)Bsh + wid * 1024 + 4096);
        GLD_LDS16(Bl + (size_t)(n0 + (f0 >> 2)) * 2048 + k0 + (f0 & 3) * 8,
                  (char*)Bsl + wid * 1024);
        GLD_LDS16(Bl + (size_t)(n0 + (f1 >> 2)) * 2048 + k0 + (f1 & 3) * 8,
                  (char*)Bsl + wid * 1024 + 4096);
        __syncthreads();
        bf16x8 af[4], bh[4], bl[4];
#pragma unroll
        for (int m = 0; m < 4; ++m)
            af[m] = *(const bf16x8*)(As + (wm * 64 + m * 16 + c16) * 32 + g * 8);
#pragma unroll
        for (int n = 0; n < 4; ++n) {
            int off = (wn * 64 + n * 16 + c16) * 32 + g * 8;
            bh[n] = *(const bf16x8*)(Bsh + off);
            bl[n] = *(const bf16x8*)(Bsl + off);
        }
#pragma unroll
        for (int m = 0; m < 4; ++m)
#pragma unroll
            for (int n = 0; n < 4; ++n) {
                acc[m][n] = __builtin_amdgcn_mfma_f32_16x16x32_bf16(af[m], bh[n], acc[m][n], 0, 0, 0);
                acc[m][n] = __builtin_amdgcn_mfma_f32_16x16x32_bf16(af[m], bl[n], acc[m][n], 0, 0, 0);
            }
    }

#pragma unroll
    for (int m = 0; m < 4; ++m)
#pragma unroll
        for (int n = 0; n < 4; ++n)
#pragma unroll
            for (int r = 0; r < 4; ++r) {
                int row = m0 + wm * 64 + m * 16 + g * 4 + r;
                int col = n0 + wn * 64 + n * 16 + c16;
                C[(size_t)row * 2560 + col] = acc[m][n][r];
            }
}

// ---------------------------------------------------------------------------
// Workspace layout (peak ~54.5 MB; phase-aliased):
//   qb    [0,          16,777,216)   [4096][2048] bf16
//   kb    [16,777,216, 25,165,824)   [4096][1024]
//   vT    [25,165,824, 33,554,432)   [1024][4096]
//   Bh    [33,554,432, 54,525,952)   [4096][2560] bf16 (dead after gemm1)
//   attnb [33,554,432, 50,331,648)   [4096][2048]  (over dead Bh)
//   ct    [50,331,648, 52,428,800)   (over dead Bh tail)
//   st    [52,428,800, 54,525,952)
//   woh   [0,          10,485,760)   [2560][2048]  (over dead qb)
//   wol   [10,485,760, 20,971,520)   (over dead qb/kb)
// ---------------------------------------------------------------------------
extern "C" void kernel_launch(void* const* d_in, const int* in_sizes, int n_in,
                              void* d_out, int out_size, void* d_ws, size_t ws_size,
                              hipStream_t stream)
{
    (void)in_sizes; (void)n_in; (void)out_size; (void)ws_size;
    const float* hs  = (const float*)d_in[0];
    const float* wq  = (const float*)d_in[3];
    const float* wk  = (const float*)d_in[4];
    const float* wv  = (const float*)d_in[5];
    const float* wo  = (const float*)d_in[6];
    const float* qnw = (const float*)d_in[7];
    const float* knw = (const float*)d_in[8];

    char* ws = (char*)d_ws;
    bf16_t* qb    = (bf16_t*)(ws);
    bf16_t* kb    = (bf16_t*)(ws + 16777216);
    bf16_t* vt    = (bf16_t*)(ws + 25165824);
    bf16_t* Bh    = (bf16_t*)(ws + 33554432);
    bf16_t* attnb = (bf16_t*)(ws + 33554432);
    float*  ct    = (float*)(ws + 50331648);
    float*  st    = (float*)(ws + 52428800);
    bf16_t* woh   = (bf16_t*)(ws);
    bf16_t* wol   = (bf16_t*)(ws + 10485760);

    // 1. weights -> Bh panel [4096][2560] (hi only): rows 0..2047 wq,
    //    2048..3071 wk, 3072..4095 wv
    transpose_h<<<dim3(32, 40), 256, 0, stream>>>(wq, Bh, 2560, 2048);
    transpose_h<<<dim3(16, 40), 256, 0, stream>>>(wk, Bh + (size_t)2048 * 2560, 2560, 1024);
    transpose_h<<<dim3(16, 40), 256, 0, stream>>>(wv, Bh + (size_t)3072 * 2560, 2560, 1024);

    // 2. fused qkv projection (2-pass)
    gemm1<<<dim3(32, 32), 256, 0, stream>>>(hs, Bh, qb, kb, vt);

    // 3. RoPE tables + norms (tables over dead Bh tail)
    rope_tables<<<2048, 256, 0, stream>>>(ct, st);
    norm_q<<<4096, 256, 0, stream>>>(qb, qnw, ct, st);
    norm_k<<<4096, 256, 0, stream>>>(kb, knw, ct, st);

    // 4. attention (writes attnb over dead Bh head)
    attn_fwd4<<<dim3(64, 8), 256, 0, stream>>>(qb, kb, vt, attnb);

    // 5. wo -> woT panels (over dead qb/kb), then output projection (2-pass)
    transpose_split<<<dim3(40, 32), 256, 0, stream>>>(wo, woh, wol, 2048, 2560);
    gemm2<<<dim3(20, 32), 256, 0, stream>>>(attnb, woh, wol, (float*)d_out);
}

// Round 9
// 410.133 us; speedup vs baseline: 2.9049x; 1.2533x over previous
//
#include <hip/hip_runtime.h>
#include <stdint.h>
#include <math.h>

typedef __bf16 bf16_t;
typedef __bf16 bf16x8 __attribute__((ext_vector_type(8)));
typedef __bf16 bf16x4 __attribute__((ext_vector_type(4)));
typedef float f32x4 __attribute__((ext_vector_type(4)));

#define GLD_LDS16(g, l)                                             \
    __builtin_amdgcn_global_load_lds(                               \
        (const __attribute__((address_space(1))) void*)(g),         \
        (__attribute__((address_space(3))) void*)(l), 16, 0, 0)

// ---------------------------------------------------------------------------
// fp32 -> bf16 elementwise (float4 -> bf16x4)
// ---------------------------------------------------------------------------
__global__ __launch_bounds__(256)
void conv_bf16(const float* __restrict__ in, bf16_t* __restrict__ out, int n4)
{
    int i = blockIdx.x * 256 + threadIdx.x;
    if (i >= n4) return;
    float4 v = ((const float4*)in)[i];
    bf16x4 o = { (bf16_t)v.x, (bf16_t)v.y, (bf16_t)v.z, (bf16_t)v.w };
    ((bf16x4*)out)[i] = o;
}

// ---------------------------------------------------------------------------
// transpose + convert: in [R][C] fp32 -> out [C][R] bf16
// ---------------------------------------------------------------------------
__global__ __launch_bounds__(256)
void transpose_h(const float* __restrict__ in, bf16_t* __restrict__ out,
                 int R, int C)
{
    __shared__ float t[64][65];
    const int r0 = blockIdx.y * 64, c0 = blockIdx.x * 64;
#pragma unroll
    for (int i = 0; i < 16; ++i) {
        int f = threadIdx.x + i * 256;
        int r = f >> 6, c = f & 63;
        t[r][c] = in[(size_t)(r0 + r) * C + c0 + c];
    }
    __syncthreads();
#pragma unroll
    for (int i = 0; i < 16; ++i) {
        int f = threadIdx.x + i * 256;
        int r = f >> 6, c = f & 63;
        out[(size_t)(c0 + r) * R + r0 + c] = (bf16_t)t[c][r];
    }
}

// ---------------------------------------------------------------------------
// RoPE cos/sin tables via fp64 (exact angle reduction)
// ---------------------------------------------------------------------------
__global__ __launch_bounds__(256)
void rope_tables(float* __restrict__ ct, float* __restrict__ st)
{
    int t = blockIdx.x * 256 + threadIdx.x;   // 4096*128
    int s = t >> 7, j = t & 127;
    double inv = exp2((double)j * (-13.28771237954945 / 128.0)); // log2(10000)
    double ang = fmod((double)s * inv, 6.283185307179586476925286766559);
    ct[t] = (float)cos(ang);
    st[t] = (float)sin(ang);
}

// ---------------------------------------------------------------------------
// GEMM1 (fused qkv, 1-pass bf16): A[4096][2560] bf16 x Bh^T[4096][2560] bf16.
// Epilogue routes by n0: q[4096][2048] | k[4096][1024] | vT[1024][4096].
// ---------------------------------------------------------------------------
__global__ __launch_bounds__(256)
void gemm1(const bf16_t* __restrict__ A, const bf16_t* __restrict__ Bh,
           bf16_t* __restrict__ qb, bf16_t* __restrict__ kb,
           bf16_t* __restrict__ vt)
{
    __shared__ __attribute__((aligned(16))) bf16_t As[128 * 32];
    __shared__ __attribute__((aligned(16))) bf16_t Bs[128 * 32];
    const int tid = threadIdx.x, lane = tid & 63, wid = tid >> 6;
    const int g = lane >> 4, c16 = lane & 15;
    const int m0 = blockIdx.y * 128, n0 = blockIdx.x * 128;
    const int wm = wid >> 1, wn = wid & 1;

    f32x4 acc[4][4];
#pragma unroll
    for (int i = 0; i < 4; ++i)
#pragma unroll
        for (int j = 0; j < 4; ++j) acc[i][j] = (f32x4)(0.f);

    const int f0 = tid, f1 = tid + 256;
    for (int k0 = 0; k0 < 2560; k0 += 32) {
        __syncthreads();
        GLD_LDS16(A + (size_t)(m0 + (f0 >> 2)) * 2560 + k0 + (f0 & 3) * 8,
                  (char*)As + wid * 1024);
        GLD_LDS16(A + (size_t)(m0 + (f1 >> 2)) * 2560 + k0 + (f1 & 3) * 8,
                  (char*)As + wid * 1024 + 4096);
        GLD_LDS16(Bh + (size_t)(n0 + (f0 >> 2)) * 2560 + k0 + (f0 & 3) * 8,
                  (char*)Bs + wid * 1024);
        GLD_LDS16(Bh + (size_t)(n0 + (f1 >> 2)) * 2560 + k0 + (f1 & 3) * 8,
                  (char*)Bs + wid * 1024 + 4096);
        __syncthreads();
        bf16x8 af[4], bf[4];
#pragma unroll
        for (int m = 0; m < 4; ++m)
            af[m] = *(const bf16x8*)(As + (wm * 64 + m * 16 + c16) * 32 + g * 8);
#pragma unroll
        for (int n = 0; n < 4; ++n)
            bf[n] = *(const bf16x8*)(Bs + (wn * 64 + n * 16 + c16) * 32 + g * 8);
#pragma unroll
        for (int m = 0; m < 4; ++m)
#pragma unroll
            for (int n = 0; n < 4; ++n)
                acc[m][n] = __builtin_amdgcn_mfma_f32_16x16x32_bf16(af[m], bf[n], acc[m][n], 0, 0, 0);
    }

    if (n0 < 2048) {          // q region
#pragma unroll
        for (int m = 0; m < 4; ++m)
#pragma unroll
            for (int n = 0; n < 4; ++n) {
                int col = n0 + wn * 64 + n * 16 + c16;
                int rowb = m0 + wm * 64 + m * 16 + g * 4;
#pragma unroll
                for (int r = 0; r < 4; ++r)
                    qb[(size_t)(rowb + r) * 2048 + col] = (bf16_t)acc[m][n][r];
            }
    } else if (n0 < 3072) {   // k region
#pragma unroll
        for (int m = 0; m < 4; ++m)
#pragma unroll
            for (int n = 0; n < 4; ++n) {
                int col = n0 + wn * 64 + n * 16 + c16 - 2048;
                int rowb = m0 + wm * 64 + m * 16 + g * 4;
#pragma unroll
                for (int r = 0; r < 4; ++r)
                    kb[(size_t)(rowb + r) * 1024 + col] = (bf16_t)acc[m][n][r];
            }
    } else {                  // v region: transposed store
#pragma unroll
        for (int m = 0; m < 4; ++m)
#pragma unroll
            for (int n = 0; n < 4; ++n) {
                int d = n0 + wn * 64 + n * 16 + c16 - 3072;
                int rowb = m0 + wm * 64 + m * 16 + g * 4;
                bf16x4 hv;
#pragma unroll
                for (int r = 0; r < 4; ++r) hv[r] = (bf16_t)acc[m][n][r];
                *(bf16x4*)(vt + (size_t)d * 4096 + rowb) = hv;
            }
    }
}

// ---------------------------------------------------------------------------
// RMSNorm + RoPE on q (in-place, plain bf16 [4096][2048]).
// ---------------------------------------------------------------------------
__global__ __launch_bounds__(256)
void norm_q(bf16_t* __restrict__ qb, const float* __restrict__ w,
            const float* __restrict__ ct, const float* __restrict__ st)
{
    const int s = blockIdx.x, t = threadIdx.x;
    const int h = t >> 5, l = t & 31;
    bf16_t* base = qb + (size_t)s * 2048 + h * 256 + l * 8;
    bf16x8 hv = *(const bf16x8*)base;
    float x[8], ss = 0.f;
#pragma unroll
    for (int j = 0; j < 8; ++j) { x[j] = (float)hv[j]; ss += x[j] * x[j]; }
#pragma unroll
    for (int mk = 1; mk < 32; mk <<= 1) ss += __shfl_xor(ss, mk);
    const float rs = rsqrtf(ss * (1.f / 256.f) + 1e-6f);
    float4 w0 = *(const float4*)(w + l * 8);
    float4 w1 = *(const float4*)(w + l * 8 + 4);
    float wa[8] = { w0.x, w0.y, w0.z, w0.w, w1.x, w1.y, w1.z, w1.w };
    float xn[8];
#pragma unroll
    for (int j = 0; j < 8; ++j) xn[j] = x[j] * rs * (1.f + wa[j]);
    const int d0 = (l * 8) & 127;
    float4 c0 = *(const float4*)(ct + s * 128 + d0);
    float4 c1 = *(const float4*)(ct + s * 128 + d0 + 4);
    float4 s0 = *(const float4*)(st + s * 128 + d0);
    float4 s1 = *(const float4*)(st + s * 128 + d0 + 4);
    float cc[8] = { c0.x, c0.y, c0.z, c0.w, c1.x, c1.y, c1.z, c1.w };
    float sn[8] = { s0.x, s0.y, s0.z, s0.w, s1.x, s1.y, s1.z, s1.w };
    const bool upper = (l >= 16);
    bf16x8 oh;
#pragma unroll
    for (int j = 0; j < 8; ++j) {
        float pn = __shfl_xor(xn[j], 16);
        float rot = upper ? pn : -pn;
        oh[j] = (bf16_t)(xn[j] * cc[j] + rot * sn[j]);
    }
    *(bf16x8*)base = oh;
}

// ---------------------------------------------------------------------------
// RMSNorm + RoPE on k (in-place, plain bf16 [4096][1024]).
// ---------------------------------------------------------------------------
__global__ __launch_bounds__(256)
void norm_k(bf16_t* __restrict__ kb, const float* __restrict__ w,
            const float* __restrict__ ct, const float* __restrict__ st)
{
    const int s = blockIdx.x, t = threadIdx.x;
    const int h = t >> 6, l = t & 63;
    bf16_t* base = kb + (size_t)s * 1024 + h * 256 + l * 4;
    bf16x4 hv = *(const bf16x4*)base;
    float x[4], ss = 0.f;
#pragma unroll
    for (int j = 0; j < 4; ++j) { x[j] = (float)hv[j]; ss += x[j] * x[j]; }
#pragma unroll
    for (int mk = 1; mk < 64; mk <<= 1) ss += __shfl_xor(ss, mk);
    const float rs = rsqrtf(ss * (1.f / 256.f) + 1e-6f);
    float4 w0 = *(const float4*)(w + l * 4);
    float wa[4] = { w0.x, w0.y, w0.z, w0.w };
    float xn[4];
#pragma unroll
    for (int j = 0; j < 4; ++j) xn[j] = x[j] * rs * (1.f + wa[j]);
    const int d0 = (l * 4) & 127;
    float4 c0 = *(const float4*)(ct + s * 128 + d0);
    float4 s0 = *(const float4*)(st + s * 128 + d0);
    float cc[4] = { c0.x, c0.y, c0.z, c0.w };
    float sn[4] = { s0.x, s0.y, s0.z, s0.w };
    const bool upper = (l >= 32);
    bf16x4 oh;
#pragma unroll
    for (int j = 0; j < 4; ++j) {
        float pn = __shfl_xor(xn[j], 32);
        float rot = upper ? pn : -pn;
        oh[j] = (bf16_t)(xn[j] * cc[j] + rot * sn[j]);
    }
    *(bf16x4*)base = oh;
}

// ---------------------------------------------------------------------------
// Sliding-window GQA flash attention with async double-buffered LDS staging.
// grid (64, 8); block 256 (4 waves x 16 q-rows).  KVBLK = 32 keys/tile.
// ---------------------------------------------------------------------------
__global__ __launch_bounds__(256)
void attn_fwd4(const bf16_t* __restrict__ qb, const bf16_t* __restrict__ kb,
               const bf16_t* __restrict__ vt, bf16_t* __restrict__ attn)
{
    __shared__ __attribute__((aligned(16))) char smem[2 * 32768];
    __shared__ __attribute__((aligned(16))) bf16_t P[4][16][40];
    const int tid = threadIdx.x, lane = tid & 63, wid = tid >> 6;
    const int g = lane >> 4, c16 = lane & 15;
    const int bx = blockIdx.x;
    const int qt = (bx & 1) ? (63 - (bx >> 1)) : (bx >> 1);   // load-balance pair
    const int h = blockIdx.y, kvh = h >> 1;
    const int qrow0 = qt * 64 + wid * 16;

    bf16x8 qf[8];
#pragma unroll
    for (int c = 0; c < 8; ++c)
        qf[c] = *(const bf16x8*)(qb + (size_t)(qrow0 + c16) * 2048 + h * 256 + c * 32 + g * 8);

    float mrow[4] = { -1e30f, -1e30f, -1e30f, -1e30f };
    float lrow[4] = { 0.f, 0.f, 0.f, 0.f };
    f32x4 acc[16];
#pragma unroll
    for (int nd = 0; nd < 16; ++nd) acc[nd] = (f32x4)(0.f);

    auto STAGE = [&](int buf, int kt) {
        char* Kd = smem + buf * 32768;
        char* Vd = smem + buf * 32768 + 16384;
        const char* ksrc = (const char*)kb + (size_t)kt * 32 * 2048 + (size_t)kvh * 512;
        const char* vsrc = (const char*)vt + (size_t)kvh * 256 * 8192 + (size_t)kt * 64;
#pragma unroll
        for (int j = 0; j < 4; ++j) {
            int c_ = j * 256 + tid;
            int row = c_ >> 5, b = c_ & 31;
            GLD_LDS16(ksrc + (size_t)row * 2048 + ((b ^ (row & 7)) << 4),
                      Kd + (j * 256 + wid * 64) * 16);
        }
#pragma unroll
        for (int j = 0; j < 4; ++j) {
            int c_ = j * 256 + tid;
            int row = c_ >> 2, b = c_ & 3;
            GLD_LDS16(vsrc + (size_t)row * 8192 + ((b ^ (row & 3)) << 4),
                      Vd + (j * 256 + wid * 64) * 16);
        }
    };

    const int ktb_lo = (qt >= 16) ? 2 * qt - 32 : 0;
    const int ktb_hi = 2 * qt + 1;
    int cur = 0;
    STAGE(0, ktb_lo);
    __syncthreads();

    const int swk = (c16 & 7) << 4;
    const int swv = (g ^ (c16 & 3)) << 4;

    for (int kt = ktb_lo; kt <= ktb_hi; ++kt) {
        if (kt < ktb_hi) STAGE(cur ^ 1, kt + 1);

        if (kt * 32 <= qrow0 + 15 && kt * 32 + 31 >= qrow0 - 1023) {
            const char* Kc = smem + cur * 32768;
            const char* Vc = smem + cur * 32768 + 16384;

            f32x4 sc[2];
#pragma unroll
            for (int n = 0; n < 2; ++n) sc[n] = (f32x4)(0.f);
#pragma unroll
            for (int n = 0; n < 2; ++n) {
                const char* kr = Kc + (n * 16 + c16) * 512;
#pragma unroll
                for (int c = 0; c < 8; ++c) {
                    bf16x8 kf = *(const bf16x8*)(kr + ((((c * 4 + g) << 4) ^ swk)));
                    sc[n] = __builtin_amdgcn_mfma_f32_16x16x32_bf16(qf[c], kf, sc[n], 0, 0, 0);
                }
            }
            float rm[4] = { -1e30f, -1e30f, -1e30f, -1e30f };
#pragma unroll
            for (int n = 0; n < 2; ++n) {
                const int key = kt * 32 + n * 16 + c16;
#pragma unroll
                for (int r = 0; r < 4; ++r) {
                    const int q = qrow0 + g * 4 + r;
                    float s = sc[n][r] * 0.0625f;
                    bool valid = (key <= q) && (q - key < 1024);
                    s = valid ? s : -1e30f;
                    sc[n][r] = s;
                    rm[r] = fmaxf(rm[r], s);
                }
            }
#pragma unroll
            for (int mk = 1; mk < 16; mk <<= 1)
#pragma unroll
                for (int r = 0; r < 4; ++r) rm[r] = fmaxf(rm[r], __shfl_xor(rm[r], mk));
            float alpha[4], psum[4] = { 0.f, 0.f, 0.f, 0.f };
#pragma unroll
            for (int r = 0; r < 4; ++r) {
                float nm = fmaxf(mrow[r], rm[r]);
                alpha[r] = __expf(mrow[r] - nm);
                mrow[r] = nm;
            }
#pragma unroll
            for (int n = 0; n < 2; ++n)
#pragma unroll
                for (int r = 0; r < 4; ++r) {
                    float sv = sc[n][r];
                    float pv = (sv > -1e29f) ? __expf(sv - mrow[r]) : 0.f;
                    sc[n][r] = pv;
                    psum[r] += pv;
                }
#pragma unroll
            for (int mk = 1; mk < 16; mk <<= 1)
#pragma unroll
                for (int r = 0; r < 4; ++r) psum[r] += __shfl_xor(psum[r], mk);
#pragma unroll
            for (int r = 0; r < 4; ++r) lrow[r] = lrow[r] * alpha[r] + psum[r];
#pragma unroll
            for (int nd = 0; nd < 16; ++nd)
#pragma unroll
                for (int r = 0; r < 4; ++r) acc[nd][r] *= alpha[r];

#pragma unroll
            for (int n = 0; n < 2; ++n)
#pragma unroll
                for (int r = 0; r < 4; ++r)
                    P[wid][g * 4 + r][n * 16 + c16] = (bf16_t)sc[n][r];
            bf16x8 pa = *(const bf16x8*)(&P[wid][c16][g * 8]);
#pragma unroll
            for (int nd = 0; nd < 16; ++nd) {
                bf16x8 vf = *(const bf16x8*)(Vc + (nd * 16 + c16) * 64 + swv);
                acc[nd] = __builtin_amdgcn_mfma_f32_16x16x32_bf16(pa, vf, acc[nd], 0, 0, 0);
            }
        }
        __syncthreads();
        cur ^= 1;
    }

    float inv[4];
#pragma unroll
    for (int r = 0; r < 4; ++r) inv[r] = 1.f / lrow[r];
#pragma unroll
    for (int nd = 0; nd < 16; ++nd)
#pragma unroll
        for (int r = 0; r < 4; ++r) {
            int row = qrow0 + g * 4 + r;
            attn[(size_t)row * 2048 + h * 256 + nd * 16 + c16] =
                (bf16_t)(acc[nd][r] * inv[r]);
        }
}

// ---------------------------------------------------------------------------
// GEMM2 (1-pass bf16): out(fp32) = attn[4096][2048] @ woT[2560][2048]^T.
// ---------------------------------------------------------------------------
__global__ __launch_bounds__(256)
void gemm2(const bf16_t* __restrict__ A, const bf16_t* __restrict__ Bh,
           float* __restrict__ C)
{
    __shared__ __attribute__((aligned(16))) bf16_t As[128 * 32];
    __shared__ __attribute__((aligned(16))) bf16_t Bs[128 * 32];
    const int tid = threadIdx.x, lane = tid & 63, wid = tid >> 6;
    const int g = lane >> 4, c16 = lane & 15;
    const int m0 = blockIdx.y * 128, n0 = blockIdx.x * 128;
    const int wm = wid >> 1, wn = wid & 1;

    f32x4 acc[4][4];
#pragma unroll
    for (int i = 0; i < 4; ++i)
#pragma unroll
        for (int j = 0; j < 4; ++j) acc[i][j] = (f32x4)(0.f);

    const int f0 = tid, f1 = tid + 256;
    for (int k0 = 0; k0 < 2048; k0 += 32) {
        __syncthreads();
        GLD_LDS16(A + (size_t)(m0 + (f0 >> 2)) * 2048 + k0 + (f0 & 3) * 8,
                  (char*)As + wid * 1024);
        GLD_LDS16(A + (size_t)(m0 + (f1 >> 2)) * 2048 + k0 + (f1 & 3) * 8,
                  (char*)As + wid * 1024 + 4096);
        GLD_LDS16(Bh + (size_t)(n0 + (f0 >> 2)) * 2048 + k0 + (f0 & 3) * 8,
                  (char*)Bs + wid * 1024);
        GLD_LDS16(Bh + (size_t)(n0 + (f1 >> 2)) * 2048 + k0 + (f1 & 3) * 8,
                  (char*)Bs + wid * 1024 + 4096);
        __syncthreads();
        bf16x8 af[4], bf[4];
#pragma unroll
        for (int m = 0; m < 4; ++m)
            af[m] = *(const bf16x8*)(As + (wm * 64 + m * 16 + c16) * 32 + g * 8);
#pragma unroll
        for (int n = 0; n < 4; ++n)
            bf[n] = *(const bf16x8*)(Bs + (wn * 64 + n * 16 + c16) * 32 + g * 8);
#pragma unroll
        for (int m = 0; m < 4; ++m)
#pragma unroll
            for (int n = 0; n < 4; ++n)
                acc[m][n] = __builtin_amdgcn_mfma_f32_16x16x32_bf16(af[m], bf[n], acc[m][n], 0, 0, 0);
    }

#pragma unroll
    for (int m = 0; m < 4; ++m)
#pragma unroll
        for (int n = 0; n < 4; ++n)
#pragma unroll
            for (int r = 0; r < 4; ++r) {
                int row = m0 + wm * 64 + m * 16 + g * 4 + r;
                int col = n0 + wn * 64 + n * 16 + c16;
                C[(size_t)row * 2560 + col] = acc[m][n][r];
            }
}

// ---------------------------------------------------------------------------
// Workspace layout (peak ~79.7 MB; phase-aliased):
//   hs_bf [0,          20,971,520)   [4096][2560] bf16 (dead after gemm1)
//   qb    [20,971,520, 37,748,736)   [4096][2048]
//   kb    [37,748,736, 46,137,344)   [4096][1024]
//   vT    [46,137,344, 54,525,952)   [1024][4096]
//   Bh    [54,525,952, 75,497,472)   [4096][2560]  (dead after gemm1)
//   ct    [75,497,472, 77,594,624)
//   st    [77,594,624, 79,691,776)
//   attnb [54,525,952, 71,303,168)   [4096][2048]  (over dead Bh)
//   woh   [0,          10,485,760)   [2560][2048]  (over dead hs_bf)
// ---------------------------------------------------------------------------
extern "C" void kernel_launch(void* const* d_in, const int* in_sizes, int n_in,
                              void* d_out, int out_size, void* d_ws, size_t ws_size,
                              hipStream_t stream)
{
    (void)in_sizes; (void)n_in; (void)out_size; (void)ws_size;
    const float* hs  = (const float*)d_in[0];
    const float* wq  = (const float*)d_in[3];
    const float* wk  = (const float*)d_in[4];
    const float* wv  = (const float*)d_in[5];
    const float* wo  = (const float*)d_in[6];
    const float* qnw = (const float*)d_in[7];
    const float* knw = (const float*)d_in[8];

    char* ws = (char*)d_ws;
    bf16_t* hs_bf = (bf16_t*)(ws);
    bf16_t* qb    = (bf16_t*)(ws + 20971520);
    bf16_t* kb    = (bf16_t*)(ws + 37748736);
    bf16_t* vt    = (bf16_t*)(ws + 46137344);
    bf16_t* Bh    = (bf16_t*)(ws + 54525952);
    float*  ct    = (float*)(ws + 75497472);
    float*  st    = (float*)(ws + 77594624);
    bf16_t* attnb = (bf16_t*)(ws + 54525952);
    bf16_t* woh   = (bf16_t*)(ws);

    // 1. hs -> bf16; weights -> Bh panel [4096][2560]
    conv_bf16<<<10240, 256, 0, stream>>>(hs, hs_bf, 4096 * 2560 / 4);
    transpose_h<<<dim3(32, 40), 256, 0, stream>>>(wq, Bh, 2560, 2048);
    transpose_h<<<dim3(16, 40), 256, 0, stream>>>(wk, Bh + (size_t)2048 * 2560, 2560, 1024);
    transpose_h<<<dim3(16, 40), 256, 0, stream>>>(wv, Bh + (size_t)3072 * 2560, 2560, 1024);

    // 2. fused qkv projection (1-pass bf16)
    gemm1<<<dim3(32, 32), 256, 0, stream>>>(hs_bf, Bh, qb, kb, vt);

    // 3. RoPE tables + norms
    rope_tables<<<2048, 256, 0, stream>>>(ct, st);
    norm_q<<<4096, 256, 0, stream>>>(qb, qnw, ct, st);
    norm_k<<<4096, 256, 0, stream>>>(kb, knw, ct, st);

    // 4. attention (writes attnb over dead Bh)
    attn_fwd4<<<dim3(64, 8), 256, 0, stream>>>(qb, kb, vt, attnb);

    // 5. wo -> woT panel (over dead hs_bf), then output projection (1-pass)
    transpose_h<<<dim3(40, 32), 256, 0, stream>>>(wo, woh, 2048, 2560);
    gemm2<<<dim3(20, 32), 256, 0, stream>>>(attnb, woh, (float*)d_out);
}

// Round 10
// 353.471 us; speedup vs baseline: 3.3706x; 1.1603x over previous
//
#include <hip/hip_runtime.h>
#include <stdint.h>
#include <math.h>

typedef __bf16 bf16_t;
typedef __bf16 bf16x8 __attribute__((ext_vector_type(8)));
typedef __bf16 bf16x4 __attribute__((ext_vector_type(4)));
typedef float f32x4 __attribute__((ext_vector_type(4)));

#define GLD_LDS16(g, l)                                             \
    __builtin_amdgcn_global_load_lds(                               \
        (const __attribute__((address_space(1))) void*)(g),         \
        (__attribute__((address_space(3))) void*)(l), 16, 0, 0)

// ---------------------------------------------------------------------------
// fp32 -> bf16 elementwise (float4 -> bf16x4)
// ---------------------------------------------------------------------------
__global__ __launch_bounds__(256)
void conv_bf16(const float* __restrict__ in, bf16_t* __restrict__ out, int n4)
{
    int i = blockIdx.x * 256 + threadIdx.x;
    if (i >= n4) return;
    float4 v = ((const float4*)in)[i];
    bf16x4 o = { (bf16_t)v.x, (bf16_t)v.y, (bf16_t)v.z, (bf16_t)v.w };
    ((bf16x4*)out)[i] = o;
}

// ---------------------------------------------------------------------------
// transpose + convert: in [R][C] fp32 -> out [C][R] bf16
// ---------------------------------------------------------------------------
__global__ __launch_bounds__(256)
void transpose_h(const float* __restrict__ in, bf16_t* __restrict__ out,
                 int R, int C)
{
    __shared__ float t[64][65];
    const int r0 = blockIdx.y * 64, c0 = blockIdx.x * 64;
#pragma unroll
    for (int i = 0; i < 16; ++i) {
        int f = threadIdx.x + i * 256;
        int r = f >> 6, c = f & 63;
        t[r][c] = in[(size_t)(r0 + r) * C + c0 + c];
    }
    __syncthreads();
#pragma unroll
    for (int i = 0; i < 16; ++i) {
        int f = threadIdx.x + i * 256;
        int r = f >> 6, c = f & 63;
        out[(size_t)(c0 + r) * R + r0 + c] = (bf16_t)t[c][r];
    }
}

// ---------------------------------------------------------------------------
// RoPE cos/sin tables via fp64 (exact angle reduction)
// ---------------------------------------------------------------------------
__global__ __launch_bounds__(256)
void rope_tables(float* __restrict__ ct, float* __restrict__ st)
{
    int t = blockIdx.x * 256 + threadIdx.x;   // 4096*128
    int s = t >> 7, j = t & 127;
    double inv = exp2((double)j * (-13.28771237954945 / 128.0)); // log2(10000)
    double ang = fmod((double)s * inv, 6.283185307179586476925286766559);
    ct[t] = (float)cos(ang);
    st[t] = (float)sin(ang);
}

// ---------------------------------------------------------------------------
// GEMM1 (fused qkv, 1-pass bf16): A[4096][2560] bf16 x Bh^T[4096][2560] bf16.
// Epilogue: q[4096][2048] | k_raw[4096][1024] | vt2 tiled+swizzled
//   vt2[kvh][kt][dd 256][keys 32], 16B blocks XOR'd by (dd&3).
// ---------------------------------------------------------------------------
__global__ __launch_bounds__(256)
void gemm1(const bf16_t* __restrict__ A, const bf16_t* __restrict__ Bh,
           bf16_t* __restrict__ qb, bf16_t* __restrict__ kb,
           bf16_t* __restrict__ vt)
{
    __shared__ __attribute__((aligned(16))) bf16_t As[128 * 32];
    __shared__ __attribute__((aligned(16))) bf16_t Bs[128 * 32];
    const int tid = threadIdx.x, lane = tid & 63, wid = tid >> 6;
    const int g = lane >> 4, c16 = lane & 15;
    const int m0 = blockIdx.y * 128, n0 = blockIdx.x * 128;
    const int wm = wid >> 1, wn = wid & 1;

    f32x4 acc[4][4];
#pragma unroll
    for (int i = 0; i < 4; ++i)
#pragma unroll
        for (int j = 0; j < 4; ++j) acc[i][j] = (f32x4)(0.f);

    const int f0 = tid, f1 = tid + 256;
    for (int k0 = 0; k0 < 2560; k0 += 32) {
        __syncthreads();
        GLD_LDS16(A + (size_t)(m0 + (f0 >> 2)) * 2560 + k0 + (f0 & 3) * 8,
                  (char*)As + wid * 1024);
        GLD_LDS16(A + (size_t)(m0 + (f1 >> 2)) * 2560 + k0 + (f1 & 3) * 8,
                  (char*)As + wid * 1024 + 4096);
        GLD_LDS16(Bh + (size_t)(n0 + (f0 >> 2)) * 2560 + k0 + (f0 & 3) * 8,
                  (char*)Bs + wid * 1024);
        GLD_LDS16(Bh + (size_t)(n0 + (f1 >> 2)) * 2560 + k0 + (f1 & 3) * 8,
                  (char*)Bs + wid * 1024 + 4096);
        __syncthreads();
        bf16x8 af[4], bf[4];
#pragma unroll
        for (int m = 0; m < 4; ++m)
            af[m] = *(const bf16x8*)(As + (wm * 64 + m * 16 + c16) * 32 + g * 8);
#pragma unroll
        for (int n = 0; n < 4; ++n)
            bf[n] = *(const bf16x8*)(Bs + (wn * 64 + n * 16 + c16) * 32 + g * 8);
#pragma unroll
        for (int m = 0; m < 4; ++m)
#pragma unroll
            for (int n = 0; n < 4; ++n)
                acc[m][n] = __builtin_amdgcn_mfma_f32_16x16x32_bf16(af[m], bf[n], acc[m][n], 0, 0, 0);
    }

    if (n0 < 2048) {          // q region
#pragma unroll
        for (int m = 0; m < 4; ++m)
#pragma unroll
            for (int n = 0; n < 4; ++n) {
                int col = n0 + wn * 64 + n * 16 + c16;
                int rowb = m0 + wm * 64 + m * 16 + g * 4;
#pragma unroll
                for (int r = 0; r < 4; ++r)
                    qb[(size_t)(rowb + r) * 2048 + col] = (bf16_t)acc[m][n][r];
            }
    } else if (n0 < 3072) {   // k region (raw, s-major; re-tiled by norm_k)
#pragma unroll
        for (int m = 0; m < 4; ++m)
#pragma unroll
            for (int n = 0; n < 4; ++n) {
                int col = n0 + wn * 64 + n * 16 + c16 - 2048;
                int rowb = m0 + wm * 64 + m * 16 + g * 4;
#pragma unroll
                for (int r = 0; r < 4; ++r)
                    kb[(size_t)(rowb + r) * 1024 + col] = (bf16_t)acc[m][n][r];
            }
    } else {                  // v region -> vt2 tiled + swizzled
#pragma unroll
        for (int m = 0; m < 4; ++m)
#pragma unroll
            for (int n = 0; n < 4; ++n) {
                int d = n0 + wn * 64 + n * 16 + c16 - 3072;   // 0..1023
                int rowb = m0 + wm * 64 + m * 16 + g * 4;     // s (mult of 4)
                int kvh_ = d >> 8, dd = d & 255;
                int kt = rowb >> 5, key = rowb & 31;
                bf16x4 hv;
#pragma unroll
                for (int r = 0; r < 4; ++r) hv[r] = (bf16_t)acc[m][n][r];
                size_t off = (size_t)kvh_ * 1048576 + (size_t)kt * 8192
                           + dd * 32 + (((key >> 3) ^ (dd & 3)) << 3) + (key & 7);
                *(bf16x4*)(vt + off) = hv;
            }
    }
}

// ---------------------------------------------------------------------------
// RMSNorm + RoPE on q (in-place, plain bf16 [4096][2048]).
// ---------------------------------------------------------------------------
__global__ __launch_bounds__(256)
void norm_q(bf16_t* __restrict__ qb, const float* __restrict__ w,
            const float* __restrict__ ct, const float* __restrict__ st)
{
    const int s = blockIdx.x, t = threadIdx.x;
    const int h = t >> 5, l = t & 31;
    bf16_t* base = qb + (size_t)s * 2048 + h * 256 + l * 8;
    bf16x8 hv = *(const bf16x8*)base;
    float x[8], ss = 0.f;
#pragma unroll
    for (int j = 0; j < 8; ++j) { x[j] = (float)hv[j]; ss += x[j] * x[j]; }
#pragma unroll
    for (int mk = 1; mk < 32; mk <<= 1) ss += __shfl_xor(ss, mk);
    const float rs = rsqrtf(ss * (1.f / 256.f) + 1e-6f);
    float4 w0 = *(const float4*)(w + l * 8);
    float4 w1 = *(const float4*)(w + l * 8 + 4);
    float wa[8] = { w0.x, w0.y, w0.z, w0.w, w1.x, w1.y, w1.z, w1.w };
    float xn[8];
#pragma unroll
    for (int j = 0; j < 8; ++j) xn[j] = x[j] * rs * (1.f + wa[j]);
    const int d0 = (l * 8) & 127;
    float4 c0 = *(const float4*)(ct + s * 128 + d0);
    float4 c1 = *(const float4*)(ct + s * 128 + d0 + 4);
    float4 s0 = *(const float4*)(st + s * 128 + d0);
    float4 s1 = *(const float4*)(st + s * 128 + d0 + 4);
    float cc[8] = { c0.x, c0.y, c0.z, c0.w, c1.x, c1.y, c1.z, c1.w };
    float sn[8] = { s0.x, s0.y, s0.z, s0.w, s1.x, s1.y, s1.z, s1.w };
    const bool upper = (l >= 16);
    bf16x8 oh;
#pragma unroll
    for (int j = 0; j < 8; ++j) {
        float pn = __shfl_xor(xn[j], 16);
        float rot = upper ? pn : -pn;
        oh[j] = (bf16_t)(xn[j] * cc[j] + rot * sn[j]);
    }
    *(bf16x8*)base = oh;
}

// ---------------------------------------------------------------------------
// RMSNorm + RoPE on k; reads raw [4096][1024], writes tiled+swizzled
//   kb2[kvh][kt][key 32][d 256], 16B blocks XOR'd by (s&7).
// ---------------------------------------------------------------------------
__global__ __launch_bounds__(256)
void norm_k(const bf16_t* __restrict__ kraw, bf16_t* __restrict__ kb2,
            const float* __restrict__ w, const float* __restrict__ ct,
            const float* __restrict__ st)
{
    const int s = blockIdx.x, t = threadIdx.x;
    const int h = t >> 6, l = t & 63;          // h == kvh
    const bf16_t* base = kraw + (size_t)s * 1024 + h * 256 + l * 4;
    bf16x4 hv = *(const bf16x4*)base;
    float x[4], ss = 0.f;
#pragma unroll
    for (int j = 0; j < 4; ++j) { x[j] = (float)hv[j]; ss += x[j] * x[j]; }
#pragma unroll
    for (int mk = 1; mk < 64; mk <<= 1) ss += __shfl_xor(ss, mk);
    const float rs = rsqrtf(ss * (1.f / 256.f) + 1e-6f);
    float4 w0 = *(const float4*)(w + l * 4);
    float wa[4] = { w0.x, w0.y, w0.z, w0.w };
    float xn[4];
#pragma unroll
    for (int j = 0; j < 4; ++j) xn[j] = x[j] * rs * (1.f + wa[j]);
    const int d0 = (l * 4) & 127;
    float4 c0 = *(const float4*)(ct + s * 128 + d0);
    float4 s0 = *(const float4*)(st + s * 128 + d0);
    float cc[4] = { c0.x, c0.y, c0.z, c0.w };
    float sn[4] = { s0.x, s0.y, s0.z, s0.w };
    const bool upper = (l >= 32);
    bf16x4 oh;
#pragma unroll
    for (int j = 0; j < 4; ++j) {
        float pn = __shfl_xor(xn[j], 32);
        float rot = upper ? pn : -pn;
        oh[j] = (bf16_t)(xn[j] * cc[j] + rot * sn[j]);
    }
    bf16_t* dst = kb2 + (size_t)h * 1048576 + (size_t)(s >> 5) * 8192
                + (s & 31) * 256 + (((l >> 1) ^ (s & 7)) << 3) + (l & 1) * 4;
    *(bf16x4*)dst = oh;
}

// ---------------------------------------------------------------------------
// Sliding-window GQA flash attention, pre-tiled K/V, dbuf LDS staging.
// grid (8 h, 64 qt) -> bid%8 == h pins each head to one XCD's L2.
// exp2-domain softmax, defer-max THR=8, split QK chains, setprio.
// ---------------------------------------------------------------------------
__global__ __launch_bounds__(256)
void attn_fwd5(const bf16_t* __restrict__ qb, const bf16_t* __restrict__ kb2,
               const bf16_t* __restrict__ vt2, bf16_t* __restrict__ attn)
{
    __shared__ __attribute__((aligned(16))) char smem[2 * 32768];
    __shared__ __attribute__((aligned(16))) bf16_t P[4][16][40];
    const int tid = threadIdx.x, lane = tid & 63, wid = tid >> 6;
    const int g = lane >> 4, c16 = lane & 15;
    const int h = blockIdx.x, kvh = h >> 1;
    const int by = blockIdx.y;
    const int qt = (by & 1) ? (63 - (by >> 1)) : (by >> 1);   // balance pair
    const int qrow0 = qt * 64 + wid * 16;

    const char* kslab = (const char*)kb2 + (size_t)kvh * 2097152;
    const char* vslab = (const char*)vt2 + (size_t)kvh * 2097152;

    bf16x8 qf[8];
#pragma unroll
    for (int c = 0; c < 8; ++c)
        qf[c] = *(const bf16x8*)(qb + (size_t)(qrow0 + c16) * 2048 + h * 256 + c * 32 + g * 8);

    float mrow[4] = { -1e30f, -1e30f, -1e30f, -1e30f };
    float lrow[4] = { 0.f, 0.f, 0.f, 0.f };
    f32x4 acc[16];
#pragma unroll
    for (int nd = 0; nd < 16; ++nd) acc[nd] = (f32x4)(0.f);

    auto STAGE = [&](int buf, int kt) {
        char* Kd = smem + buf * 32768;
        char* Vd = smem + buf * 32768 + 16384;
        const char* ks = kslab + (size_t)kt * 16384;
        const char* vs = vslab + (size_t)kt * 16384;
#pragma unroll
        for (int j = 0; j < 4; ++j)
            GLD_LDS16(ks + (size_t)(j * 256 + tid) * 16, Kd + (j * 256 + wid * 64) * 16);
#pragma unroll
        for (int j = 0; j < 4; ++j)
            GLD_LDS16(vs + (size_t)(j * 256 + tid) * 16, Vd + (j * 256 + wid * 64) * 16);
    };

    const int ktb_lo = (qt >= 16) ? 2 * qt - 32 : 0;
    const int ktb_hi = 2 * qt + 1;
    int cur = 0;
    STAGE(0, ktb_lo);
    __syncthreads();

    const int swk = (c16 & 7) << 4;
    const int swv = (g ^ (c16 & 3)) << 4;
    const float S2 = 0.090168441f;   // 2^-4 * log2(e)

    for (int kt = ktb_lo; kt <= ktb_hi; ++kt) {
        if (kt < ktb_hi) STAGE(cur ^ 1, kt + 1);

        if (kt * 32 <= qrow0 + 15 && kt * 32 + 31 >= qrow0 - 1023) {
            const char* Kc = smem + cur * 32768;
            const char* Vc = smem + cur * 32768 + 16384;

            f32x4 scA[2], scB[2];
#pragma unroll
            for (int n = 0; n < 2; ++n) { scA[n] = (f32x4)(0.f); scB[n] = (f32x4)(0.f); }
            __builtin_amdgcn_s_setprio(1);
#pragma unroll
            for (int n = 0; n < 2; ++n) {
                const char* kr = Kc + (n * 16 + c16) * 512;
#pragma unroll
                for (int c = 0; c < 4; ++c) {
                    bf16x8 kf = *(const bf16x8*)(kr + ((((c * 4 + g) << 4) ^ swk)));
                    scA[n] = __builtin_amdgcn_mfma_f32_16x16x32_bf16(qf[c], kf, scA[n], 0, 0, 0);
                }
#pragma unroll
                for (int c = 4; c < 8; ++c) {
                    bf16x8 kf = *(const bf16x8*)(kr + ((((c * 4 + g) << 4) ^ swk)));
                    scB[n] = __builtin_amdgcn_mfma_f32_16x16x32_bf16(qf[c], kf, scB[n], 0, 0, 0);
                }
            }
            __builtin_amdgcn_s_setprio(0);

            float s2[2][4], rm[4] = { -1e30f, -1e30f, -1e30f, -1e30f };
#pragma unroll
            for (int n = 0; n < 2; ++n) {
                const int key = kt * 32 + n * 16 + c16;
#pragma unroll
                for (int r = 0; r < 4; ++r) {
                    const int q = qrow0 + g * 4 + r;
                    float v = (scA[n][r] + scB[n][r]) * S2;
                    bool valid = (key <= q) && (q - key < 1024);
                    v = valid ? v : -1e30f;
                    s2[n][r] = v;
                    rm[r] = fmaxf(rm[r], v);
                }
            }
#pragma unroll
            for (int mk = 1; mk < 16; mk <<= 1)
#pragma unroll
                for (int r = 0; r < 4; ++r) rm[r] = fmaxf(rm[r], __shfl_xor(rm[r], mk));

            bool grow = false;
#pragma unroll
            for (int r = 0; r < 4; ++r) grow = grow || (rm[r] > mrow[r] + 8.f);
            if (__any(grow)) {
                float alpha[4];
#pragma unroll
                for (int r = 0; r < 4; ++r) {
                    float nm = fmaxf(mrow[r], rm[r]);
                    alpha[r] = __builtin_amdgcn_exp2f(mrow[r] - nm);
                    mrow[r] = nm;
                    lrow[r] *= alpha[r];
                }
#pragma unroll
                for (int nd = 0; nd < 16; ++nd)
#pragma unroll
                    for (int r = 0; r < 4; ++r) acc[nd][r] *= alpha[r];
            }

            float psum[4] = { 0.f, 0.f, 0.f, 0.f };
#pragma unroll
            for (int n = 0; n < 2; ++n)
#pragma unroll
                for (int r = 0; r < 4; ++r) {
                    float sv = s2[n][r];
                    float pv = (sv > -1e29f) ? __builtin_amdgcn_exp2f(sv - mrow[r]) : 0.f;
                    s2[n][r] = pv;
                    psum[r] += pv;
                }
#pragma unroll
            for (int mk = 1; mk < 16; mk <<= 1)
#pragma unroll
                for (int r = 0; r < 4; ++r) psum[r] += __shfl_xor(psum[r], mk);
#pragma unroll
            for (int r = 0; r < 4; ++r) lrow[r] += psum[r];

#pragma unroll
            for (int n = 0; n < 2; ++n)
#pragma unroll
                for (int r = 0; r < 4; ++r)
                    P[wid][g * 4 + r][n * 16 + c16] = (bf16_t)s2[n][r];
            bf16x8 pa = *(const bf16x8*)(&P[wid][c16][g * 8]);
            __builtin_amdgcn_s_setprio(1);
#pragma unroll
            for (int nd = 0; nd < 16; ++nd) {
                bf16x8 vf = *(const bf16x8*)(Vc + (nd * 16 + c16) * 64 + swv);
                acc[nd] = __builtin_amdgcn_mfma_f32_16x16x32_bf16(pa, vf, acc[nd], 0, 0, 0);
            }
            __builtin_amdgcn_s_setprio(0);
        }
        __syncthreads();
        cur ^= 1;
    }

    float inv[4];
#pragma unroll
    for (int r = 0; r < 4; ++r) inv[r] = 1.f / lrow[r];
#pragma unroll
    for (int nd = 0; nd < 16; ++nd)
#pragma unroll
        for (int r = 0; r < 4; ++r) {
            int row = qrow0 + g * 4 + r;
            attn[(size_t)row * 2048 + h * 256 + nd * 16 + c16] =
                (bf16_t)(acc[nd][r] * inv[r]);
        }
}

// ---------------------------------------------------------------------------
// GEMM2 (1-pass bf16): out(fp32) = attn[4096][2048] @ woT[2560][2048]^T.
// ---------------------------------------------------------------------------
__global__ __launch_bounds__(256)
void gemm2(const bf16_t* __restrict__ A, const bf16_t* __restrict__ Bh,
           float* __restrict__ C)
{
    __shared__ __attribute__((aligned(16))) bf16_t As[128 * 32];
    __shared__ __attribute__((aligned(16))) bf16_t Bs[128 * 32];
    const int tid = threadIdx.x, lane = tid & 63, wid = tid >> 6;
    const int g = lane >> 4, c16 = lane & 15;
    const int m0 = blockIdx.y * 128, n0 = blockIdx.x * 128;
    const int wm = wid >> 1, wn = wid & 1;

    f32x4 acc[4][4];
#pragma unroll
    for (int i = 0; i < 4; ++i)
#pragma unroll
        for (int j = 0; j < 4; ++j) acc[i][j] = (f32x4)(0.f);

    const int f0 = tid, f1 = tid + 256;
    for (int k0 = 0; k0 < 2048; k0 += 32) {
        __syncthreads();
        GLD_LDS16(A + (size_t)(m0 + (f0 >> 2)) * 2048 + k0 + (f0 & 3) * 8,
                  (char*)As + wid * 1024);
        GLD_LDS16(A + (size_t)(m0 + (f1 >> 2)) * 2048 + k0 + (f1 & 3) * 8,
                  (char*)As + wid * 1024 + 4096);
        GLD_LDS16(Bh + (size_t)(n0 + (f0 >> 2)) * 2048 + k0 + (f0 & 3) * 8,
                  (char*)Bs + wid * 1024);
        GLD_LDS16(Bh + (size_t)(n0 + (f1 >> 2)) * 2048 + k0 + (f1 & 3) * 8,
                  (char*)Bs + wid * 1024 + 4096);
        __syncthreads();
        bf16x8 af[4], bf[4];
#pragma unroll
        for (int m = 0; m < 4; ++m)
            af[m] = *(const bf16x8*)(As + (wm * 64 + m * 16 + c16) * 32 + g * 8);
#pragma unroll
        for (int n = 0; n < 4; ++n)
            bf[n] = *(const bf16x8*)(Bs + (wn * 64 + n * 16 + c16) * 32 + g * 8);
#pragma unroll
        for (int m = 0; m < 4; ++m)
#pragma unroll
            for (int n = 0; n < 4; ++n)
                acc[m][n] = __builtin_amdgcn_mfma_f32_16x16x32_bf16(af[m], bf[n], acc[m][n], 0, 0, 0);
    }

#pragma unroll
    for (int m = 0; m < 4; ++m)
#pragma unroll
        for (int n = 0; n < 4; ++n)
#pragma unroll
            for (int r = 0; r < 4; ++r) {
                int row = m0 + wm * 64 + m * 16 + g * 4 + r;
                int col = n0 + wn * 64 + n * 16 + c16;
                C[(size_t)row * 2560 + col] = acc[m][n][r];
            }
}

// ---------------------------------------------------------------------------
// Workspace (peak ~79.7 MB, phase-aliased):
//   hs_bf [0,          20,971,520)  (dead after gemm1)
//   qb    [20,971,520, 37,748,736)
//   kb_raw[37,748,736, 46,137,344)  (dead after norm_k)
//   vt2   [46,137,344, 54,525,952)  tiled+swizzled
//   Bh    [54,525,952, 75,497,472)  (dead after gemm1)
//   kb2   [54,525,952, 62,914,560)  (over dead Bh; by norm_k)
//   ct    [75,497,472, 77,594,624)
//   st    [77,594,624, 79,691,776)
//   attnb [0,          16,777,216)  (over dead hs_bf)
//   woh   [20,971,520, 31,457,280)  (over dead qb, after attn)
// ---------------------------------------------------------------------------
extern "C" void kernel_launch(void* const* d_in, const int* in_sizes, int n_in,
                              void* d_out, int out_size, void* d_ws, size_t ws_size,
                              hipStream_t stream)
{
    (void)in_sizes; (void)n_in; (void)out_size; (void)ws_size;
    const float* hs  = (const float*)d_in[0];
    const float* wq  = (const float*)d_in[3];
    const float* wk  = (const float*)d_in[4];
    const float* wv  = (const float*)d_in[5];
    const float* wo  = (const float*)d_in[6];
    const float* qnw = (const float*)d_in[7];
    const float* knw = (const float*)d_in[8];

    char* ws = (char*)d_ws;
    bf16_t* hs_bf = (bf16_t*)(ws);
    bf16_t* qb    = (bf16_t*)(ws + 20971520);
    bf16_t* kraw  = (bf16_t*)(ws + 37748736);
    bf16_t* vt2   = (bf16_t*)(ws + 46137344);
    bf16_t* Bh    = (bf16_t*)(ws + 54525952);
    bf16_t* kb2   = (bf16_t*)(ws + 54525952);
    float*  ct    = (float*)(ws + 75497472);
    float*  st    = (float*)(ws + 77594624);
    bf16_t* attnb = (bf16_t*)(ws);
    bf16_t* woh   = (bf16_t*)(ws + 20971520);

    // 1. hs -> bf16; weights -> Bh panel [4096][2560]
    conv_bf16<<<10240, 256, 0, stream>>>(hs, hs_bf, 4096 * 2560 / 4);
    transpose_h<<<dim3(32, 40), 256, 0, stream>>>(wq, Bh, 2560, 2048);
    transpose_h<<<dim3(16, 40), 256, 0, stream>>>(wk, Bh + (size_t)2048 * 2560, 2560, 1024);
    transpose_h<<<dim3(16, 40), 256, 0, stream>>>(wv, Bh + (size_t)3072 * 2560, 2560, 1024);

    // 2. fused qkv projection (1-pass bf16); v written tiled+swizzled
    gemm1<<<dim3(32, 32), 256, 0, stream>>>(hs_bf, Bh, qb, kraw, vt2);

    // 3. RoPE tables + norms (norm_k re-tiles K into kb2 over dead Bh)
    rope_tables<<<2048, 256, 0, stream>>>(ct, st);
    norm_q<<<4096, 256, 0, stream>>>(qb, qnw, ct, st);
    norm_k<<<4096, 256, 0, stream>>>(kraw, kb2, knw, ct, st);

    // 4. attention (grid (h, qt) -> head-per-XCD pinning)
    attn_fwd5<<<dim3(8, 64), 256, 0, stream>>>(qb, kb2, vt2, attnb);

    // 5. wo -> woT panel (over dead qb), then output projection (1-pass)
    transpose_h<<<dim3(40, 32), 256, 0, stream>>>(wo, woh, 2048, 2560);
    gemm2<<<dim3(20, 32), 256, 0, stream>>>(attnb, woh, (float*)d_out);
}

// Round 11
// 307.971 us; speedup vs baseline: 3.8686x; 1.1477x over previous
//
#include <hip/hip_runtime.h>
#include <stdint.h>
#include <math.h>

typedef __bf16 bf16_t;
typedef __bf16 bf16x8 __attribute__((ext_vector_type(8)));
typedef __bf16 bf16x4 __attribute__((ext_vector_type(4)));
typedef float f32x4 __attribute__((ext_vector_type(4)));

#define GLD_LDS16(g, l)                                             \
    __builtin_amdgcn_global_load_lds(                               \
        (const __attribute__((address_space(1))) void*)(g),         \
        (__attribute__((address_space(3))) void*)(l), 16, 0, 0)

#define WAITV(N) asm volatile("s_waitcnt vmcnt(" #N ")" ::: "memory")
#define BARRIER() do { __builtin_amdgcn_sched_barrier(0);           \
                       __builtin_amdgcn_s_barrier();                \
                       __builtin_amdgcn_sched_barrier(0); } while (0)

// ---------------------------------------------------------------------------
// fp32 -> bf16 elementwise (float4 -> bf16x4)
// ---------------------------------------------------------------------------
__global__ __launch_bounds__(256)
void conv_bf16(const float* __restrict__ in, bf16_t* __restrict__ out, int n4)
{
    int i = blockIdx.x * 256 + threadIdx.x;
    if (i >= n4) return;
    float4 v = ((const float4*)in)[i];
    bf16x4 o = { (bf16_t)v.x, (bf16_t)v.y, (bf16_t)v.z, (bf16_t)v.w };
    ((bf16x4*)out)[i] = o;
}

// ---------------------------------------------------------------------------
// transpose + convert: in [R][C] fp32 -> out [C][R] bf16
// ---------------------------------------------------------------------------
__global__ __launch_bounds__(256)
void transpose_h(const float* __restrict__ in, bf16_t* __restrict__ out,
                 int R, int C)
{
    __shared__ float t[64][65];
    const int r0 = blockIdx.y * 64, c0 = blockIdx.x * 64;
#pragma unroll
    for (int i = 0; i < 16; ++i) {
        int f = threadIdx.x + i * 256;
        int r = f >> 6, c = f & 63;
        t[r][c] = in[(size_t)(r0 + r) * C + c0 + c];
    }
    __syncthreads();
#pragma unroll
    for (int i = 0; i < 16; ++i) {
        int f = threadIdx.x + i * 256;
        int r = f >> 6, c = f & 63;
        out[(size_t)(c0 + r) * R + r0 + c] = (bf16_t)t[c][r];
    }
}

// ---------------------------------------------------------------------------
// RoPE cos/sin tables via fp64 (exact angle reduction)
// ---------------------------------------------------------------------------
__global__ __launch_bounds__(256)
void rope_tables(float* __restrict__ ct, float* __restrict__ st)
{
    int t = blockIdx.x * 256 + threadIdx.x;   // 4096*128
    int s = t >> 7, j = t & 127;
    double inv = exp2((double)j * (-13.28771237954945 / 128.0)); // log2(10000)
    double ang = fmod((double)s * inv, 6.283185307179586476925286766559);
    ct[t] = (float)cos(ang);
    st[t] = (float)sin(ang);
}

// ---------------------------------------------------------------------------
// GEMM1 (fused qkv), 8-phase 256x256 tile, BK=64, 8 waves (2Mx4N), 128 KiB
// LDS double-buffer, XOR-swizzled (slot = b ^ (row&7), both sides), counted
// vmcnt (2) — never 0 in steady state.  K = 2560 -> 40 K-tiles.
// Epilogue: q[4096][2048] | k_raw[4096][1024] | vt2 tiled+swizzled.
// ---------------------------------------------------------------------------
__global__ __launch_bounds__(512, 2)
void gemm1(const bf16_t* __restrict__ A, const bf16_t* __restrict__ Bh,
           bf16_t* __restrict__ qb, bf16_t* __restrict__ kb,
           bf16_t* __restrict__ vt)
{
    __shared__ __attribute__((aligned(16))) char smem[131072];
    const int tid = threadIdx.x, lane = tid & 63, wid = tid >> 6;
    const int g = lane >> 4, c16 = lane & 15;
    const int wm = wid >> 2, wn = wid & 3;          // 2 x 4 wave grid
    const int m0 = blockIdx.y * 256, n0 = blockIdx.x * 256;
    const int swz = c16 & 7;
    const int NT = 40;                               // 2560 / 64

    f32x4 acc[8][4];
#pragma unroll
    for (int m = 0; m < 8; ++m)
#pragma unroll
        for (int n = 0; n < 4; ++n) acc[m][n] = (f32x4)(0.f);

    // stage A half-tile (128 rows x 64 k) of K-tile kt into buffer dbuf
    auto STAGE_A = [&](int dbuf, int kt, int half) {
#pragma unroll
        for (int pl = 0; pl < 2; ++pl) {
            int c = pl * 512 + tid;                 // chunk 0..1023
            int row = c >> 3, b = c & 7;
            GLD_LDS16(A + (size_t)(m0 + half * 128 + row) * 2560 + kt * 64
                        + ((b ^ (row & 7)) << 3),
                      smem + dbuf * 65536 + half * 16384
                        + (pl * 512 + wid * 64) * 16);
        }
    };
    // stage B quarter-pair qp (rows with (r&63)<32 for qp=0, >=32 for qp=1)
    auto STAGE_B = [&](int dbuf, int kt, int qp) {
#pragma unroll
        for (int pl = 0; pl < 2; ++pl) {
            int c = pl * 512 + tid;                 // chunk 0..1023
            int u = c >> 3, b = c & 7;              // u = row-within-unit
            int row = ((u >> 5) << 6) + qp * 32 + (u & 31);   // abs row 0..255
            int u0 = pl * 64 + wid * 8;
            int row0 = ((u0 >> 5) << 6) + qp * 32 + (u0 & 31);
            GLD_LDS16(Bh + (size_t)(n0 + row) * 2560 + kt * 64
                        + ((b ^ (row & 7)) << 3),
                      smem + dbuf * 65536 + 32768 + row0 * 128);
        }
    };

    // prologue: full tile 0 into buffer 0
    STAGE_A(0, 0, 0); STAGE_A(0, 0, 1); STAGE_B(0, 0, 0); STAGE_B(0, 0, 1);
    WAITV(2);          // A0,A1,Bq01 landed; Bq23 may fly (needed at p1)
    BARRIER();

    for (int t = 0; t < NT; ++t) {
        const int buf = t & 1, nbuf = buf ^ 1;
        const char* Ab = smem + buf * 65536;
        const char* Bb = smem + buf * 65536 + 32768;
        auto rdA = [&](int m, int kk) {
            return *(const bf16x8*)(Ab + (wm * 128 + m * 16 + c16) * 128
                                       + (((kk * 4 + g) ^ swz) << 4));
        };
        auto rdB = [&](int n, int kk) {
            return *(const bf16x8*)(Bb + (wn * 64 + n * 16 + c16) * 128
                                       + (((kk * 4 + g) ^ swz) << 4));
        };
        bf16x8 a[8], b0, b1, b2, b3;

        // ---- phase 0: n{0,1} kk0 -------------------------------------
#pragma unroll
        for (int m = 0; m < 8; ++m) a[m] = rdA(m, 0);
        b0 = rdB(0, 0); b1 = rdB(1, 0);
        if (t + 1 < NT) STAGE_A(nbuf, t + 1, 0);
        BARRIER();
        __builtin_amdgcn_s_setprio(1);
#pragma unroll
        for (int m = 0; m < 8; ++m) {
            acc[m][0] = __builtin_amdgcn_mfma_f32_16x16x32_bf16(a[m], b0, acc[m][0], 0, 0, 0);
            acc[m][1] = __builtin_amdgcn_mfma_f32_16x16x32_bf16(a[m], b1, acc[m][1], 0, 0, 0);
        }
        __builtin_amdgcn_s_setprio(0);
        if (t + 1 < NT) { WAITV(2); } else { WAITV(0); }   // Bq23(t) landed
        BARRIER();

        // ---- phase 1: n{2,3} kk0 -------------------------------------
        b2 = rdB(2, 0); b3 = rdB(3, 0);
        if (t + 1 < NT) STAGE_A(nbuf, t + 1, 1);
        BARRIER();
        __builtin_amdgcn_s_setprio(1);
#pragma unroll
        for (int m = 0; m < 8; ++m) {
            acc[m][2] = __builtin_amdgcn_mfma_f32_16x16x32_bf16(a[m], b2, acc[m][2], 0, 0, 0);
            acc[m][3] = __builtin_amdgcn_mfma_f32_16x16x32_bf16(a[m], b3, acc[m][3], 0, 0, 0);
        }
        __builtin_amdgcn_s_setprio(0);
        BARRIER();

        // ---- phase 2: n{0,1} kk1 -------------------------------------
#pragma unroll
        for (int m = 0; m < 8; ++m) a[m] = rdA(m, 1);
        b0 = rdB(0, 1); b1 = rdB(1, 1);
        if (t + 1 < NT) STAGE_B(nbuf, t + 1, 0);
        BARRIER();
        __builtin_amdgcn_s_setprio(1);
#pragma unroll
        for (int m = 0; m < 8; ++m) {
            acc[m][0] = __builtin_amdgcn_mfma_f32_16x16x32_bf16(a[m], b0, acc[m][0], 0, 0, 0);
            acc[m][1] = __builtin_amdgcn_mfma_f32_16x16x32_bf16(a[m], b1, acc[m][1], 0, 0, 0);
        }
        __builtin_amdgcn_s_setprio(0);
        BARRIER();

        // ---- phase 3: n{2,3} kk1 -------------------------------------
        b2 = rdB(2, 1); b3 = rdB(3, 1);
        if (t + 1 < NT) STAGE_B(nbuf, t + 1, 1);
        BARRIER();
        __builtin_amdgcn_s_setprio(1);
#pragma unroll
        for (int m = 0; m < 8; ++m) {
            acc[m][2] = __builtin_amdgcn_mfma_f32_16x16x32_bf16(a[m], b2, acc[m][2], 0, 0, 0);
            acc[m][3] = __builtin_amdgcn_mfma_f32_16x16x32_bf16(a[m], b3, acc[m][3], 0, 0, 0);
        }
        __builtin_amdgcn_s_setprio(0);
        if (t + 1 < NT) WAITV(2);   // A0,A1,Bq01(t+1) landed; Bq23(t+1) flies
        BARRIER();
    }

    // -------- epilogue: route by output column region ------------------
    if (n0 < 2048) {          // q region
#pragma unroll
        for (int m = 0; m < 8; ++m)
#pragma unroll
            for (int n = 0; n < 4; ++n) {
                int col = n0 + wn * 64 + n * 16 + c16;
                int rowb = m0 + wm * 128 + m * 16 + g * 4;
#pragma unroll
                for (int r = 0; r < 4; ++r)
                    qb[(size_t)(rowb + r) * 2048 + col] = (bf16_t)acc[m][n][r];
            }
    } else if (n0 < 3072) {   // k region (raw, re-tiled by norm_k)
#pragma unroll
        for (int m = 0; m < 8; ++m)
#pragma unroll
            for (int n = 0; n < 4; ++n) {
                int col = n0 + wn * 64 + n * 16 + c16 - 2048;
                int rowb = m0 + wm * 128 + m * 16 + g * 4;
#pragma unroll
                for (int r = 0; r < 4; ++r)
                    kb[(size_t)(rowb + r) * 1024 + col] = (bf16_t)acc[m][n][r];
            }
    } else {                  // v region -> vt2 tiled + swizzled
#pragma unroll
        for (int m = 0; m < 8; ++m)
#pragma unroll
            for (int n = 0; n < 4; ++n) {
                int d = n0 + wn * 64 + n * 16 + c16 - 3072;   // 0..1023
                int rowb = m0 + wm * 128 + m * 16 + g * 4;    // s (mult of 4)
                int kvh_ = d >> 8, dd = d & 255;
                int kt = rowb >> 5, key = rowb & 31;
                bf16x4 hv;
#pragma unroll
                for (int r = 0; r < 4; ++r) hv[r] = (bf16_t)acc[m][n][r];
                size_t off = (size_t)kvh_ * 1048576 + (size_t)kt * 8192
                           + dd * 32 + (((key >> 3) ^ (dd & 3)) << 3) + (key & 7);
                *(bf16x4*)(vt + off) = hv;
            }
    }
}

// ---------------------------------------------------------------------------
// RMSNorm + RoPE on q (in-place, plain bf16 [4096][2048]).
// ---------------------------------------------------------------------------
__global__ __launch_bounds__(256)
void norm_q(bf16_t* __restrict__ qb, const float* __restrict__ w,
            const float* __restrict__ ct, const float* __restrict__ st)
{
    const int s = blockIdx.x, t = threadIdx.x;
    const int h = t >> 5, l = t & 31;
    bf16_t* base = qb + (size_t)s * 2048 + h * 256 + l * 8;
    bf16x8 hv = *(const bf16x8*)base;
    float x[8], ss = 0.f;
#pragma unroll
    for (int j = 0; j < 8; ++j) { x[j] = (float)hv[j]; ss += x[j] * x[j]; }
#pragma unroll
    for (int mk = 1; mk < 32; mk <<= 1) ss += __shfl_xor(ss, mk);
    const float rs = rsqrtf(ss * (1.f / 256.f) + 1e-6f);
    float4 w0 = *(const float4*)(w + l * 8);
    float4 w1 = *(const float4*)(w + l * 8 + 4);
    float wa[8] = { w0.x, w0.y, w0.z, w0.w, w1.x, w1.y, w1.z, w1.w };
    float xn[8];
#pragma unroll
    for (int j = 0; j < 8; ++j) xn[j] = x[j] * rs * (1.f + wa[j]);
    const int d0 = (l * 8) & 127;
    float4 c0 = *(const float4*)(ct + s * 128 + d0);
    float4 c1 = *(const float4*)(ct + s * 128 + d0 + 4);
    float4 s0 = *(const float4*)(st + s * 128 + d0);
    float4 s1 = *(const float4*)(st + s * 128 + d0 + 4);
    float cc[8] = { c0.x, c0.y, c0.z, c0.w, c1.x, c1.y, c1.z, c1.w };
    float sn[8] = { s0.x, s0.y, s0.z, s0.w, s1.x, s1.y, s1.z, s1.w };
    const bool upper = (l >= 16);
    bf16x8 oh;
#pragma unroll
    for (int j = 0; j < 8; ++j) {
        float pn = __shfl_xor(xn[j], 16);
        float rot = upper ? pn : -pn;
        oh[j] = (bf16_t)(xn[j] * cc[j] + rot * sn[j]);
    }
    *(bf16x8*)base = oh;
}

// ---------------------------------------------------------------------------
// RMSNorm + RoPE on k; reads raw [4096][1024], writes tiled+swizzled
//   kb2[kvh][kt][key 32][d 256], 16B blocks XOR'd by (s&7).
// ---------------------------------------------------------------------------
__global__ __launch_bounds__(256)
void norm_k(const bf16_t* __restrict__ kraw, bf16_t* __restrict__ kb2,
            const float* __restrict__ w, const float* __restrict__ ct,
            const float* __restrict__ st)
{
    const int s = blockIdx.x, t = threadIdx.x;
    const int h = t >> 6, l = t & 63;          // h == kvh
    const bf16_t* base = kraw + (size_t)s * 1024 + h * 256 + l * 4;
    bf16x4 hv = *(const bf16x4*)base;
    float x[4], ss = 0.f;
#pragma unroll
    for (int j = 0; j < 4; ++j) { x[j] = (float)hv[j]; ss += x[j] * x[j]; }
#pragma unroll
    for (int mk = 1; mk < 64; mk <<= 1) ss += __shfl_xor(ss, mk);
    const float rs = rsqrtf(ss * (1.f / 256.f) + 1e-6f);
    float4 w0 = *(const float4*)(w + l * 4);
    float wa[4] = { w0.x, w0.y, w0.z, w0.w };
    float xn[4];
#pragma unroll
    for (int j = 0; j < 4; ++j) xn[j] = x[j] * rs * (1.f + wa[j]);
    const int d0 = (l * 4) & 127;
    float4 c0 = *(const float4*)(ct + s * 128 + d0);
    float4 s0 = *(const float4*)(st + s * 128 + d0);
    float cc[4] = { c0.x, c0.y, c0.z, c0.w };
    float sn[4] = { s0.x, s0.y, s0.z, s0.w };
    const bool upper = (l >= 32);
    bf16x4 oh;
#pragma unroll
    for (int j = 0; j < 4; ++j) {
        float pn = __shfl_xor(xn[j], 32);
        float rot = upper ? pn : -pn;
        oh[j] = (bf16_t)(xn[j] * cc[j] + rot * sn[j]);
    }
    bf16_t* dst = kb2 + (size_t)h * 1048576 + (size_t)(s >> 5) * 8192
                + (s & 31) * 256 + (((l >> 1) ^ (s & 7)) << 3) + (l & 1) * 4;
    *(bf16x4*)dst = oh;
}

// ---------------------------------------------------------------------------
// Sliding-window GQA flash attention, pre-tiled K/V, dbuf LDS staging.
// grid (8 h, 64 qt) -> bid%8 == h pins each head to one XCD's L2.
// ---------------------------------------------------------------------------
__global__ __launch_bounds__(256)
void attn_fwd5(const bf16_t* __restrict__ qb, const bf16_t* __restrict__ kb2,
               const bf16_t* __restrict__ vt2, bf16_t* __restrict__ attn)
{
    __shared__ __attribute__((aligned(16))) char smem[2 * 32768];
    __shared__ __attribute__((aligned(16))) bf16_t P[4][16][40];
    const int tid = threadIdx.x, lane = tid & 63, wid = tid >> 6;
    const int g = lane >> 4, c16 = lane & 15;
    const int h = blockIdx.x, kvh = h >> 1;
    const int by = blockIdx.y;
    const int qt = (by & 1) ? (63 - (by >> 1)) : (by >> 1);   // balance pair
    const int qrow0 = qt * 64 + wid * 16;

    const char* kslab = (const char*)kb2 + (size_t)kvh * 2097152;
    const char* vslab = (const char*)vt2 + (size_t)kvh * 2097152;

    bf16x8 qf[8];
#pragma unroll
    for (int c = 0; c < 8; ++c)
        qf[c] = *(const bf16x8*)(qb + (size_t)(qrow0 + c16) * 2048 + h * 256 + c * 32 + g * 8);

    float mrow[4] = { -1e30f, -1e30f, -1e30f, -1e30f };
    float lrow[4] = { 0.f, 0.f, 0.f, 0.f };
    f32x4 acc[16];
#pragma unroll
    for (int nd = 0; nd < 16; ++nd) acc[nd] = (f32x4)(0.f);

    auto STAGE = [&](int buf, int kt) {
        char* Kd = smem + buf * 32768;
        char* Vd = smem + buf * 32768 + 16384;
        const char* ks = kslab + (size_t)kt * 16384;
        const char* vs = vslab + (size_t)kt * 16384;
#pragma unroll
        for (int j = 0; j < 4; ++j)
            GLD_LDS16(ks + (size_t)(j * 256 + tid) * 16, Kd + (j * 256 + wid * 64) * 16);
#pragma unroll
        for (int j = 0; j < 4; ++j)
            GLD_LDS16(vs + (size_t)(j * 256 + tid) * 16, Vd + (j * 256 + wid * 64) * 16);
    };

    const int ktb_lo = (qt >= 16) ? 2 * qt - 32 : 0;
    const int ktb_hi = 2 * qt + 1;
    int cur = 0;
    STAGE(0, ktb_lo);
    __syncthreads();

    const int swk = (c16 & 7) << 4;
    const int swv = (g ^ (c16 & 3)) << 4;
    const float S2 = 0.090168441f;   // 2^-4 * log2(e)

    for (int kt = ktb_lo; kt <= ktb_hi; ++kt) {
        if (kt < ktb_hi) STAGE(cur ^ 1, kt + 1);

        if (kt * 32 <= qrow0 + 15 && kt * 32 + 31 >= qrow0 - 1023) {
            const char* Kc = smem + cur * 32768;
            const char* Vc = smem + cur * 32768 + 16384;

            f32x4 scA[2], scB[2];
#pragma unroll
            for (int n = 0; n < 2; ++n) { scA[n] = (f32x4)(0.f); scB[n] = (f32x4)(0.f); }
            __builtin_amdgcn_s_setprio(1);
#pragma unroll
            for (int n = 0; n < 2; ++n) {
                const char* kr = Kc + (n * 16 + c16) * 512;
#pragma unroll
                for (int c = 0; c < 4; ++c) {
                    bf16x8 kf = *(const bf16x8*)(kr + ((((c * 4 + g) << 4) ^ swk)));
                    scA[n] = __builtin_amdgcn_mfma_f32_16x16x32_bf16(qf[c], kf, scA[n], 0, 0, 0);
                }
#pragma unroll
                for (int c = 4; c < 8; ++c) {
                    bf16x8 kf = *(const bf16x8*)(kr + ((((c * 4 + g) << 4) ^ swk)));
                    scB[n] = __builtin_amdgcn_mfma_f32_16x16x32_bf16(qf[c], kf, scB[n], 0, 0, 0);
                }
            }
            __builtin_amdgcn_s_setprio(0);

            float s2[2][4], rm[4] = { -1e30f, -1e30f, -1e30f, -1e30f };
#pragma unroll
            for (int n = 0; n < 2; ++n) {
                const int key = kt * 32 + n * 16 + c16;
#pragma unroll
                for (int r = 0; r < 4; ++r) {
                    const int q = qrow0 + g * 4 + r;
                    float v = (scA[n][r] + scB[n][r]) * S2;
                    bool valid = (key <= q) && (q - key < 1024);
                    v = valid ? v : -1e30f;
                    s2[n][r] = v;
                    rm[r] = fmaxf(rm[r], v);
                }
            }
#pragma unroll
            for (int mk = 1; mk < 16; mk <<= 1)
#pragma unroll
                for (int r = 0; r < 4; ++r) rm[r] = fmaxf(rm[r], __shfl_xor(rm[r], mk));

            bool grow = false;
#pragma unroll
            for (int r = 0; r < 4; ++r) grow = grow || (rm[r] > mrow[r] + 8.f);
            if (__any(grow)) {
                float alpha[4];
#pragma unroll
                for (int r = 0; r < 4; ++r) {
                    float nm = fmaxf(mrow[r], rm[r]);
                    alpha[r] = __builtin_amdgcn_exp2f(mrow[r] - nm);
                    mrow[r] = nm;
                    lrow[r] *= alpha[r];
                }
#pragma unroll
                for (int nd = 0; nd < 16; ++nd)
#pragma unroll
                    for (int r = 0; r < 4; ++r) acc[nd][r] *= alpha[r];
            }

            float psum[4] = { 0.f, 0.f, 0.f, 0.f };
#pragma unroll
            for (int n = 0; n < 2; ++n)
#pragma unroll
                for (int r = 0; r < 4; ++r) {
                    float sv = s2[n][r];
                    float pv = (sv > -1e29f) ? __builtin_amdgcn_exp2f(sv - mrow[r]) : 0.f;
                    s2[n][r] = pv;
                    psum[r] += pv;
                }
#pragma unroll
            for (int mk = 1; mk < 16; mk <<= 1)
#pragma unroll
                for (int r = 0; r < 4; ++r) psum[r] += __shfl_xor(psum[r], mk);
#pragma unroll
            for (int r = 0; r < 4; ++r) lrow[r] += psum[r];

#pragma unroll
            for (int n = 0; n < 2; ++n)
#pragma unroll
                for (int r = 0; r < 4; ++r)
                    P[wid][g * 4 + r][n * 16 + c16] = (bf16_t)s2[n][r];
            bf16x8 pa = *(const bf16x8*)(&P[wid][c16][g * 8]);
            __builtin_amdgcn_s_setprio(1);
#pragma unroll
            for (int nd = 0; nd < 16; ++nd) {
                bf16x8 vf = *(const bf16x8*)(Vc + (nd * 16 + c16) * 64 + swv);
                acc[nd] = __builtin_amdgcn_mfma_f32_16x16x32_bf16(pa, vf, acc[nd], 0, 0, 0);
            }
            __builtin_amdgcn_s_setprio(0);
        }
        __syncthreads();
        cur ^= 1;
    }

    float inv[4];
#pragma unroll
    for (int r = 0; r < 4; ++r) inv[r] = 1.f / lrow[r];
#pragma unroll
    for (int nd = 0; nd < 16; ++nd)
#pragma unroll
        for (int r = 0; r < 4; ++r) {
            int row = qrow0 + g * 4 + r;
            attn[(size_t)row * 2048 + h * 256 + nd * 16 + c16] =
                (bf16_t)(acc[nd][r] * inv[r]);
        }
}

// ---------------------------------------------------------------------------
// GEMM2 (1-pass bf16): out(fp32) = attn[4096][2048] @ woT[2560][2048]^T.
// ---------------------------------------------------------------------------
__global__ __launch_bounds__(256)
void gemm2(const bf16_t* __restrict__ A, const bf16_t* __restrict__ Bh,
           float* __restrict__ C)
{
    __shared__ __attribute__((aligned(16))) bf16_t As[128 * 32];
    __shared__ __attribute__((aligned(16))) bf16_t Bs[128 * 32];
    const int tid = threadIdx.x, lane = tid & 63, wid = tid >> 6;
    const int g = lane >> 4, c16 = lane & 15;
    const int m0 = blockIdx.y * 128, n0 = blockIdx.x * 128;
    const int wm = wid >> 1, wn = wid & 1;

    f32x4 acc[4][4];
#pragma unroll
    for (int i = 0; i < 4; ++i)
#pragma unroll
        for (int j = 0; j < 4; ++j) acc[i][j] = (f32x4)(0.f);

    const int f0 = tid, f1 = tid + 256;
    for (int k0 = 0; k0 < 2048; k0 += 32) {
        __syncthreads();
        GLD_LDS16(A + (size_t)(m0 + (f0 >> 2)) * 2048 + k0 + (f0 & 3) * 8,
                  (char*)As + wid * 1024);
        GLD_LDS16(A + (size_t)(m0 + (f1 >> 2)) * 2048 + k0 + (f1 & 3) * 8,
                  (char*)As + wid * 1024 + 4096);
        GLD_LDS16(Bh + (size_t)(n0 + (f0 >> 2)) * 2048 + k0 + (f0 & 3) * 8,
                  (char*)Bs + wid * 1024);
        GLD_LDS16(Bh + (size_t)(n0 + (f1 >> 2)) * 2048 + k0 + (f1 & 3) * 8,
                  (char*)Bs + wid * 1024 + 4096);
        __syncthreads();
        bf16x8 af[4], bf[4];
#pragma unroll
        for (int m = 0; m < 4; ++m)
            af[m] = *(const bf16x8*)(As + (wm * 64 + m * 16 + c16) * 32 + g * 8);
#pragma unroll
        for (int n = 0; n < 4; ++n)
            bf[n] = *(const bf16x8*)(Bs + (wn * 64 + n * 16 + c16) * 32 + g * 8);
#pragma unroll
        for (int m = 0; m < 4; ++m)
#pragma unroll
            for (int n = 0; n < 4; ++n)
                acc[m][n] = __builtin_amdgcn_mfma_f32_16x16x32_bf16(af[m], bf[n], acc[m][n], 0, 0, 0);
    }

#pragma unroll
    for (int m = 0; m < 4; ++m)
#pragma unroll
        for (int n = 0; n < 4; ++n)
#pragma unroll
            for (int r = 0; r < 4; ++r) {
                int row = m0 + wm * 64 + m * 16 + g * 4 + r;
                int col = n0 + wn * 64 + n * 16 + c16;
                C[(size_t)row * 2560 + col] = acc[m][n][r];
            }
}

// ---------------------------------------------------------------------------
// Workspace (peak ~79.7 MB, phase-aliased):
//   hs_bf [0,          20,971,520)  (dead after gemm1)
//   qb    [20,971,520, 37,748,736)
//   kb_raw[37,748,736, 46,137,344)  (dead after norm_k)
//   vt2   [46,137,344, 54,525,952)  tiled+swizzled
//   Bh    [54,525,952, 75,497,472)  (dead after gemm1)
//   kb2   [54,525,952, 62,914,560)  (over dead Bh; by norm_k)
//   ct    [75,497,472, 77,594,624)
//   st    [77,594,624, 79,691,776)
//   attnb [0,          16,777,216)  (over dead hs_bf)
//   woh   [20,971,520, 31,457,280)  (over dead qb, after attn)
// ---------------------------------------------------------------------------
extern "C" void kernel_launch(void* const* d_in, const int* in_sizes, int n_in,
                              void* d_out, int out_size, void* d_ws, size_t ws_size,
                              hipStream_t stream)
{
    (void)in_sizes; (void)n_in; (void)out_size; (void)ws_size;
    const float* hs  = (const float*)d_in[0];
    const float* wq  = (const float*)d_in[3];
    const float* wk  = (const float*)d_in[4];
    const float* wv  = (const float*)d_in[5];
    const float* wo  = (const float*)d_in[6];
    const float* qnw = (const float*)d_in[7];
    const float* knw = (const float*)d_in[8];

    char* ws = (char*)d_ws;
    bf16_t* hs_bf = (bf16_t*)(ws);
    bf16_t* qb    = (bf16_t*)(ws + 20971520);
    bf16_t* kraw  = (bf16_t*)(ws + 37748736);
    bf16_t* vt2   = (bf16_t*)(ws + 46137344);
    bf16_t* Bh    = (bf16_t*)(ws + 54525952);
    bf16_t* kb2   = (bf16_t*)(ws + 54525952);
    float*  ct    = (float*)(ws + 75497472);
    float*  st    = (float*)(ws + 77594624);
    bf16_t* attnb = (bf16_t*)(ws);
    bf16_t* woh   = (bf16_t*)(ws + 20971520);

    // 1. hs -> bf16; weights -> Bh panel [4096][2560]
    conv_bf16<<<10240, 256, 0, stream>>>(hs, hs_bf, 4096 * 2560 / 4);
    transpose_h<<<dim3(32, 40), 256, 0, stream>>>(wq, Bh, 2560, 2048);
    transpose_h<<<dim3(16, 40), 256, 0, stream>>>(wk, Bh + (size_t)2048 * 2560, 2560, 1024);
    transpose_h<<<dim3(16, 40), 256, 0, stream>>>(wv, Bh + (size_t)3072 * 2560, 2560, 1024);

    // 2. fused qkv projection (8-phase 256^2, 512 threads)
    gemm1<<<dim3(16, 16), 512, 0, stream>>>(hs_bf, Bh, qb, kraw, vt2);

    // 3. RoPE tables + norms (norm_k re-tiles K into kb2 over dead Bh)
    rope_tables<<<2048, 256, 0, stream>>>(ct, st);
    norm_q<<<4096, 256, 0, stream>>>(qb, qnw, ct, st);
    norm_k<<<4096, 256, 0, stream>>>(kraw, kb2, knw, ct, st);

    // 4. attention (grid (h, qt) -> head-per-XCD pinning)
    attn_fwd5<<<dim3(8, 64), 256, 0, stream>>>(qb, kb2, vt2, attnb);

    // 5. wo -> woT panel (over dead qb), then output projection (1-pass)
    transpose_h<<<dim3(40, 32), 256, 0, stream>>>(wo, woh, 2048, 2560);
    gemm2<<<dim3(20, 32), 256, 0, stream>>>(attnb, woh, (float*)d_out);
}

// Round 12
// 243.876 us; speedup vs baseline: 4.8853x; 1.2628x over previous
//
#include <hip/hip_runtime.h>
#include <stdint.h>
#include <math.h>

typedef __bf16 bf16_t;
typedef __bf16 bf16x8 __attribute__((ext_vector_type(8)));
typedef __bf16 bf16x4 __attribute__((ext_vector_type(4)));
typedef float f32x4 __attribute__((ext_vector_type(4)));

#define GLD_LDS16(g, l)                                             \
    __builtin_amdgcn_global_load_lds(                               \
        (const __attribute__((address_space(1))) void*)(g),         \
        (__attribute__((address_space(3))) void*)(l), 16, 0, 0)

#define WAITV(N) asm volatile("s_waitcnt vmcnt(" #N ")" ::: "memory")
#define BARRIER() do { __builtin_amdgcn_sched_barrier(0);           \
                       __builtin_amdgcn_s_barrier();                \
                       __builtin_amdgcn_sched_barrier(0); } while (0)

// ---------------------------------------------------------------------------
// fp32 -> bf16 elementwise (float4 -> bf16x4)
// ---------------------------------------------------------------------------
__global__ __launch_bounds__(256)
void conv_bf16(const float* __restrict__ in, bf16_t* __restrict__ out, int n4)
{
    int i = blockIdx.x * 256 + threadIdx.x;
    if (i >= n4) return;
    float4 v = ((const float4*)in)[i];
    bf16x4 o = { (bf16_t)v.x, (bf16_t)v.y, (bf16_t)v.z, (bf16_t)v.w };
    ((bf16x4*)out)[i] = o;
}

// ---------------------------------------------------------------------------
// transpose + convert: in [R][C] fp32 -> out [C][R] bf16
// ---------------------------------------------------------------------------
__global__ __launch_bounds__(256)
void transpose_h(const float* __restrict__ in, bf16_t* __restrict__ out,
                 int R, int C)
{
    __shared__ float t[64][65];
    const int r0 = blockIdx.y * 64, c0 = blockIdx.x * 64;
#pragma unroll
    for (int i = 0; i < 16; ++i) {
        int f = threadIdx.x + i * 256;
        int r = f >> 6, c = f & 63;
        t[r][c] = in[(size_t)(r0 + r) * C + c0 + c];
    }
    __syncthreads();
#pragma unroll
    for (int i = 0; i < 16; ++i) {
        int f = threadIdx.x + i * 256;
        int r = f >> 6, c = f & 63;
        out[(size_t)(c0 + r) * R + r0 + c] = (bf16_t)t[c][r];
    }
}

// ---------------------------------------------------------------------------
// RoPE cos/sin tables via fp64 (exact angle reduction)
// ---------------------------------------------------------------------------
__global__ __launch_bounds__(256)
void rope_tables(float* __restrict__ ct, float* __restrict__ st)
{
    int t = blockIdx.x * 256 + threadIdx.x;   // 4096*128
    int s = t >> 7, j = t & 127;
    double inv = exp2((double)j * (-13.28771237954945 / 128.0)); // log2(10000)
    double ang = fmod((double)s * inv, 6.283185307179586476925286766559);
    ct[t] = (float)cos(ang);
    st[t] = (float)sin(ang);
}

// ---------------------------------------------------------------------------
// GEMM1 (fused qkv), 8-phase 256x256 tile, BK=64, 8 waves (2Mx4N), 128 KiB
// LDS double-buffer, XOR-swizzled, counted vmcnt.  K = 2560 -> 40 K-tiles.
// ---------------------------------------------------------------------------
__global__ __launch_bounds__(512, 2)
void gemm1(const bf16_t* __restrict__ A, const bf16_t* __restrict__ Bh,
           bf16_t* __restrict__ qb, bf16_t* __restrict__ kb,
           bf16_t* __restrict__ vt)
{
    __shared__ __attribute__((aligned(16))) char smem[131072];
    const int tid = threadIdx.x, lane = tid & 63, wid = tid >> 6;
    const int g = lane >> 4, c16 = lane & 15;
    const int wm = wid >> 2, wn = wid & 3;          // 2 x 4 wave grid
    const int m0 = blockIdx.y * 256, n0 = blockIdx.x * 256;
    const int swz = c16 & 7;
    const int NT = 40;                               // 2560 / 64

    f32x4 acc[8][4];
#pragma unroll
    for (int m = 0; m < 8; ++m)
#pragma unroll
        for (int n = 0; n < 4; ++n) acc[m][n] = (f32x4)(0.f);

    auto STAGE_A = [&](int dbuf, int kt, int half) {
#pragma unroll
        for (int pl = 0; pl < 2; ++pl) {
            int c = pl * 512 + tid;
            int row = c >> 3, b = c & 7;
            GLD_LDS16(A + (size_t)(m0 + half * 128 + row) * 2560 + kt * 64
                        + ((b ^ (row & 7)) << 3),
                      smem + dbuf * 65536 + half * 16384
                        + (pl * 512 + wid * 64) * 16);
        }
    };
    auto STAGE_B = [&](int dbuf, int kt, int qp) {
#pragma unroll
        for (int pl = 0; pl < 2; ++pl) {
            int c = pl * 512 + tid;
            int u = c >> 3, b = c & 7;
            int row = ((u >> 5) << 6) + qp * 32 + (u & 31);
            int u0 = pl * 64 + wid * 8;
            int row0 = ((u0 >> 5) << 6) + qp * 32 + (u0 & 31);
            GLD_LDS16(Bh + (size_t)(n0 + row) * 2560 + kt * 64
                        + ((b ^ (row & 7)) << 3),
                      smem + dbuf * 65536 + 32768 + row0 * 128);
        }
    };

    STAGE_A(0, 0, 0); STAGE_A(0, 0, 1); STAGE_B(0, 0, 0); STAGE_B(0, 0, 1);
    WAITV(2);
    BARRIER();

    for (int t = 0; t < NT; ++t) {
        const int buf = t & 1, nbuf = buf ^ 1;
        const char* Ab = smem + buf * 65536;
        const char* Bb = smem + buf * 65536 + 32768;
        auto rdA = [&](int m, int kk) {
            return *(const bf16x8*)(Ab + (wm * 128 + m * 16 + c16) * 128
                                       + (((kk * 4 + g) ^ swz) << 4));
        };
        auto rdB = [&](int n, int kk) {
            return *(const bf16x8*)(Bb + (wn * 64 + n * 16 + c16) * 128
                                       + (((kk * 4 + g) ^ swz) << 4));
        };
        bf16x8 a[8], b0, b1, b2, b3;

#pragma unroll
        for (int m = 0; m < 8; ++m) a[m] = rdA(m, 0);
        b0 = rdB(0, 0); b1 = rdB(1, 0);
        if (t + 1 < NT) STAGE_A(nbuf, t + 1, 0);
        BARRIER();
        __builtin_amdgcn_s_setprio(1);
#pragma unroll
        for (int m = 0; m < 8; ++m) {
            acc[m][0] = __builtin_amdgcn_mfma_f32_16x16x32_bf16(a[m], b0, acc[m][0], 0, 0, 0);
            acc[m][1] = __builtin_amdgcn_mfma_f32_16x16x32_bf16(a[m], b1, acc[m][1], 0, 0, 0);
        }
        __builtin_amdgcn_s_setprio(0);
        if (t + 1 < NT) { WAITV(2); } else { WAITV(0); }
        BARRIER();

        b2 = rdB(2, 0); b3 = rdB(3, 0);
        if (t + 1 < NT) STAGE_A(nbuf, t + 1, 1);
        BARRIER();
        __builtin_amdgcn_s_setprio(1);
#pragma unroll
        for (int m = 0; m < 8; ++m) {
            acc[m][2] = __builtin_amdgcn_mfma_f32_16x16x32_bf16(a[m], b2, acc[m][2], 0, 0, 0);
            acc[m][3] = __builtin_amdgcn_mfma_f32_16x16x32_bf16(a[m], b3, acc[m][3], 0, 0, 0);
        }
        __builtin_amdgcn_s_setprio(0);
        BARRIER();

#pragma unroll
        for (int m = 0; m < 8; ++m) a[m] = rdA(m, 1);
        b0 = rdB(0, 1); b1 = rdB(1, 1);
        if (t + 1 < NT) STAGE_B(nbuf, t + 1, 0);
        BARRIER();
        __builtin_amdgcn_s_setprio(1);
#pragma unroll
        for (int m = 0; m < 8; ++m) {
            acc[m][0] = __builtin_amdgcn_mfma_f32_16x16x32_bf16(a[m], b0, acc[m][0], 0, 0, 0);
            acc[m][1] = __builtin_amdgcn_mfma_f32_16x16x32_bf16(a[m], b1, acc[m][1], 0, 0, 0);
        }
        __builtin_amdgcn_s_setprio(0);
        BARRIER();

        b2 = rdB(2, 1); b3 = rdB(3, 1);
        if (t + 1 < NT) STAGE_B(nbuf, t + 1, 1);
        BARRIER();
        __builtin_amdgcn_s_setprio(1);
#pragma unroll
        for (int m = 0; m < 8; ++m) {
            acc[m][2] = __builtin_amdgcn_mfma_f32_16x16x32_bf16(a[m], b2, acc[m][2], 0, 0, 0);
            acc[m][3] = __builtin_amdgcn_mfma_f32_16x16x32_bf16(a[m], b3, acc[m][3], 0, 0, 0);
        }
        __builtin_amdgcn_s_setprio(0);
        if (t + 1 < NT) WAITV(2);
        BARRIER();
    }

    if (n0 < 2048) {          // q region
#pragma unroll
        for (int m = 0; m < 8; ++m)
#pragma unroll
            for (int n = 0; n < 4; ++n) {
                int col = n0 + wn * 64 + n * 16 + c16;
                int rowb = m0 + wm * 128 + m * 16 + g * 4;
#pragma unroll
                for (int r = 0; r < 4; ++r)
                    qb[(size_t)(rowb + r) * 2048 + col] = (bf16_t)acc[m][n][r];
            }
    } else if (n0 < 3072) {   // k region (raw, re-tiled by norm_k)
#pragma unroll
        for (int m = 0; m < 8; ++m)
#pragma unroll
            for (int n = 0; n < 4; ++n) {
                int col = n0 + wn * 64 + n * 16 + c16 - 2048;
                int rowb = m0 + wm * 128 + m * 16 + g * 4;
#pragma unroll
                for (int r = 0; r < 4; ++r)
                    kb[(size_t)(rowb + r) * 1024 + col] = (bf16_t)acc[m][n][r];
            }
    } else {                  // v region -> vt2 tiled + swizzled
#pragma unroll
        for (int m = 0; m < 8; ++m)
#pragma unroll
            for (int n = 0; n < 4; ++n) {
                int d = n0 + wn * 64 + n * 16 + c16 - 3072;
                int rowb = m0 + wm * 128 + m * 16 + g * 4;
                int kvh_ = d >> 8, dd = d & 255;
                int kt = rowb >> 5, key = rowb & 31;
                bf16x4 hv;
#pragma unroll
                for (int r = 0; r < 4; ++r) hv[r] = (bf16_t)acc[m][n][r];
                size_t off = (size_t)kvh_ * 1048576 + (size_t)kt * 8192
                           + dd * 32 + (((key >> 3) ^ (dd & 3)) << 3) + (key & 7);
                *(bf16x4*)(vt + off) = hv;
            }
    }
}

// ---------------------------------------------------------------------------
// GEMM2, same 8-phase 256x256 template, K = 2048 -> NT = 32, fp32 epilogue.
// ---------------------------------------------------------------------------
__global__ __launch_bounds__(512, 2)
void gemm2p(const bf16_t* __restrict__ A, const bf16_t* __restrict__ Bh,
            float* __restrict__ C)
{
    __shared__ __attribute__((aligned(16))) char smem[131072];
    const int tid = threadIdx.x, lane = tid & 63, wid = tid >> 6;
    const int g = lane >> 4, c16 = lane & 15;
    const int wm = wid >> 2, wn = wid & 3;
    const int m0 = blockIdx.y * 256, n0 = blockIdx.x * 256;
    const int swz = c16 & 7;
    const int NT = 32;                               // 2048 / 64

    f32x4 acc[8][4];
#pragma unroll
    for (int m = 0; m < 8; ++m)
#pragma unroll
        for (int n = 0; n < 4; ++n) acc[m][n] = (f32x4)(0.f);

    auto STAGE_A = [&](int dbuf, int kt, int half) {
#pragma unroll
        for (int pl = 0; pl < 2; ++pl) {
            int c = pl * 512 + tid;
            int row = c >> 3, b = c & 7;
            GLD_LDS16(A + (size_t)(m0 + half * 128 + row) * 2048 + kt * 64
                        + ((b ^ (row & 7)) << 3),
                      smem + dbuf * 65536 + half * 16384
                        + (pl * 512 + wid * 64) * 16);
        }
    };
    auto STAGE_B = [&](int dbuf, int kt, int qp) {
#pragma unroll
        for (int pl = 0; pl < 2; ++pl) {
            int c = pl * 512 + tid;
            int u = c >> 3, b = c & 7;
            int row = ((u >> 5) << 6) + qp * 32 + (u & 31);
            int u0 = pl * 64 + wid * 8;
            int row0 = ((u0 >> 5) << 6) + qp * 32 + (u0 & 31);
            GLD_LDS16(Bh + (size_t)(n0 + row) * 2048 + kt * 64
                        + ((b ^ (row & 7)) << 3),
                      smem + dbuf * 65536 + 32768 + row0 * 128);
        }
    };

    STAGE_A(0, 0, 0); STAGE_A(0, 0, 1); STAGE_B(0, 0, 0); STAGE_B(0, 0, 1);
    WAITV(2);
    BARRIER();

    for (int t = 0; t < NT; ++t) {
        const int buf = t & 1, nbuf = buf ^ 1;
        const char* Ab = smem + buf * 65536;
        const char* Bb = smem + buf * 65536 + 32768;
        auto rdA = [&](int m, int kk) {
            return *(const bf16x8*)(Ab + (wm * 128 + m * 16 + c16) * 128
                                       + (((kk * 4 + g) ^ swz) << 4));
        };
        auto rdB = [&](int n, int kk) {
            return *(const bf16x8*)(Bb + (wn * 64 + n * 16 + c16) * 128
                                       + (((kk * 4 + g) ^ swz) << 4));
        };
        bf16x8 a[8], b0, b1, b2, b3;

#pragma unroll
        for (int m = 0; m < 8; ++m) a[m] = rdA(m, 0);
        b0 = rdB(0, 0); b1 = rdB(1, 0);
        if (t + 1 < NT) STAGE_A(nbuf, t + 1, 0);
        BARRIER();
        __builtin_amdgcn_s_setprio(1);
#pragma unroll
        for (int m = 0; m < 8; ++m) {
            acc[m][0] = __builtin_amdgcn_mfma_f32_16x16x32_bf16(a[m], b0, acc[m][0], 0, 0, 0);
            acc[m][1] = __builtin_amdgcn_mfma_f32_16x16x32_bf16(a[m], b1, acc[m][1], 0, 0, 0);
        }
        __builtin_amdgcn_s_setprio(0);
        if (t + 1 < NT) { WAITV(2); } else { WAITV(0); }
        BARRIER();

        b2 = rdB(2, 0); b3 = rdB(3, 0);
        if (t + 1 < NT) STAGE_A(nbuf, t + 1, 1);
        BARRIER();
        __builtin_amdgcn_s_setprio(1);
#pragma unroll
        for (int m = 0; m < 8; ++m) {
            acc[m][2] = __builtin_amdgcn_mfma_f32_16x16x32_bf16(a[m], b2, acc[m][2], 0, 0, 0);
            acc[m][3] = __builtin_amdgcn_mfma_f32_16x16x32_bf16(a[m], b3, acc[m][3], 0, 0, 0);
        }
        __builtin_amdgcn_s_setprio(0);
        BARRIER();

#pragma unroll
        for (int m = 0; m < 8; ++m) a[m] = rdA(m, 1);
        b0 = rdB(0, 1); b1 = rdB(1, 1);
        if (t + 1 < NT) STAGE_B(nbuf, t + 1, 0);
        BARRIER();
        __builtin_amdgcn_s_setprio(1);
#pragma unroll
        for (int m = 0; m < 8; ++m) {
            acc[m][0] = __builtin_amdgcn_mfma_f32_16x16x32_bf16(a[m], b0, acc[m][0], 0, 0, 0);
            acc[m][1] = __builtin_amdgcn_mfma_f32_16x16x32_bf16(a[m], b1, acc[m][1], 0, 0, 0);
        }
        __builtin_amdgcn_s_setprio(0);
        BARRIER();

        b2 = rdB(2, 1); b3 = rdB(3, 1);
        if (t + 1 < NT) STAGE_B(nbuf, t + 1, 1);
        BARRIER();
        __builtin_amdgcn_s_setprio(1);
#pragma unroll
        for (int m = 0; m < 8; ++m) {
            acc[m][2] = __builtin_amdgcn_mfma_f32_16x16x32_bf16(a[m], b2, acc[m][2], 0, 0, 0);
            acc[m][3] = __builtin_amdgcn_mfma_f32_16x16x32_bf16(a[m], b3, acc[m][3], 0, 0, 0);
        }
        __builtin_amdgcn_s_setprio(0);
        if (t + 1 < NT) WAITV(2);
        BARRIER();
    }

#pragma unroll
    for (int m = 0; m < 8; ++m)
#pragma unroll
        for (int n = 0; n < 4; ++n) {
            int col = n0 + wn * 64 + n * 16 + c16;
            int rowb = m0 + wm * 128 + m * 16 + g * 4;
#pragma unroll
            for (int r = 0; r < 4; ++r)
                C[(size_t)(rowb + r) * 2560 + col] = acc[m][n][r];
        }
}

// ---------------------------------------------------------------------------
// RMSNorm + RoPE on q (in-place, plain bf16 [4096][2048]).
// ---------------------------------------------------------------------------
__global__ __launch_bounds__(256)
void norm_q(bf16_t* __restrict__ qb, const float* __restrict__ w,
            const float* __restrict__ ct, const float* __restrict__ st)
{
    const int s = blockIdx.x, t = threadIdx.x;
    const int h = t >> 5, l = t & 31;
    bf16_t* base = qb + (size_t)s * 2048 + h * 256 + l * 8;
    bf16x8 hv = *(const bf16x8*)base;
    float x[8], ss = 0.f;
#pragma unroll
    for (int j = 0; j < 8; ++j) { x[j] = (float)hv[j]; ss += x[j] * x[j]; }
#pragma unroll
    for (int mk = 1; mk < 32; mk <<= 1) ss += __shfl_xor(ss, mk);
    const float rs = rsqrtf(ss * (1.f / 256.f) + 1e-6f);
    float4 w0 = *(const float4*)(w + l * 8);
    float4 w1 = *(const float4*)(w + l * 8 + 4);
    float wa[8] = { w0.x, w0.y, w0.z, w0.w, w1.x, w1.y, w1.z, w1.w };
    float xn[8];
#pragma unroll
    for (int j = 0; j < 8; ++j) xn[j] = x[j] * rs * (1.f + wa[j]);
    const int d0 = (l * 8) & 127;
    float4 c0 = *(const float4*)(ct + s * 128 + d0);
    float4 c1 = *(const float4*)(ct + s * 128 + d0 + 4);
    float4 s0 = *(const float4*)(st + s * 128 + d0);
    float4 s1 = *(const float4*)(st + s * 128 + d0 + 4);
    float cc[8] = { c0.x, c0.y, c0.z, c0.w, c1.x, c1.y, c1.z, c1.w };
    float sn[8] = { s0.x, s0.y, s0.z, s0.w, s1.x, s1.y, s1.z, s1.w };
    const bool upper = (l >= 16);
    bf16x8 oh;
#pragma unroll
    for (int j = 0; j < 8; ++j) {
        float pn = __shfl_xor(xn[j], 16);
        float rot = upper ? pn : -pn;
        oh[j] = (bf16_t)(xn[j] * cc[j] + rot * sn[j]);
    }
    *(bf16x8*)base = oh;
}

// ---------------------------------------------------------------------------
// RMSNorm + RoPE on k; raw [4096][1024] -> kb2[kvh][kt][key 32][d 256],
// 16B blocks XOR'd by (s&7).
// ---------------------------------------------------------------------------
__global__ __launch_bounds__(256)
void norm_k(const bf16_t* __restrict__ kraw, bf16_t* __restrict__ kb2,
            const float* __restrict__ w, const float* __restrict__ ct,
            const float* __restrict__ st)
{
    const int s = blockIdx.x, t = threadIdx.x;
    const int h = t >> 6, l = t & 63;
    const bf16_t* base = kraw + (size_t)s * 1024 + h * 256 + l * 4;
    bf16x4 hv = *(const bf16x4*)base;
    float x[4], ss = 0.f;
#pragma unroll
    for (int j = 0; j < 4; ++j) { x[j] = (float)hv[j]; ss += x[j] * x[j]; }
#pragma unroll
    for (int mk = 1; mk < 64; mk <<= 1) ss += __shfl_xor(ss, mk);
    const float rs = rsqrtf(ss * (1.f / 256.f) + 1e-6f);
    float4 w0 = *(const float4*)(w + l * 4);
    float wa[4] = { w0.x, w0.y, w0.z, w0.w };
    float xn[4];
#pragma unroll
    for (int j = 0; j < 4; ++j) xn[j] = x[j] * rs * (1.f + wa[j]);
    const int d0 = (l * 4) & 127;
    float4 c0 = *(const float4*)(ct + s * 128 + d0);
    float4 s0 = *(const float4*)(st + s * 128 + d0);
    float cc[4] = { c0.x, c0.y, c0.z, c0.w };
    float sn[4] = { s0.x, s0.y, s0.z, s0.w };
    const bool upper = (l >= 32);
    bf16x4 oh;
#pragma unroll
    for (int j = 0; j < 4; ++j) {
        float pn = __shfl_xor(xn[j], 32);
        float rot = upper ? pn : -pn;
        oh[j] = (bf16_t)(xn[j] * cc[j] + rot * sn[j]);
    }
    bf16_t* dst = kb2 + (size_t)h * 1048576 + (size_t)(s >> 5) * 8192
                + (s & 31) * 256 + (((l >> 1) ^ (s & 7)) << 3) + (l & 1) * 4;
    *(bf16x4*)dst = oh;
}

// ---------------------------------------------------------------------------
// Sliding-window GQA flash attention, no-max softmax (exact shift-invariance;
// post-RMSNorm operands bound |s2| <= ~23 so exp2 never overflows f32/bf16).
// Per-lane lrow partials; single cross-lane reduce at kernel end.
// ---------------------------------------------------------------------------
__global__ __launch_bounds__(256)
void attn_fwd6(const bf16_t* __restrict__ qb, const bf16_t* __restrict__ kb2,
               const bf16_t* __restrict__ vt2, bf16_t* __restrict__ attn)
{
    __shared__ __attribute__((aligned(16))) char smem[2 * 32768];
    __shared__ __attribute__((aligned(16))) bf16_t P[4][16][40];
    const int tid = threadIdx.x, lane = tid & 63, wid = tid >> 6;
    const int g = lane >> 4, c16 = lane & 15;
    const int h = blockIdx.x, kvh = h >> 1;
    const int by = blockIdx.y;
    const int qt = (by & 1) ? (63 - (by >> 1)) : (by >> 1);   // balance pair
    const int qrow0 = qt * 64 + wid * 16;

    const char* kslab = (const char*)kb2 + (size_t)kvh * 2097152;
    const char* vslab = (const char*)vt2 + (size_t)kvh * 2097152;

    bf16x8 qf[8];
#pragma unroll
    for (int c = 0; c < 8; ++c)
        qf[c] = *(const bf16x8*)(qb + (size_t)(qrow0 + c16) * 2048 + h * 256 + c * 32 + g * 8);

    float lrow[4] = { 0.f, 0.f, 0.f, 0.f };
    f32x4 acc[16];
#pragma unroll
    for (int nd = 0; nd < 16; ++nd) acc[nd] = (f32x4)(0.f);

    auto STAGE = [&](int buf, int kt) {
        char* Kd = smem + buf * 32768;
        char* Vd = smem + buf * 32768 + 16384;
        const char* ks = kslab + (size_t)kt * 16384;
        const char* vs = vslab + (size_t)kt * 16384;
#pragma unroll
        for (int j = 0; j < 4; ++j)
            GLD_LDS16(ks + (size_t)(j * 256 + tid) * 16, Kd + (j * 256 + wid * 64) * 16);
#pragma unroll
        for (int j = 0; j < 4; ++j)
            GLD_LDS16(vs + (size_t)(j * 256 + tid) * 16, Vd + (j * 256 + wid * 64) * 16);
    };

    const int ktb_lo = (qt >= 16) ? 2 * qt - 32 : 0;
    const int ktb_hi = 2 * qt + 1;
    int cur = 0;
    STAGE(0, ktb_lo);
    __syncthreads();

    const int swk = (c16 & 7) << 4;
    const int swv = (g ^ (c16 & 3)) << 4;
    const float S2 = 0.090168441f;   // 2^-4 * log2(e)

    for (int kt = ktb_lo; kt <= ktb_hi; ++kt) {
        if (kt < ktb_hi) STAGE(cur ^ 1, kt + 1);

        if (kt * 32 <= qrow0 + 15 && kt * 32 + 31 >= qrow0 - 1023) {
            const char* Kc = smem + cur * 32768;
            const char* Vc = smem + cur * 32768 + 16384;

            f32x4 scA[2], scB[2];
#pragma unroll
            for (int n = 0; n < 2; ++n) { scA[n] = (f32x4)(0.f); scB[n] = (f32x4)(0.f); }
            __builtin_amdgcn_s_setprio(1);
#pragma unroll
            for (int n = 0; n < 2; ++n) {
                const char* kr = Kc + (n * 16 + c16) * 512;
#pragma unroll
                for (int c = 0; c < 4; ++c) {
                    bf16x8 kf = *(const bf16x8*)(kr + ((((c * 4 + g) << 4) ^ swk)));
                    scA[n] = __builtin_amdgcn_mfma_f32_16x16x32_bf16(qf[c], kf, scA[n], 0, 0, 0);
                }
#pragma unroll
                for (int c = 4; c < 8; ++c) {
                    bf16x8 kf = *(const bf16x8*)(kr + ((((c * 4 + g) << 4) ^ swk)));
                    scB[n] = __builtin_amdgcn_mfma_f32_16x16x32_bf16(qf[c], kf, scB[n], 0, 0, 0);
                }
            }
            __builtin_amdgcn_s_setprio(0);

            // no-max softmax: P = exp2(s2), masked -> 0
            float p2[2][4];
            const bool fullv = (kt * 32 + 31 <= qrow0) && (kt * 32 >= qrow0 - 1008);
            if (fullv) {
#pragma unroll
                for (int n = 0; n < 2; ++n)
#pragma unroll
                    for (int r = 0; r < 4; ++r)
                        p2[n][r] = __builtin_amdgcn_exp2f((scA[n][r] + scB[n][r]) * S2);
            } else {
#pragma unroll
                for (int n = 0; n < 2; ++n) {
                    const int key = kt * 32 + n * 16 + c16;
#pragma unroll
                    for (int r = 0; r < 4; ++r) {
                        const int q = qrow0 + g * 4 + r;
                        bool valid = (key <= q) && (q - key < 1024);
                        float e = __builtin_amdgcn_exp2f((scA[n][r] + scB[n][r]) * S2);
                        p2[n][r] = valid ? e : 0.f;
                    }
                }
            }
#pragma unroll
            for (int n = 0; n < 2; ++n)
#pragma unroll
                for (int r = 0; r < 4; ++r) lrow[r] += p2[n][r];

#pragma unroll
            for (int n = 0; n < 2; ++n)
#pragma unroll
                for (int r = 0; r < 4; ++r)
                    P[wid][g * 4 + r][n * 16 + c16] = (bf16_t)p2[n][r];
            bf16x8 pa = *(const bf16x8*)(&P[wid][c16][g * 8]);
            __builtin_amdgcn_s_setprio(1);
#pragma unroll
            for (int nd = 0; nd < 16; ++nd) {
                bf16x8 vf = *(const bf16x8*)(Vc + (nd * 16 + c16) * 64 + swv);
                acc[nd] = __builtin_amdgcn_mfma_f32_16x16x32_bf16(pa, vf, acc[nd], 0, 0, 0);
            }
            __builtin_amdgcn_s_setprio(0);
        }
        __syncthreads();
        cur ^= 1;
    }

    // single cross-lane reduce of lrow over the 16 c16 lanes (same g)
#pragma unroll
    for (int mk = 1; mk < 16; mk <<= 1)
#pragma unroll
        for (int r = 0; r < 4; ++r) lrow[r] += __shfl_xor(lrow[r], mk);

    float inv[4];
#pragma unroll
    for (int r = 0; r < 4; ++r) inv[r] = 1.f / lrow[r];
#pragma unroll
    for (int nd = 0; nd < 16; ++nd)
#pragma unroll
        for (int r = 0; r < 4; ++r) {
            int row = qrow0 + g * 4 + r;
            attn[(size_t)row * 2048 + h * 256 + nd * 16 + c16] =
                (bf16_t)(acc[nd][r] * inv[r]);
        }
}

// ---------------------------------------------------------------------------
// Workspace (peak ~79.7 MB, phase-aliased):
//   hs_bf [0,          20,971,520)  (dead after gemm1)
//   qb    [20,971,520, 37,748,736)
//   kb_raw[37,748,736, 46,137,344)  (dead after norm_k)
//   vt2   [46,137,344, 54,525,952)  tiled+swizzled
//   Bh    [54,525,952, 75,497,472)  (dead after gemm1)
//   kb2   [54,525,952, 62,914,560)  (over dead Bh; by norm_k)
//   ct    [75,497,472, 77,594,624)
//   st    [77,594,624, 79,691,776)
//   attnb [0,          16,777,216)  (over dead hs_bf)
//   woh   [20,971,520, 31,457,280)  (over dead qb, after attn)
// ---------------------------------------------------------------------------
extern "C" void kernel_launch(void* const* d_in, const int* in_sizes, int n_in,
                              void* d_out, int out_size, void* d_ws, size_t ws_size,
                              hipStream_t stream)
{
    (void)in_sizes; (void)n_in; (void)out_size; (void)ws_size;
    const float* hs  = (const float*)d_in[0];
    const float* wq  = (const float*)d_in[3];
    const float* wk  = (const float*)d_in[4];
    const float* wv  = (const float*)d_in[5];
    const float* wo  = (const float*)d_in[6];
    const float* qnw = (const float*)d_in[7];
    const float* knw = (const float*)d_in[8];

    char* ws = (char*)d_ws;
    bf16_t* hs_bf = (bf16_t*)(ws);
    bf16_t* qb    = (bf16_t*)(ws + 20971520);
    bf16_t* kraw  = (bf16_t*)(ws + 37748736);
    bf16_t* vt2   = (bf16_t*)(ws + 46137344);
    bf16_t* Bh    = (bf16_t*)(ws + 54525952);
    bf16_t* kb2   = (bf16_t*)(ws + 54525952);
    float*  ct    = (float*)(ws + 75497472);
    float*  st    = (float*)(ws + 77594624);
    bf16_t* attnb = (bf16_t*)(ws);
    bf16_t* woh   = (bf16_t*)(ws + 20971520);

    // 1. hs -> bf16; weights -> Bh panel [4096][2560]
    conv_bf16<<<10240, 256, 0, stream>>>(hs, hs_bf, 4096 * 2560 / 4);
    transpose_h<<<dim3(32, 40), 256, 0, stream>>>(wq, Bh, 2560, 2048);
    transpose_h<<<dim3(16, 40), 256, 0, stream>>>(wk, Bh + (size_t)2048 * 2560, 2560, 1024);
    transpose_h<<<dim3(16, 40), 256, 0, stream>>>(wv, Bh + (size_t)3072 * 2560, 2560, 1024);

    // 2. fused qkv projection (8-phase 256^2, 512 threads)
    gemm1<<<dim3(16, 16), 512, 0, stream>>>(hs_bf, Bh, qb, kraw, vt2);

    // 3. RoPE tables + norms (norm_k re-tiles K into kb2 over dead Bh)
    rope_tables<<<2048, 256, 0, stream>>>(ct, st);
    norm_q<<<4096, 256, 0, stream>>>(qb, qnw, ct, st);
    norm_k<<<4096, 256, 0, stream>>>(kraw, kb2, knw, ct, st);

    // 4. attention (grid (h, qt) -> head-per-XCD pinning)
    attn_fwd6<<<dim3(8, 64), 256, 0, stream>>>(qb, kb2, vt2, attnb);

    // 5. wo -> woT panel (over dead qb), then output projection (8-phase)
    transpose_h<<<dim3(40, 32), 256, 0, stream>>>(wo, woh, 2048, 2560);
    gemm2p<<<dim3(10, 16), 512, 0, stream>>>(attnb, woh, (float*)d_out);
}

// Round 13
// 239.641 us; speedup vs baseline: 4.9717x; 1.0177x over previous
//
#include <hip/hip_runtime.h>
#include <stdint.h>
#include <math.h>

typedef __bf16 bf16_t;
typedef __bf16 bf16x8 __attribute__((ext_vector_type(8)));
typedef __bf16 bf16x4 __attribute__((ext_vector_type(4)));
typedef float f32x4 __attribute__((ext_vector_type(4)));

#define GLD_LDS16(g, l)                                             \
    __builtin_amdgcn_global_load_lds(                               \
        (const __attribute__((address_space(1))) void*)(g),         \
        (__attribute__((address_space(3))) void*)(l), 16, 0, 0)

#define WAITV(N) asm volatile("s_waitcnt vmcnt(" #N ")" ::: "memory")
#define BARRIER() do { __builtin_amdgcn_sched_barrier(0);           \
                       __builtin_amdgcn_s_barrier();                \
                       __builtin_amdgcn_sched_barrier(0); } while (0)

// ---------------------------------------------------------------------------
// prep: fused weight transposes (wq/wk/wv -> Bh panel) + hs fp32->bf16 conv.
// blocks [0,1280) wq | [1280,1920) wk | [1920,2560) wv | [2560,12800) conv.
// ---------------------------------------------------------------------------
__global__ __launch_bounds__(256)
void prep(const float* __restrict__ hs, bf16_t* __restrict__ hsb,
          const float* __restrict__ wq, const float* __restrict__ wk,
          const float* __restrict__ wv, bf16_t* __restrict__ Bh)
{
    const int b = blockIdx.x;
    if (b >= 2560) {                       // conv: 10240 blocks x 256 x 4
        int i = (b - 2560) * 256 + threadIdx.x;
        float4 v = ((const float4*)hs)[i];
        bf16x4 o = { (bf16_t)v.x, (bf16_t)v.y, (bf16_t)v.z, (bf16_t)v.w };
        ((bf16x4*)hsb)[i] = o;
        return;
    }
    const float* src; bf16_t* dst; int C, bx, by;
    if (b < 1280)      { src = wq; dst = Bh;                          C = 2048; bx = b % 32;          by = b / 32; }
    else if (b < 1920) { src = wk; dst = Bh + (size_t)2048 * 2560;    C = 1024; bx = (b - 1280) % 16; by = (b - 1280) / 16; }
    else               { src = wv; dst = Bh + (size_t)3072 * 2560;    C = 1024; bx = (b - 1920) % 16; by = (b - 1920) / 16; }
    const int R = 2560;
    __shared__ float t[64][65];
    const int r0 = by * 64, c0 = bx * 64;
#pragma unroll
    for (int i = 0; i < 16; ++i) {
        int f = threadIdx.x + i * 256;
        int r = f >> 6, c = f & 63;
        t[r][c] = src[(size_t)(r0 + r) * C + c0 + c];
    }
    __syncthreads();
#pragma unroll
    for (int i = 0; i < 16; ++i) {
        int f = threadIdx.x + i * 256;
        int r = f >> 6, c = f & 63;
        dst[(size_t)(c0 + r) * R + r0 + c] = (bf16_t)t[c][r];
    }
}

// ---------------------------------------------------------------------------
// transpose + convert: in [R][C] fp32 -> out [C][R] bf16   (for wo)
// ---------------------------------------------------------------------------
__global__ __launch_bounds__(256)
void transpose_h(const float* __restrict__ in, bf16_t* __restrict__ out,
                 int R, int C)
{
    __shared__ float t[64][65];
    const int r0 = blockIdx.y * 64, c0 = blockIdx.x * 64;
#pragma unroll
    for (int i = 0; i < 16; ++i) {
        int f = threadIdx.x + i * 256;
        int r = f >> 6, c = f & 63;
        t[r][c] = in[(size_t)(r0 + r) * C + c0 + c];
    }
    __syncthreads();
#pragma unroll
    for (int i = 0; i < 16; ++i) {
        int f = threadIdx.x + i * 256;
        int r = f >> 6, c = f & 63;
        out[(size_t)(c0 + r) * R + r0 + c] = (bf16_t)t[c][r];
    }
}

// ---------------------------------------------------------------------------
// RoPE cos/sin tables via fp64 (exact angle reduction)
// ---------------------------------------------------------------------------
__global__ __launch_bounds__(256)
void rope_tables(float* __restrict__ ct, float* __restrict__ st)
{
    int t = blockIdx.x * 256 + threadIdx.x;   // 4096*128
    int s = t >> 7, j = t & 127;
    double inv = exp2((double)j * (-13.28771237954945 / 128.0)); // log2(10000)
    double ang = fmod((double)s * inv, 6.283185307179586476925286766559);
    ct[t] = (float)cos(ang);
    st[t] = (float)sin(ang);
}

// ---------------------------------------------------------------------------
// GEMM1 (fused qkv), 8-phase 256x256 tile, BK=64, 8 waves (2Mx4N), 128 KiB
// LDS double-buffer, XOR-swizzled, counted vmcnt with early-issue schedule:
// all 4 stage units for t+1 issued in P0/P1; WAITV(4)@P0-end, WAITV(2)@P3-end.
// ---------------------------------------------------------------------------
__global__ __launch_bounds__(512, 2)
void gemm1(const bf16_t* __restrict__ A, const bf16_t* __restrict__ Bh,
           bf16_t* __restrict__ qb, bf16_t* __restrict__ kb,
           bf16_t* __restrict__ vt)
{
    __shared__ __attribute__((aligned(16))) char smem[131072];
    const int tid = threadIdx.x, lane = tid & 63, wid = tid >> 6;
    const int g = lane >> 4, c16 = lane & 15;
    const int wm = wid >> 2, wn = wid & 3;          // 2 x 4 wave grid
    const int m0 = blockIdx.y * 256, n0 = blockIdx.x * 256;
    const int swz = c16 & 7;
    const int NT = 40;                               // 2560 / 64

    f32x4 acc[8][4];
#pragma unroll
    for (int m = 0; m < 8; ++m)
#pragma unroll
        for (int n = 0; n < 4; ++n) acc[m][n] = (f32x4)(0.f);

    auto STAGE_A = [&](int dbuf, int kt, int half) {
#pragma unroll
        for (int pl = 0; pl < 2; ++pl) {
            int c = pl * 512 + tid;
            int row = c >> 3, b = c & 7;
            GLD_LDS16(A + (size_t)(m0 + half * 128 + row) * 2560 + kt * 64
                        + ((b ^ (row & 7)) << 3),
                      smem + dbuf * 65536 + half * 16384
                        + (pl * 512 + wid * 64) * 16);
        }
    };
    auto STAGE_B = [&](int dbuf, int kt, int qp) {
#pragma unroll
        for (int pl = 0; pl < 2; ++pl) {
            int c = pl * 512 + tid;
            int u = c >> 3, b = c & 7;
            int row = ((u >> 5) << 6) + qp * 32 + (u & 31);
            int u0 = pl * 64 + wid * 8;
            int row0 = ((u0 >> 5) << 6) + qp * 32 + (u0 & 31);
            GLD_LDS16(Bh + (size_t)(n0 + row) * 2560 + kt * 64
                        + ((b ^ (row & 7)) << 3),
                      smem + dbuf * 65536 + 32768 + row0 * 128);
        }
    };

    // prologue: A0,Bq0,A1,Bq1 of tile 0; drain to 2 (Bq1 may fly)
    STAGE_A(0, 0, 0); STAGE_B(0, 0, 0); STAGE_A(0, 0, 1); STAGE_B(0, 0, 1);
    WAITV(2);
    BARRIER();

    for (int t = 0; t < NT; ++t) {
        const int buf = t & 1, nbuf = buf ^ 1;
        const char* Ab = smem + buf * 65536;
        const char* Bb = smem + buf * 65536 + 32768;
        auto rdA = [&](int m, int kk) {
            return *(const bf16x8*)(Ab + (wm * 128 + m * 16 + c16) * 128
                                       + (((kk * 4 + g) ^ swz) << 4));
        };
        auto rdB = [&](int n, int kk) {
            return *(const bf16x8*)(Bb + (wn * 64 + n * 16 + c16) * 128
                                       + (((kk * 4 + g) ^ swz) << 4));
        };
        bf16x8 a[8], b0, b1, b2, b3;

        // ---- P0: n{0,1} kk0; issue t+1.{A0,Bq0} ----------------------
#pragma unroll
        for (int m = 0; m < 8; ++m) a[m] = rdA(m, 0);
        b0 = rdB(0, 0); b1 = rdB(1, 0);
        if (t + 1 < NT) { STAGE_A(nbuf, t + 1, 0); STAGE_B(nbuf, t + 1, 0); }
        BARRIER();
        __builtin_amdgcn_s_setprio(1);
#pragma unroll
        for (int m = 0; m < 8; ++m) {
            acc[m][0] = __builtin_amdgcn_mfma_f32_16x16x32_bf16(a[m], b0, acc[m][0], 0, 0, 0);
            acc[m][1] = __builtin_amdgcn_mfma_f32_16x16x32_bf16(a[m], b1, acc[m][1], 0, 0, 0);
        }
        __builtin_amdgcn_s_setprio(0);
        if (t + 1 < NT) { WAITV(4); } else { WAITV(0); }   // drain t.Bq1
        BARRIER();

        // ---- P1: n{2,3} kk0; issue t+1.{A1,Bq1} ----------------------
        b2 = rdB(2, 0); b3 = rdB(3, 0);
        if (t + 1 < NT) { STAGE_A(nbuf, t + 1, 1); STAGE_B(nbuf, t + 1, 1); }
        BARRIER();
        __builtin_amdgcn_s_setprio(1);
#pragma unroll
        for (int m = 0; m < 8; ++m) {
            acc[m][2] = __builtin_amdgcn_mfma_f32_16x16x32_bf16(a[m], b2, acc[m][2], 0, 0, 0);
            acc[m][3] = __builtin_amdgcn_mfma_f32_16x16x32_bf16(a[m], b3, acc[m][3], 0, 0, 0);
        }
        __builtin_amdgcn_s_setprio(0);
        BARRIER();

        // ---- P2: n{0,1} kk1 ------------------------------------------
#pragma unroll
        for (int m = 0; m < 8; ++m) a[m] = rdA(m, 1);
        b0 = rdB(0, 1); b1 = rdB(1, 1);
        BARRIER();
        __builtin_amdgcn_s_setprio(1);
#pragma unroll
        for (int m = 0; m < 8; ++m) {
            acc[m][0] = __builtin_amdgcn_mfma_f32_16x16x32_bf16(a[m], b0, acc[m][0], 0, 0, 0);
            acc[m][1] = __builtin_amdgcn_mfma_f32_16x16x32_bf16(a[m], b1, acc[m][1], 0, 0, 0);
        }
        __builtin_amdgcn_s_setprio(0);
        BARRIER();

        // ---- P3: n{2,3} kk1 ------------------------------------------
        b2 = rdB(2, 1); b3 = rdB(3, 1);
        BARRIER();
        __builtin_amdgcn_s_setprio(1);
#pragma unroll
        for (int m = 0; m < 8; ++m) {
            acc[m][2] = __builtin_amdgcn_mfma_f32_16x16x32_bf16(a[m], b2, acc[m][2], 0, 0, 0);
            acc[m][3] = __builtin_amdgcn_mfma_f32_16x16x32_bf16(a[m], b3, acc[m][3], 0, 0, 0);
        }
        __builtin_amdgcn_s_setprio(0);
        if (t + 1 < NT) WAITV(2);   // drain t+1.{A0,Bq0,A1}; Bq1 flies
        BARRIER();
    }

    if (n0 < 2048) {          // q region
#pragma unroll
        for (int m = 0; m < 8; ++m)
#pragma unroll
            for (int n = 0; n < 4; ++n) {
                int col = n0 + wn * 64 + n * 16 + c16;
                int rowb = m0 + wm * 128 + m * 16 + g * 4;
#pragma unroll
                for (int r = 0; r < 4; ++r)
                    qb[(size_t)(rowb + r) * 2048 + col] = (bf16_t)acc[m][n][r];
            }
    } else if (n0 < 3072) {   // k region (raw, re-tiled by norm_qk)
#pragma unroll
        for (int m = 0; m < 8; ++m)
#pragma unroll
            for (int n = 0; n < 4; ++n) {
                int col = n0 + wn * 64 + n * 16 + c16 - 2048;
                int rowb = m0 + wm * 128 + m * 16 + g * 4;
#pragma unroll
                for (int r = 0; r < 4; ++r)
                    kb[(size_t)(rowb + r) * 1024 + col] = (bf16_t)acc[m][n][r];
            }
    } else {                  // v region -> vt2 tiled + swizzled
#pragma unroll
        for (int m = 0; m < 8; ++m)
#pragma unroll
            for (int n = 0; n < 4; ++n) {
                int d = n0 + wn * 64 + n * 16 + c16 - 3072;
                int rowb = m0 + wm * 128 + m * 16 + g * 4;
                int kvh_ = d >> 8, dd = d & 255;
                int kt = rowb >> 5, key = rowb & 31;
                bf16x4 hv;
#pragma unroll
                for (int r = 0; r < 4; ++r) hv[r] = (bf16_t)acc[m][n][r];
                size_t off = (size_t)kvh_ * 1048576 + (size_t)kt * 8192
                           + dd * 32 + (((key >> 3) ^ (dd & 3)) << 3) + (key & 7);
                *(bf16x4*)(vt + off) = hv;
            }
    }
}

// ---------------------------------------------------------------------------
// GEMM2, same template/schedule, K = 2048 -> NT = 32, fp32 epilogue.
// ---------------------------------------------------------------------------
__global__ __launch_bounds__(512, 2)
void gemm2p(const bf16_t* __restrict__ A, const bf16_t* __restrict__ Bh,
            float* __restrict__ C)
{
    __shared__ __attribute__((aligned(16))) char smem[131072];
    const int tid = threadIdx.x, lane = tid & 63, wid = tid >> 6;
    const int g = lane >> 4, c16 = lane & 15;
    const int wm = wid >> 2, wn = wid & 3;
    const int m0 = blockIdx.y * 256, n0 = blockIdx.x * 256;
    const int swz = c16 & 7;
    const int NT = 32;                               // 2048 / 64

    f32x4 acc[8][4];
#pragma unroll
    for (int m = 0; m < 8; ++m)
#pragma unroll
        for (int n = 0; n < 4; ++n) acc[m][n] = (f32x4)(0.f);

    auto STAGE_A = [&](int dbuf, int kt, int half) {
#pragma unroll
        for (int pl = 0; pl < 2; ++pl) {
            int c = pl * 512 + tid;
            int row = c >> 3, b = c & 7;
            GLD_LDS16(A + (size_t)(m0 + half * 128 + row) * 2048 + kt * 64
                        + ((b ^ (row & 7)) << 3),
                      smem + dbuf * 65536 + half * 16384
                        + (pl * 512 + wid * 64) * 16);
        }
    };
    auto STAGE_B = [&](int dbuf, int kt, int qp) {
#pragma unroll
        for (int pl = 0; pl < 2; ++pl) {
            int c = pl * 512 + tid;
            int u = c >> 3, b = c & 7;
            int row = ((u >> 5) << 6) + qp * 32 + (u & 31);
            int u0 = pl * 64 + wid * 8;
            int row0 = ((u0 >> 5) << 6) + qp * 32 + (u0 & 31);
            GLD_LDS16(Bh + (size_t)(n0 + row) * 2048 + kt * 64
                        + ((b ^ (row & 7)) << 3),
                      smem + dbuf * 65536 + 32768 + row0 * 128);
        }
    };

    STAGE_A(0, 0, 0); STAGE_B(0, 0, 0); STAGE_A(0, 0, 1); STAGE_B(0, 0, 1);
    WAITV(2);
    BARRIER();

    for (int t = 0; t < NT; ++t) {
        const int buf = t & 1, nbuf = buf ^ 1;
        const char* Ab = smem + buf * 65536;
        const char* Bb = smem + buf * 65536 + 32768;
        auto rdA = [&](int m, int kk) {
            return *(const bf16x8*)(Ab + (wm * 128 + m * 16 + c16) * 128
                                       + (((kk * 4 + g) ^ swz) << 4));
        };
        auto rdB = [&](int n, int kk) {
            return *(const bf16x8*)(Bb + (wn * 64 + n * 16 + c16) * 128
                                       + (((kk * 4 + g) ^ swz) << 4));
        };
        bf16x8 a[8], b0, b1, b2, b3;

#pragma unroll
        for (int m = 0; m < 8; ++m) a[m] = rdA(m, 0);
        b0 = rdB(0, 0); b1 = rdB(1, 0);
        if (t + 1 < NT) { STAGE_A(nbuf, t + 1, 0); STAGE_B(nbuf, t + 1, 0); }
        BARRIER();
        __builtin_amdgcn_s_setprio(1);
#pragma unroll
        for (int m = 0; m < 8; ++m) {
            acc[m][0] = __builtin_amdgcn_mfma_f32_16x16x32_bf16(a[m], b0, acc[m][0], 0, 0, 0);
            acc[m][1] = __builtin_amdgcn_mfma_f32_16x16x32_bf16(a[m], b1, acc[m][1], 0, 0, 0);
        }
        __builtin_amdgcn_s_setprio(0);
        if (t + 1 < NT) { WAITV(4); } else { WAITV(0); }
        BARRIER();

        b2 = rdB(2, 0); b3 = rdB(3, 0);
        if (t + 1 < NT) { STAGE_A(nbuf, t + 1, 1); STAGE_B(nbuf, t + 1, 1); }
        BARRIER();
        __builtin_amdgcn_s_setprio(1);
#pragma unroll
        for (int m = 0; m < 8; ++m) {
            acc[m][2] = __builtin_amdgcn_mfma_f32_16x16x32_bf16(a[m], b2, acc[m][2], 0, 0, 0);
            acc[m][3] = __builtin_amdgcn_mfma_f32_16x16x32_bf16(a[m], b3, acc[m][3], 0, 0, 0);
        }
        __builtin_amdgcn_s_setprio(0);
        BARRIER();

#pragma unroll
        for (int m = 0; m < 8; ++m) a[m] = rdA(m, 1);
        b0 = rdB(0, 1); b1 = rdB(1, 1);
        BARRIER();
        __builtin_amdgcn_s_setprio(1);
#pragma unroll
        for (int m = 0; m < 8; ++m) {
            acc[m][0] = __builtin_amdgcn_mfma_f32_16x16x32_bf16(a[m], b0, acc[m][0], 0, 0, 0);
            acc[m][1] = __builtin_amdgcn_mfma_f32_16x16x32_bf16(a[m], b1, acc[m][1], 0, 0, 0);
        }
        __builtin_amdgcn_s_setprio(0);
        BARRIER();

        b2 = rdB(2, 1); b3 = rdB(3, 1);
        BARRIER();
        __builtin_amdgcn_s_setprio(1);
#pragma unroll
        for (int m = 0; m < 8; ++m) {
            acc[m][2] = __builtin_amdgcn_mfma_f32_16x16x32_bf16(a[m], b2, acc[m][2], 0, 0, 0);
            acc[m][3] = __builtin_amdgcn_mfma_f32_16x16x32_bf16(a[m], b3, acc[m][3], 0, 0, 0);
        }
        __builtin_amdgcn_s_setprio(0);
        if (t + 1 < NT) WAITV(2);
        BARRIER();
    }

#pragma unroll
    for (int m = 0; m < 8; ++m)
#pragma unroll
        for (int n = 0; n < 4; ++n) {
            int col = n0 + wn * 64 + n * 16 + c16;
            int rowb = m0 + wm * 128 + m * 16 + g * 4;
#pragma unroll
            for (int r = 0; r < 4; ++r)
                C[(size_t)(rowb + r) * 2560 + col] = acc[m][n][r];
        }
}

// ---------------------------------------------------------------------------
// Fused RMSNorm + RoPE: threads 0..255 handle q row (in-place), threads
// 256..511 handle k row (raw -> kb2 tiled+swizzled).
// ---------------------------------------------------------------------------
__global__ __launch_bounds__(512)
void norm_qk(bf16_t* __restrict__ qb, const bf16_t* __restrict__ kraw,
             bf16_t* __restrict__ kb2, const float* __restrict__ qw,
             const float* __restrict__ kw, const float* __restrict__ ct,
             const float* __restrict__ st)
{
    const int s = blockIdx.x, t = threadIdx.x;
    if (t < 256) {
        const int h = t >> 5, l = t & 31;
        bf16_t* base = qb + (size_t)s * 2048 + h * 256 + l * 8;
        bf16x8 hv = *(const bf16x8*)base;
        float x[8], ss = 0.f;
#pragma unroll
        for (int j = 0; j < 8; ++j) { x[j] = (float)hv[j]; ss += x[j] * x[j]; }
#pragma unroll
        for (int mk = 1; mk < 32; mk <<= 1) ss += __shfl_xor(ss, mk);
        const float rs = rsqrtf(ss * (1.f / 256.f) + 1e-6f);
        float4 w0 = *(const float4*)(qw + l * 8);
        float4 w1 = *(const float4*)(qw + l * 8 + 4);
        float wa[8] = { w0.x, w0.y, w0.z, w0.w, w1.x, w1.y, w1.z, w1.w };
        float xn[8];
#pragma unroll
        for (int j = 0; j < 8; ++j) xn[j] = x[j] * rs * (1.f + wa[j]);
        const int d0 = (l * 8) & 127;
        float4 c0 = *(const float4*)(ct + s * 128 + d0);
        float4 c1 = *(const float4*)(ct + s * 128 + d0 + 4);
        float4 s0 = *(const float4*)(st + s * 128 + d0);
        float4 s1 = *(const float4*)(st + s * 128 + d0 + 4);
        float cc[8] = { c0.x, c0.y, c0.z, c0.w, c1.x, c1.y, c1.z, c1.w };
        float sn[8] = { s0.x, s0.y, s0.z, s0.w, s1.x, s1.y, s1.z, s1.w };
        const bool upper = (l >= 16);
        bf16x8 oh;
#pragma unroll
        for (int j = 0; j < 8; ++j) {
            float pn = __shfl_xor(xn[j], 16);
            float rot = upper ? pn : -pn;
            oh[j] = (bf16_t)(xn[j] * cc[j] + rot * sn[j]);
        }
        *(bf16x8*)base = oh;
    } else {
        const int tk = t - 256;
        const int h = tk >> 6, l = tk & 63;
        const bf16_t* base = kraw + (size_t)s * 1024 + h * 256 + l * 4;
        bf16x4 hv = *(const bf16x4*)base;
        float x[4], ss = 0.f;
#pragma unroll
        for (int j = 0; j < 4; ++j) { x[j] = (float)hv[j]; ss += x[j] * x[j]; }
#pragma unroll
        for (int mk = 1; mk < 64; mk <<= 1) ss += __shfl_xor(ss, mk);
        const float rs = rsqrtf(ss * (1.f / 256.f) + 1e-6f);
        float4 w0 = *(const float4*)(kw + l * 4);
        float wa[4] = { w0.x, w0.y, w0.z, w0.w };
        float xn[4];
#pragma unroll
        for (int j = 0; j < 4; ++j) xn[j] = x[j] * rs * (1.f + wa[j]);
        const int d0 = (l * 4) & 127;
        float4 c0 = *(const float4*)(ct + s * 128 + d0);
        float4 s0 = *(const float4*)(st + s * 128 + d0);
        float cc[4] = { c0.x, c0.y, c0.z, c0.w };
        float sn[4] = { s0.x, s0.y, s0.z, s0.w };
        const bool upper = (l >= 32);
        bf16x4 oh;
#pragma unroll
        for (int j = 0; j < 4; ++j) {
            float pn = __shfl_xor(xn[j], 32);
            float rot = upper ? pn : -pn;
            oh[j] = (bf16_t)(xn[j] * cc[j] + rot * sn[j]);
        }
        bf16_t* dst = kb2 + (size_t)h * 1048576 + (size_t)(s >> 5) * 8192
                    + (s & 31) * 256 + (((l >> 1) ^ (s & 7)) << 3) + (l & 1) * 4;
        *(bf16x4*)dst = oh;
    }
}

// ---------------------------------------------------------------------------
// Sliding-window GQA flash attention, no-max softmax, pre-tiled K/V.
// ---------------------------------------------------------------------------
__global__ __launch_bounds__(256)
void attn_fwd6(const bf16_t* __restrict__ qb, const bf16_t* __restrict__ kb2,
               const bf16_t* __restrict__ vt2, bf16_t* __restrict__ attn)
{
    __shared__ __attribute__((aligned(16))) char smem[2 * 32768];
    __shared__ __attribute__((aligned(16))) bf16_t P[4][16][40];
    const int tid = threadIdx.x, lane = tid & 63, wid = tid >> 6;
    const int g = lane >> 4, c16 = lane & 15;
    const int h = blockIdx.x, kvh = h >> 1;
    const int by = blockIdx.y;
    const int qt = (by & 1) ? (63 - (by >> 1)) : (by >> 1);   // balance pair
    const int qrow0 = qt * 64 + wid * 16;

    const char* kslab = (const char*)kb2 + (size_t)kvh * 2097152;
    const char* vslab = (const char*)vt2 + (size_t)kvh * 2097152;

    bf16x8 qf[8];
#pragma unroll
    for (int c = 0; c < 8; ++c)
        qf[c] = *(const bf16x8*)(qb + (size_t)(qrow0 + c16) * 2048 + h * 256 + c * 32 + g * 8);

    float lrow[4] = { 0.f, 0.f, 0.f, 0.f };
    f32x4 acc[16];
#pragma unroll
    for (int nd = 0; nd < 16; ++nd) acc[nd] = (f32x4)(0.f);

    auto STAGE = [&](int buf, int kt) {
        char* Kd = smem + buf * 32768;
        char* Vd = smem + buf * 32768 + 16384;
        const char* ks = kslab + (size_t)kt * 16384;
        const char* vs = vslab + (size_t)kt * 16384;
#pragma unroll
        for (int j = 0; j < 4; ++j)
            GLD_LDS16(ks + (size_t)(j * 256 + tid) * 16, Kd + (j * 256 + wid * 64) * 16);
#pragma unroll
        for (int j = 0; j < 4; ++j)
            GLD_LDS16(vs + (size_t)(j * 256 + tid) * 16, Vd + (j * 256 + wid * 64) * 16);
    };

    const int ktb_lo = (qt >= 16) ? 2 * qt - 32 : 0;
    const int ktb_hi = 2 * qt + 1;
    int cur = 0;
    STAGE(0, ktb_lo);
    __syncthreads();

    const int swk = (c16 & 7) << 4;
    const int swv = (g ^ (c16 & 3)) << 4;
    const float S2 = 0.090168441f;   // 2^-4 * log2(e)

    for (int kt = ktb_lo; kt <= ktb_hi; ++kt) {
        if (kt < ktb_hi) STAGE(cur ^ 1, kt + 1);

        if (kt * 32 <= qrow0 + 15 && kt * 32 + 31 >= qrow0 - 1023) {
            const char* Kc = smem + cur * 32768;
            const char* Vc = smem + cur * 32768 + 16384;

            f32x4 scA[2], scB[2];
#pragma unroll
            for (int n = 0; n < 2; ++n) { scA[n] = (f32x4)(0.f); scB[n] = (f32x4)(0.f); }
            __builtin_amdgcn_s_setprio(1);
#pragma unroll
            for (int n = 0; n < 2; ++n) {
                const char* kr = Kc + (n * 16 + c16) * 512;
#pragma unroll
                for (int c = 0; c < 4; ++c) {
                    bf16x8 kf = *(const bf16x8*)(kr + ((((c * 4 + g) << 4) ^ swk)));
                    scA[n] = __builtin_amdgcn_mfma_f32_16x16x32_bf16(qf[c], kf, scA[n], 0, 0, 0);
                }
#pragma unroll
                for (int c = 4; c < 8; ++c) {
                    bf16x8 kf = *(const bf16x8*)(kr + ((((c * 4 + g) << 4) ^ swk)));
                    scB[n] = __builtin_amdgcn_mfma_f32_16x16x32_bf16(qf[c], kf, scB[n], 0, 0, 0);
                }
            }
            __builtin_amdgcn_s_setprio(0);

            float p2[2][4];
            const bool fullv = (kt * 32 + 31 <= qrow0) && (kt * 32 >= qrow0 - 1008);
            if (fullv) {
#pragma unroll
                for (int n = 0; n < 2; ++n)
#pragma unroll
                    for (int r = 0; r < 4; ++r)
                        p2[n][r] = __builtin_amdgcn_exp2f((scA[n][r] + scB[n][r]) * S2);
            } else {
#pragma unroll
                for (int n = 0; n < 2; ++n) {
                    const int key = kt * 32 + n * 16 + c16;
#pragma unroll
                    for (int r = 0; r < 4; ++r) {
                        const int q = qrow0 + g * 4 + r;
                        bool valid = (key <= q) && (q - key < 1024);
                        float e = __builtin_amdgcn_exp2f((scA[n][r] + scB[n][r]) * S2);
                        p2[n][r] = valid ? e : 0.f;
                    }
                }
            }
#pragma unroll
            for (int n = 0; n < 2; ++n)
#pragma unroll
                for (int r = 0; r < 4; ++r) lrow[r] += p2[n][r];

#pragma unroll
            for (int n = 0; n < 2; ++n)
#pragma unroll
                for (int r = 0; r < 4; ++r)
                    P[wid][g * 4 + r][n * 16 + c16] = (bf16_t)p2[n][r];
            bf16x8 pa = *(const bf16x8*)(&P[wid][c16][g * 8]);
            __builtin_amdgcn_s_setprio(1);
#pragma unroll
            for (int nd = 0; nd < 16; ++nd) {
                bf16x8 vf = *(const bf16x8*)(Vc + (nd * 16 + c16) * 64 + swv);
                acc[nd] = __builtin_amdgcn_mfma_f32_16x16x32_bf16(pa, vf, acc[nd], 0, 0, 0);
            }
            __builtin_amdgcn_s_setprio(0);
        }
        __syncthreads();
        cur ^= 1;
    }

#pragma unroll
    for (int mk = 1; mk < 16; mk <<= 1)
#pragma unroll
        for (int r = 0; r < 4; ++r) lrow[r] += __shfl_xor(lrow[r], mk);

    float inv[4];
#pragma unroll
    for (int r = 0; r < 4; ++r) inv[r] = 1.f / lrow[r];
#pragma unroll
    for (int nd = 0; nd < 16; ++nd)
#pragma unroll
        for (int r = 0; r < 4; ++r) {
            int row = qrow0 + g * 4 + r;
            attn[(size_t)row * 2048 + h * 256 + nd * 16 + c16] =
                (bf16_t)(acc[nd][r] * inv[r]);
        }
}

// ---------------------------------------------------------------------------
// Workspace (peak ~79.7 MB, phase-aliased):
//   hs_bf [0,          20,971,520)  (dead after gemm1)
//   qb    [20,971,520, 37,748,736)
//   kb_raw[37,748,736, 46,137,344)  (dead after norm_qk)
//   vt2   [46,137,344, 54,525,952)  tiled+swizzled
//   Bh    [54,525,952, 75,497,472)  (dead after gemm1)
//   kb2   [54,525,952, 62,914,560)  (over dead Bh; by norm_qk)
//   ct    [75,497,472, 77,594,624)
//   st    [77,594,624, 79,691,776)
//   attnb [0,          16,777,216)  (over dead hs_bf)
//   woh   [20,971,520, 31,457,280)  (over dead qb, after attn)
// ---------------------------------------------------------------------------
extern "C" void kernel_launch(void* const* d_in, const int* in_sizes, int n_in,
                              void* d_out, int out_size, void* d_ws, size_t ws_size,
                              hipStream_t stream)
{
    (void)in_sizes; (void)n_in; (void)out_size; (void)ws_size;
    const float* hs  = (const float*)d_in[0];
    const float* wq  = (const float*)d_in[3];
    const float* wk  = (const float*)d_in[4];
    const float* wv  = (const float*)d_in[5];
    const float* wo  = (const float*)d_in[6];
    const float* qnw = (const float*)d_in[7];
    const float* knw = (const float*)d_in[8];

    char* ws = (char*)d_ws;
    bf16_t* hs_bf = (bf16_t*)(ws);
    bf16_t* qb    = (bf16_t*)(ws + 20971520);
    bf16_t* kraw  = (bf16_t*)(ws + 37748736);
    bf16_t* vt2   = (bf16_t*)(ws + 46137344);
    bf16_t* Bh    = (bf16_t*)(ws + 54525952);
    bf16_t* kb2   = (bf16_t*)(ws + 54525952);
    float*  ct    = (float*)(ws + 75497472);
    float*  st    = (float*)(ws + 77594624);
    bf16_t* attnb = (bf16_t*)(ws);
    bf16_t* woh   = (bf16_t*)(ws + 20971520);

    // 1. fused prep: hs->bf16 + wq/wk/wv -> Bh panel; rope tables
    prep<<<12800, 256, 0, stream>>>(hs, hs_bf, wq, wk, wv, Bh);
    rope_tables<<<2048, 256, 0, stream>>>(ct, st);

    // 2. fused qkv projection (8-phase 256^2, early-issue counted vmcnt)
    gemm1<<<dim3(16, 16), 512, 0, stream>>>(hs_bf, Bh, qb, kraw, vt2);

    // 3. fused norms (q in-place; k re-tiled into kb2 over dead Bh)
    norm_qk<<<4096, 512, 0, stream>>>(qb, kraw, kb2, qnw, knw, ct, st);

    // 4. attention (grid (h, qt) -> head-per-XCD pinning)
    attn_fwd6<<<dim3(8, 64), 256, 0, stream>>>(qb, kb2, vt2, attnb);

    // 5. wo -> woT panel (over dead qb), then output projection
    transpose_h<<<dim3(40, 32), 256, 0, stream>>>(wo, woh, 2048, 2560);
    gemm2p<<<dim3(10, 16), 512, 0, stream>>>(attnb, woh, (float*)d_out);
}

// Round 14
// 233.873 us; speedup vs baseline: 5.0943x; 1.0247x over previous
//
#include <hip/hip_runtime.h>
#include <stdint.h>
#include <math.h>

typedef __bf16 bf16_t;
typedef __bf16 bf16x8 __attribute__((ext_vector_type(8)));
typedef __bf16 bf16x4 __attribute__((ext_vector_type(4)));
typedef float f32x4 __attribute__((ext_vector_type(4)));

#define GLD_LDS16(g, l)                                             \
    __builtin_amdgcn_global_load_lds(                               \
        (const __attribute__((address_space(1))) void*)(g),         \
        (__attribute__((address_space(3))) void*)(l), 16, 0, 0)

#define WAITV(N) asm volatile("s_waitcnt vmcnt(" #N ")" ::: "memory")
#define BARRIER() do { __builtin_amdgcn_sched_barrier(0);           \
                       __builtin_amdgcn_s_barrier();                \
                       __builtin_amdgcn_sched_barrier(0); } while (0)

// ---------------------------------------------------------------------------
// prep: fused weight transposes (wq/wk/wv -> Bh panel) + RoPE tables +
// hs fp32->bf16 conv.
// blocks [0,1280) wq | [1280,1920) wk | [1920,2560) wv | [2560,4608) rope |
//        [4608,14848) conv.
// ---------------------------------------------------------------------------
__global__ __launch_bounds__(256)
void prep(const float* __restrict__ hs, bf16_t* __restrict__ hsb,
          const float* __restrict__ wq, const float* __restrict__ wk,
          const float* __restrict__ wv, bf16_t* __restrict__ Bh,
          float* __restrict__ ct, float* __restrict__ st)
{
    const int b = blockIdx.x;
    if (b >= 4608) {                       // conv: 10240 blocks x 256 x 4
        int i = (b - 4608) * 256 + threadIdx.x;
        float4 v = ((const float4*)hs)[i];
        bf16x4 o = { (bf16_t)v.x, (bf16_t)v.y, (bf16_t)v.z, (bf16_t)v.w };
        ((bf16x4*)hsb)[i] = o;
        return;
    }
    if (b >= 2560) {                       // rope tables: 2048 blocks
        int t = (b - 2560) * 256 + threadIdx.x;   // 4096*128
        int s = t >> 7, j = t & 127;
        double inv = exp2((double)j * (-13.28771237954945 / 128.0));
        double ang = fmod((double)s * inv, 6.283185307179586476925286766559);
        ct[t] = (float)cos(ang);
        st[t] = (float)sin(ang);
        return;
    }
    const float* src; bf16_t* dst; int C, bx, by;
    if (b < 1280)      { src = wq; dst = Bh;                          C = 2048; bx = b % 32;          by = b / 32; }
    else if (b < 1920) { src = wk; dst = Bh + (size_t)2048 * 2560;    C = 1024; bx = (b - 1280) % 16; by = (b - 1280) / 16; }
    else               { src = wv; dst = Bh + (size_t)3072 * 2560;    C = 1024; bx = (b - 1920) % 16; by = (b - 1920) / 16; }
    const int R = 2560;
    __shared__ float t[64][65];
    const int r0 = by * 64, c0 = bx * 64;
#pragma unroll
    for (int i = 0; i < 16; ++i) {
        int f = threadIdx.x + i * 256;
        int r = f >> 6, c = f & 63;
        t[r][c] = src[(size_t)(r0 + r) * C + c0 + c];
    }
    __syncthreads();
#pragma unroll
    for (int i = 0; i < 16; ++i) {
        int f = threadIdx.x + i * 256;
        int r = f >> 6, c = f & 63;
        dst[(size_t)(c0 + r) * R + r0 + c] = (bf16_t)t[c][r];
    }
}

// ---------------------------------------------------------------------------
// transpose + convert: in [R][C] fp32 -> out [C][R] bf16   (for wo)
// ---------------------------------------------------------------------------
__global__ __launch_bounds__(256)
void transpose_h(const float* __restrict__ in, bf16_t* __restrict__ out,
                 int R, int C)
{
    __shared__ float t[64][65];
    const int r0 = blockIdx.y * 64, c0 = blockIdx.x * 64;
#pragma unroll
    for (int i = 0; i < 16; ++i) {
        int f = threadIdx.x + i * 256;
        int r = f >> 6, c = f & 63;
        t[r][c] = in[(size_t)(r0 + r) * C + c0 + c];
    }
    __syncthreads();
#pragma unroll
    for (int i = 0; i < 16; ++i) {
        int f = threadIdx.x + i * 256;
        int r = f >> 6, c = f & 63;
        out[(size_t)(c0 + r) * R + r0 + c] = (bf16_t)t[c][r];
    }
}

// ---------------------------------------------------------------------------
// GEMM1 (fused qkv), 8-phase 256x256 tile, BK=64, 8 waves (2Mx4N), 128 KiB
// LDS double-buffer, XOR-swizzled, counted vmcnt — round-12 proven schedule
// (one stage unit per phase; WAITV(2)@P0-end and @P3-end).
// ---------------------------------------------------------------------------
__global__ __launch_bounds__(512, 2)
void gemm1(const bf16_t* __restrict__ A, const bf16_t* __restrict__ Bh,
           bf16_t* __restrict__ qb, bf16_t* __restrict__ kb,
           bf16_t* __restrict__ vt)
{
    __shared__ __attribute__((aligned(16))) char smem[131072];
    const int tid = threadIdx.x, lane = tid & 63, wid = tid >> 6;
    const int g = lane >> 4, c16 = lane & 15;
    const int wm = wid >> 2, wn = wid & 3;          // 2 x 4 wave grid
    const int m0 = blockIdx.y * 256, n0 = blockIdx.x * 256;
    const int swz = c16 & 7;
    const int NT = 40;                               // 2560 / 64

    f32x4 acc[8][4];
#pragma unroll
    for (int m = 0; m < 8; ++m)
#pragma unroll
        for (int n = 0; n < 4; ++n) acc[m][n] = (f32x4)(0.f);

    auto STAGE_A = [&](int dbuf, int kt, int half) {
#pragma unroll
        for (int pl = 0; pl < 2; ++pl) {
            int c = pl * 512 + tid;
            int row = c >> 3, b = c & 7;
            GLD_LDS16(A + (size_t)(m0 + half * 128 + row) * 2560 + kt * 64
                        + ((b ^ (row & 7)) << 3),
                      smem + dbuf * 65536 + half * 16384
                        + (pl * 512 + wid * 64) * 16);
        }
    };
    auto STAGE_B = [&](int dbuf, int kt, int qp) {
#pragma unroll
        for (int pl = 0; pl < 2; ++pl) {
            int c = pl * 512 + tid;
            int u = c >> 3, b = c & 7;
            int row = ((u >> 5) << 6) + qp * 32 + (u & 31);
            int u0 = pl * 64 + wid * 8;
            int row0 = ((u0 >> 5) << 6) + qp * 32 + (u0 & 31);
            GLD_LDS16(Bh + (size_t)(n0 + row) * 2560 + kt * 64
                        + ((b ^ (row & 7)) << 3),
                      smem + dbuf * 65536 + 32768 + row0 * 128);
        }
    };

    STAGE_A(0, 0, 0); STAGE_A(0, 0, 1); STAGE_B(0, 0, 0); STAGE_B(0, 0, 1);
    WAITV(2);
    BARRIER();

    for (int t = 0; t < NT; ++t) {
        const int buf = t & 1, nbuf = buf ^ 1;
        const char* Ab = smem + buf * 65536;
        const char* Bb = smem + buf * 65536 + 32768;
        auto rdA = [&](int m, int kk) {
            return *(const bf16x8*)(Ab + (wm * 128 + m * 16 + c16) * 128
                                       + (((kk * 4 + g) ^ swz) << 4));
        };
        auto rdB = [&](int n, int kk) {
            return *(const bf16x8*)(Bb + (wn * 64 + n * 16 + c16) * 128
                                       + (((kk * 4 + g) ^ swz) << 4));
        };
        bf16x8 a[8], b0, b1, b2, b3;

        // ---- P0: n{0,1} kk0; issue t+1.A0 ----------------------------
#pragma unroll
        for (int m = 0; m < 8; ++m) a[m] = rdA(m, 0);
        b0 = rdB(0, 0); b1 = rdB(1, 0);
        if (t + 1 < NT) STAGE_A(nbuf, t + 1, 0);
        BARRIER();
        __builtin_amdgcn_s_setprio(1);
#pragma unroll
        for (int m = 0; m < 8; ++m) {
            acc[m][0] = __builtin_amdgcn_mfma_f32_16x16x32_bf16(a[m], b0, acc[m][0], 0, 0, 0);
            acc[m][1] = __builtin_amdgcn_mfma_f32_16x16x32_bf16(a[m], b1, acc[m][1], 0, 0, 0);
        }
        __builtin_amdgcn_s_setprio(0);
        if (t + 1 < NT) { WAITV(2); } else { WAITV(0); }   // t.Bq23 landed
        BARRIER();

        // ---- P1: n{2,3} kk0; issue t+1.A1 ----------------------------
        b2 = rdB(2, 0); b3 = rdB(3, 0);
        if (t + 1 < NT) STAGE_A(nbuf, t + 1, 1);
        BARRIER();
        __builtin_amdgcn_s_setprio(1);
#pragma unroll
        for (int m = 0; m < 8; ++m) {
            acc[m][2] = __builtin_amdgcn_mfma_f32_16x16x32_bf16(a[m], b2, acc[m][2], 0, 0, 0);
            acc[m][3] = __builtin_amdgcn_mfma_f32_16x16x32_bf16(a[m], b3, acc[m][3], 0, 0, 0);
        }
        __builtin_amdgcn_s_setprio(0);
        BARRIER();

        // ---- P2: n{0,1} kk1; issue t+1.Bq0 ---------------------------
#pragma unroll
        for (int m = 0; m < 8; ++m) a[m] = rdA(m, 1);
        b0 = rdB(0, 1); b1 = rdB(1, 1);
        if (t + 1 < NT) STAGE_B(nbuf, t + 1, 0);
        BARRIER();
        __builtin_amdgcn_s_setprio(1);
#pragma unroll
        for (int m = 0; m < 8; ++m) {
            acc[m][0] = __builtin_amdgcn_mfma_f32_16x16x32_bf16(a[m], b0, acc[m][0], 0, 0, 0);
            acc[m][1] = __builtin_amdgcn_mfma_f32_16x16x32_bf16(a[m], b1, acc[m][1], 0, 0, 0);
        }
        __builtin_amdgcn_s_setprio(0);
        BARRIER();

        // ---- P3: n{2,3} kk1; issue t+1.Bq1 ---------------------------
        b2 = rdB(2, 1); b3 = rdB(3, 1);
        if (t + 1 < NT) STAGE_B(nbuf, t + 1, 1);
        BARRIER();
        __builtin_amdgcn_s_setprio(1);
#pragma unroll
        for (int m = 0; m < 8; ++m) {
            acc[m][2] = __builtin_amdgcn_mfma_f32_16x16x32_bf16(a[m], b2, acc[m][2], 0, 0, 0);
            acc[m][3] = __builtin_amdgcn_mfma_f32_16x16x32_bf16(a[m], b3, acc[m][3], 0, 0, 0);
        }
        __builtin_amdgcn_s_setprio(0);
        if (t + 1 < NT) WAITV(2);   // t+1.{A0,A1} landed; Bq01/Bq23 fly
        BARRIER();
    }

    if (n0 < 2048) {          // q region
#pragma unroll
        for (int m = 0; m < 8; ++m)
#pragma unroll
            for (int n = 0; n < 4; ++n) {
                int col = n0 + wn * 64 + n * 16 + c16;
                int rowb = m0 + wm * 128 + m * 16 + g * 4;
#pragma unroll
                for (int r = 0; r < 4; ++r)
                    qb[(size_t)(rowb + r) * 2048 + col] = (bf16_t)acc[m][n][r];
            }
    } else if (n0 < 3072) {   // k region (raw, re-tiled by norm_qk)
#pragma unroll
        for (int m = 0; m < 8; ++m)
#pragma unroll
            for (int n = 0; n < 4; ++n) {
                int col = n0 + wn * 64 + n * 16 + c16 - 2048;
                int rowb = m0 + wm * 128 + m * 16 + g * 4;
#pragma unroll
                for (int r = 0; r < 4; ++r)
                    kb[(size_t)(rowb + r) * 1024 + col] = (bf16_t)acc[m][n][r];
            }
    } else {                  // v region -> vt2 tiled + swizzled
#pragma unroll
        for (int m = 0; m < 8; ++m)
#pragma unroll
            for (int n = 0; n < 4; ++n) {
                int d = n0 + wn * 64 + n * 16 + c16 - 3072;
                int rowb = m0 + wm * 128 + m * 16 + g * 4;
                int kvh_ = d >> 8, dd = d & 255;
                int kt = rowb >> 5, key = rowb & 31;
                bf16x4 hv;
#pragma unroll
                for (int r = 0; r < 4; ++r) hv[r] = (bf16_t)acc[m][n][r];
                size_t off = (size_t)kvh_ * 1048576 + (size_t)kt * 8192
                           + dd * 32 + (((key >> 3) ^ (dd & 3)) << 3) + (key & 7);
                *(bf16x4*)(vt + off) = hv;
            }
    }
}

// ---------------------------------------------------------------------------
// GEMM2, same template/schedule (round-12), K = 2048 -> NT = 32, fp32 out.
// ---------------------------------------------------------------------------
__global__ __launch_bounds__(512, 2)
void gemm2p(const bf16_t* __restrict__ A, const bf16_t* __restrict__ Bh,
            float* __restrict__ C)
{
    __shared__ __attribute__((aligned(16))) char smem[131072];
    const int tid = threadIdx.x, lane = tid & 63, wid = tid >> 6;
    const int g = lane >> 4, c16 = lane & 15;
    const int wm = wid >> 2, wn = wid & 3;
    const int m0 = blockIdx.y * 256, n0 = blockIdx.x * 256;
    const int swz = c16 & 7;
    const int NT = 32;                               // 2048 / 64

    f32x4 acc[8][4];
#pragma unroll
    for (int m = 0; m < 8; ++m)
#pragma unroll
        for (int n = 0; n < 4; ++n) acc[m][n] = (f32x4)(0.f);

    auto STAGE_A = [&](int dbuf, int kt, int half) {
#pragma unroll
        for (int pl = 0; pl < 2; ++pl) {
            int c = pl * 512 + tid;
            int row = c >> 3, b = c & 7;
            GLD_LDS16(A + (size_t)(m0 + half * 128 + row) * 2048 + kt * 64
                        + ((b ^ (row & 7)) << 3),
                      smem + dbuf * 65536 + half * 16384
                        + (pl * 512 + wid * 64) * 16);
        }
    };
    auto STAGE_B = [&](int dbuf, int kt, int qp) {
#pragma unroll
        for (int pl = 0; pl < 2; ++pl) {
            int c = pl * 512 + tid;
            int u = c >> 3, b = c & 7;
            int row = ((u >> 5) << 6) + qp * 32 + (u & 31);
            int u0 = pl * 64 + wid * 8;
            int row0 = ((u0 >> 5) << 6) + qp * 32 + (u0 & 31);
            GLD_LDS16(Bh + (size_t)(n0 + row) * 2048 + kt * 64
                        + ((b ^ (row & 7)) << 3),
                      smem + dbuf * 65536 + 32768 + row0 * 128);
        }
    };

    STAGE_A(0, 0, 0); STAGE_A(0, 0, 1); STAGE_B(0, 0, 0); STAGE_B(0, 0, 1);
    WAITV(2);
    BARRIER();

    for (int t = 0; t < NT; ++t) {
        const int buf = t & 1, nbuf = buf ^ 1;
        const char* Ab = smem + buf * 65536;
        const char* Bb = smem + buf * 65536 + 32768;
        auto rdA = [&](int m, int kk) {
            return *(const bf16x8*)(Ab + (wm * 128 + m * 16 + c16) * 128
                                       + (((kk * 4 + g) ^ swz) << 4));
        };
        auto rdB = [&](int n, int kk) {
            return *(const bf16x8*)(Bb + (wn * 64 + n * 16 + c16) * 128
                                       + (((kk * 4 + g) ^ swz) << 4));
        };
        bf16x8 a[8], b0, b1, b2, b3;

#pragma unroll
        for (int m = 0; m < 8; ++m) a[m] = rdA(m, 0);
        b0 = rdB(0, 0); b1 = rdB(1, 0);
        if (t + 1 < NT) STAGE_A(nbuf, t + 1, 0);
        BARRIER();
        __builtin_amdgcn_s_setprio(1);
#pragma unroll
        for (int m = 0; m < 8; ++m) {
            acc[m][0] = __builtin_amdgcn_mfma_f32_16x16x32_bf16(a[m], b0, acc[m][0], 0, 0, 0);
            acc[m][1] = __builtin_amdgcn_mfma_f32_16x16x32_bf16(a[m], b1, acc[m][1], 0, 0, 0);
        }
        __builtin_amdgcn_s_setprio(0);
        if (t + 1 < NT) { WAITV(2); } else { WAITV(0); }
        BARRIER();

        b2 = rdB(2, 0); b3 = rdB(3, 0);
        if (t + 1 < NT) STAGE_A(nbuf, t + 1, 1);
        BARRIER();
        __builtin_amdgcn_s_setprio(1);
#pragma unroll
        for (int m = 0; m < 8; ++m) {
            acc[m][2] = __builtin_amdgcn_mfma_f32_16x16x32_bf16(a[m], b2, acc[m][2], 0, 0, 0);
            acc[m][3] = __builtin_amdgcn_mfma_f32_16x16x32_bf16(a[m], b3, acc[m][3], 0, 0, 0);
        }
        __builtin_amdgcn_s_setprio(0);
        BARRIER();

#pragma unroll
        for (int m = 0; m < 8; ++m) a[m] = rdA(m, 1);
        b0 = rdB(0, 1); b1 = rdB(1, 1);
        if (t + 1 < NT) STAGE_B(nbuf, t + 1, 0);
        BARRIER();
        __builtin_amdgcn_s_setprio(1);
#pragma unroll
        for (int m = 0; m < 8; ++m) {
            acc[m][0] = __builtin_amdgcn_mfma_f32_16x16x32_bf16(a[m], b0, acc[m][0], 0, 0, 0);
            acc[m][1] = __builtin_amdgcn_mfma_f32_16x16x32_bf16(a[m], b1, acc[m][1], 0, 0, 0);
        }
        __builtin_amdgcn_s_setprio(0);
        BARRIER();

        b2 = rdB(2, 1); b3 = rdB(3, 1);
        if (t + 1 < NT) STAGE_B(nbuf, t + 1, 1);
        BARRIER();
        __builtin_amdgcn_s_setprio(1);
#pragma unroll
        for (int m = 0; m < 8; ++m) {
            acc[m][2] = __builtin_amdgcn_mfma_f32_16x16x32_bf16(a[m], b2, acc[m][2], 0, 0, 0);
            acc[m][3] = __builtin_amdgcn_mfma_f32_16x16x32_bf16(a[m], b3, acc[m][3], 0, 0, 0);
        }
        __builtin_amdgcn_s_setprio(0);
        if (t + 1 < NT) WAITV(2);
        BARRIER();
    }

#pragma unroll
    for (int m = 0; m < 8; ++m)
#pragma unroll
        for (int n = 0; n < 4; ++n) {
            int col = n0 + wn * 64 + n * 16 + c16;
            int rowb = m0 + wm * 128 + m * 16 + g * 4;
#pragma unroll
            for (int r = 0; r < 4; ++r)
                C[(size_t)(rowb + r) * 2560 + col] = acc[m][n][r];
        }
}

// ---------------------------------------------------------------------------
// Fused RMSNorm + RoPE: threads 0..255 handle q row (in-place), threads
// 256..511 handle k row (raw -> kb2 tiled+swizzled).
// ---------------------------------------------------------------------------
__global__ __launch_bounds__(512)
void norm_qk(bf16_t* __restrict__ qb, const bf16_t* __restrict__ kraw,
             bf16_t* __restrict__ kb2, const float* __restrict__ qw,
             const float* __restrict__ kw, const float* __restrict__ ct,
             const float* __restrict__ st)
{
    const int s = blockIdx.x, t = threadIdx.x;
    if (t < 256) {
        const int h = t >> 5, l = t & 31;
        bf16_t* base = qb + (size_t)s * 2048 + h * 256 + l * 8;
        bf16x8 hv = *(const bf16x8*)base;
        float x[8], ss = 0.f;
#pragma unroll
        for (int j = 0; j < 8; ++j) { x[j] = (float)hv[j]; ss += x[j] * x[j]; }
#pragma unroll
        for (int mk = 1; mk < 32; mk <<= 1) ss += __shfl_xor(ss, mk);
        const float rs = rsqrtf(ss * (1.f / 256.f) + 1e-6f);
        float4 w0 = *(const float4*)(qw + l * 8);
        float4 w1 = *(const float4*)(qw + l * 8 + 4);
        float wa[8] = { w0.x, w0.y, w0.z, w0.w, w1.x, w1.y, w1.z, w1.w };
        float xn[8];
#pragma unroll
        for (int j = 0; j < 8; ++j) xn[j] = x[j] * rs * (1.f + wa[j]);
        const int d0 = (l * 8) & 127;
        float4 c0 = *(const float4*)(ct + s * 128 + d0);
        float4 c1 = *(const float4*)(ct + s * 128 + d0 + 4);
        float4 s0 = *(const float4*)(st + s * 128 + d0);
        float4 s1 = *(const float4*)(st + s * 128 + d0 + 4);
        float cc[8] = { c0.x, c0.y, c0.z, c0.w, c1.x, c1.y, c1.z, c1.w };
        float sn[8] = { s0.x, s0.y, s0.z, s0.w, s1.x, s1.y, s1.z, s1.w };
        const bool upper = (l >= 16);
        bf16x8 oh;
#pragma unroll
        for (int j = 0; j < 8; ++j) {
            float pn = __shfl_xor(xn[j], 16);
            float rot = upper ? pn : -pn;
            oh[j] = (bf16_t)(xn[j] * cc[j] + rot * sn[j]);
        }
        *(bf16x8*)base = oh;
    } else {
        const int tk = t - 256;
        const int h = tk >> 6, l = tk & 63;
        const bf16_t* base = kraw + (size_t)s * 1024 + h * 256 + l * 4;
        bf16x4 hv = *(const bf16x4*)base;
        float x[4], ss = 0.f;
#pragma unroll
        for (int j = 0; j < 4; ++j) { x[j] = (float)hv[j]; ss += x[j] * x[j]; }
#pragma unroll
        for (int mk = 1; mk < 64; mk <<= 1) ss += __shfl_xor(ss, mk);
        const float rs = rsqrtf(ss * (1.f / 256.f) + 1e-6f);
        float4 w0 = *(const float4*)(kw + l * 4);
        float wa[4] = { w0.x, w0.y, w0.z, w0.w };
        float xn[4];
#pragma unroll
        for (int j = 0; j < 4; ++j) xn[j] = x[j] * rs * (1.f + wa[j]);
        const int d0 = (l * 4) & 127;
        float4 c0 = *(const float4*)(ct + s * 128 + d0);
        float4 s0 = *(const float4*)(st + s * 128 + d0);
        float cc[4] = { c0.x, c0.y, c0.z, c0.w };
        float sn[4] = { s0.x, s0.y, s0.z, s0.w };
        const bool upper = (l >= 32);
        bf16x4 oh;
#pragma unroll
        for (int j = 0; j < 4; ++j) {
            float pn = __shfl_xor(xn[j], 32);
            float rot = upper ? pn : -pn;
            oh[j] = (bf16_t)(xn[j] * cc[j] + rot * sn[j]);
        }
        bf16_t* dst = kb2 + (size_t)h * 1048576 + (size_t)(s >> 5) * 8192
                    + (s & 31) * 256 + (((l >> 1) ^ (s & 7)) << 3) + (l & 1) * 4;
        *(bf16x4*)dst = oh;
    }
}

// ---------------------------------------------------------------------------
// Sliding-window GQA flash attention, no-max softmax, pre-tiled K/V.
// ---------------------------------------------------------------------------
__global__ __launch_bounds__(256)
void attn_fwd6(const bf16_t* __restrict__ qb, const bf16_t* __restrict__ kb2,
               const bf16_t* __restrict__ vt2, bf16_t* __restrict__ attn)
{
    __shared__ __attribute__((aligned(16))) char smem[2 * 32768];
    __shared__ __attribute__((aligned(16))) bf16_t P[4][16][40];
    const int tid = threadIdx.x, lane = tid & 63, wid = tid >> 6;
    const int g = lane >> 4, c16 = lane & 15;
    const int h = blockIdx.x, kvh = h >> 1;
    const int by = blockIdx.y;
    const int qt = (by & 1) ? (63 - (by >> 1)) : (by >> 1);   // balance pair
    const int qrow0 = qt * 64 + wid * 16;

    const char* kslab = (const char*)kb2 + (size_t)kvh * 2097152;
    const char* vslab = (const char*)vt2 + (size_t)kvh * 2097152;

    bf16x8 qf[8];
#pragma unroll
    for (int c = 0; c < 8; ++c)
        qf[c] = *(const bf16x8*)(qb + (size_t)(qrow0 + c16) * 2048 + h * 256 + c * 32 + g * 8);

    float lrow[4] = { 0.f, 0.f, 0.f, 0.f };
    f32x4 acc[16];
#pragma unroll
    for (int nd = 0; nd < 16; ++nd) acc[nd] = (f32x4)(0.f);

    auto STAGE = [&](int buf, int kt) {
        char* Kd = smem + buf * 32768;
        char* Vd = smem + buf * 32768 + 16384;
        const char* ks = kslab + (size_t)kt * 16384;
        const char* vs = vslab + (size_t)kt * 16384;
#pragma unroll
        for (int j = 0; j < 4; ++j)
            GLD_LDS16(ks + (size_t)(j * 256 + tid) * 16, Kd + (j * 256 + wid * 64) * 16);
#pragma unroll
        for (int j = 0; j < 4; ++j)
            GLD_LDS16(vs + (size_t)(j * 256 + tid) * 16, Vd + (j * 256 + wid * 64) * 16);
    };

    const int ktb_lo = (qt >= 16) ? 2 * qt - 32 : 0;
    const int ktb_hi = 2 * qt + 1;
    int cur = 0;
    STAGE(0, ktb_lo);
    __syncthreads();

    const int swk = (c16 & 7) << 4;
    const int swv = (g ^ (c16 & 3)) << 4;
    const float S2 = 0.090168441f;   // 2^-4 * log2(e)

    for (int kt = ktb_lo; kt <= ktb_hi; ++kt) {
        if (kt < ktb_hi) STAGE(cur ^ 1, kt + 1);

        if (kt * 32 <= qrow0 + 15 && kt * 32 + 31 >= qrow0 - 1023) {
            const char* Kc = smem + cur * 32768;
            const char* Vc = smem + cur * 32768 + 16384;

            f32x4 scA[2], scB[2];
#pragma unroll
            for (int n = 0; n < 2; ++n) { scA[n] = (f32x4)(0.f); scB[n] = (f32x4)(0.f); }
            __builtin_amdgcn_s_setprio(1);
#pragma unroll
            for (int n = 0; n < 2; ++n) {
                const char* kr = Kc + (n * 16 + c16) * 512;
#pragma unroll
                for (int c = 0; c < 4; ++c) {
                    bf16x8 kf = *(const bf16x8*)(kr + ((((c * 4 + g) << 4) ^ swk)));
                    scA[n] = __builtin_amdgcn_mfma_f32_16x16x32_bf16(qf[c], kf, scA[n], 0, 0, 0);
                }
#pragma unroll
                for (int c = 4; c < 8; ++c) {
                    bf16x8 kf = *(const bf16x8*)(kr + ((((c * 4 + g) << 4) ^ swk)));
                    scB[n] = __builtin_amdgcn_mfma_f32_16x16x32_bf16(qf[c], kf, scB[n], 0, 0, 0);
                }
            }
            __builtin_amdgcn_s_setprio(0);

            float p2[2][4];
            const bool fullv = (kt * 32 + 31 <= qrow0) && (kt * 32 >= qrow0 - 1008);
            if (fullv) {
#pragma unroll
                for (int n = 0; n < 2; ++n)
#pragma unroll
                    for (int r = 0; r < 4; ++r)
                        p2[n][r] = __builtin_amdgcn_exp2f((scA[n][r] + scB[n][r]) * S2);
            } else {
#pragma unroll
                for (int n = 0; n < 2; ++n) {
                    const int key = kt * 32 + n * 16 + c16;
#pragma unroll
                    for (int r = 0; r < 4; ++r) {
                        const int q = qrow0 + g * 4 + r;
                        bool valid = (key <= q) && (q - key < 1024);
                        float e = __builtin_amdgcn_exp2f((scA[n][r] + scB[n][r]) * S2);
                        p2[n][r] = valid ? e : 0.f;
                    }
                }
            }
#pragma unroll
            for (int n = 0; n < 2; ++n)
#pragma unroll
                for (int r = 0; r < 4; ++r) lrow[r] += p2[n][r];

#pragma unroll
            for (int n = 0; n < 2; ++n)
#pragma unroll
                for (int r = 0; r < 4; ++r)
                    P[wid][g * 4 + r][n * 16 + c16] = (bf16_t)p2[n][r];
            bf16x8 pa = *(const bf16x8*)(&P[wid][c16][g * 8]);
            __builtin_amdgcn_s_setprio(1);
#pragma unroll
            for (int nd = 0; nd < 16; ++nd) {
                bf16x8 vf = *(const bf16x8*)(Vc + (nd * 16 + c16) * 64 + swv);
                acc[nd] = __builtin_amdgcn_mfma_f32_16x16x32_bf16(pa, vf, acc[nd], 0, 0, 0);
            }
            __builtin_amdgcn_s_setprio(0);
        }
        __syncthreads();
        cur ^= 1;
    }

#pragma unroll
    for (int mk = 1; mk < 16; mk <<= 1)
#pragma unroll
        for (int r = 0; r < 4; ++r) lrow[r] += __shfl_xor(lrow[r], mk);

    float inv[4];
#pragma unroll
    for (int r = 0; r < 4; ++r) inv[r] = 1.f / lrow[r];
#pragma unroll
    for (int nd = 0; nd < 16; ++nd)
#pragma unroll
        for (int r = 0; r < 4; ++r) {
            int row = qrow0 + g * 4 + r;
            attn[(size_t)row * 2048 + h * 256 + nd * 16 + c16] =
                (bf16_t)(acc[nd][r] * inv[r]);
        }
}

// ---------------------------------------------------------------------------
// Workspace (peak ~79.7 MB, phase-aliased):
//   hs_bf [0,          20,971,520)  (dead after gemm1)
//   qb    [20,971,520, 37,748,736)
//   kb_raw[37,748,736, 46,137,344)  (dead after norm_qk)
//   vt2   [46,137,344, 54,525,952)  tiled+swizzled
//   Bh    [54,525,952, 75,497,472)  (dead after gemm1)
//   kb2   [54,525,952, 62,914,560)  (over dead Bh; by norm_qk)
//   ct    [75,497,472, 77,594,624)
//   st    [77,594,624, 79,691,776)
//   attnb [0,          16,777,216)  (over dead hs_bf)
//   woh   [20,971,520, 31,457,280)  (over dead qb, after attn)
// ---------------------------------------------------------------------------
extern "C" void kernel_launch(void* const* d_in, const int* in_sizes, int n_in,
                              void* d_out, int out_size, void* d_ws, size_t ws_size,
                              hipStream_t stream)
{
    (void)in_sizes; (void)n_in; (void)out_size; (void)ws_size;
    const float* hs  = (const float*)d_in[0];
    const float* wq  = (const float*)d_in[3];
    const float* wk  = (const float*)d_in[4];
    const float* wv  = (const float*)d_in[5];
    const float* wo  = (const float*)d_in[6];
    const float* qnw = (const float*)d_in[7];
    const float* knw = (const float*)d_in[8];

    char* ws = (char*)d_ws;
    bf16_t* hs_bf = (bf16_t*)(ws);
    bf16_t* qb    = (bf16_t*)(ws + 20971520);
    bf16_t* kraw  = (bf16_t*)(ws + 37748736);
    bf16_t* vt2   = (bf16_t*)(ws + 46137344);
    bf16_t* Bh    = (bf16_t*)(ws + 54525952);
    bf16_t* kb2   = (bf16_t*)(ws + 54525952);
    float*  ct    = (float*)(ws + 75497472);
    float*  st    = (float*)(ws + 77594624);
    bf16_t* attnb = (bf16_t*)(ws);
    bf16_t* woh   = (bf16_t*)(ws + 20971520);

    // 1. fused prep: hs->bf16 + weight transposes + rope tables
    prep<<<14848, 256, 0, stream>>>(hs, hs_bf, wq, wk, wv, Bh, ct, st);

    // 2. fused qkv projection (8-phase 256^2, round-12 schedule)
    gemm1<<<dim3(16, 16), 512, 0, stream>>>(hs_bf, Bh, qb, kraw, vt2);

    // 3. fused norms (q in-place; k re-tiled into kb2 over dead Bh)
    norm_qk<<<4096, 512, 0, stream>>>(qb, kraw, kb2, qnw, knw, ct, st);

    // 4. attention (grid (h, qt) -> head-per-XCD pinning)
    attn_fwd6<<<dim3(8, 64), 256, 0, stream>>>(qb, kb2, vt2, attnb);

    // 5. wo -> woT panel (over dead qb), then output projection
    transpose_h<<<dim3(40, 32), 256, 0, stream>>>(wo, woh, 2048, 2560);
    gemm2p<<<dim3(10, 16), 512, 0, stream>>>(attnb, woh, (float*)d_out);
}